// Round 3
// baseline (939.552 us; speedup 1.0000x reference)
//
#include <hip/hip_runtime.h>
#include <hip/hip_bf16.h>
#include <cstdint>

// ---------------- problem constants ----------------
namespace {
constexpr int BB = 4;
constexpr int CC = 27;
constexpr int HW = 448 * 448;                 // 200704
constexpr long long CHW = (long long)CC * HW; // 5419008
constexpr int NP = 196;                        // patch positions
constexpr int NSTRIP = HW / NP;                // 1024
constexpr int GG = 56 * 56;                    // 3136 pooled positions
constexpr int DSPLIT = 16;
constexpr int DTOT = CC * NSTRIP;              // 27648
constexpr int DCHUNK = DTOT / DSPLIT;          // 1728
constexpr float SCALE_P = 0.0060140449f;       // 1/sqrt(27648)
constexpr float SCALE_G = 0.1924500897f;       // 1/sqrt(27)
constexpr float EPSV = 1e-5f;
constexpr int KSPLIT = 32;                     // key splits for global attn
constexpr int KPB = GG / KSPLIT;               // 98 keys per block
}

__device__ __forceinline__ float bf2f(unsigned short u) {
    return __uint_as_float(((uint32_t)u) << 16);
}

// ---------------- 1. GroupNorm stats ----------------
__global__ void k_gn_partial(const float* __restrict__ x, float* __restrict__ part) {
    int blk = blockIdx.x;          // BB*1024 blocks
    int b = blk >> 10;
    int chunk = blk & 1023;
    const int CLEN = (int)(CHW / 1024);   // 5292
    const float* p = x + (size_t)b * CHW + (size_t)chunk * CLEN;
    float s = 0.f, ss = 0.f;
    for (int i = threadIdx.x; i < CLEN; i += 256) {
        float v = p[i];
        s += v; ss += v * v;
    }
    for (int o = 32; o; o >>= 1) { s += __shfl_down(s, o); ss += __shfl_down(ss, o); }
    __shared__ float ls[4], lss[4];
    int wid = threadIdx.x >> 6, lane = threadIdx.x & 63;
    if (lane == 0) { ls[wid] = s; lss[wid] = ss; }
    __syncthreads();
    if (threadIdx.x == 0) {
        float S = ls[0] + ls[1] + ls[2] + ls[3];
        float SS = lss[0] + lss[1] + lss[2] + lss[3];
        part[blk * 2] = S; part[blk * 2 + 1] = SS;
    }
}

__global__ void k_gn_final(const float* __restrict__ part, float* __restrict__ stats) {
    int b = blockIdx.x;
    float s = 0.f, ss = 0.f;
    for (int i = threadIdx.x; i < 1024; i += 256) {
        s += part[(b * 1024 + i) * 2];
        ss += part[(b * 1024 + i) * 2 + 1];
    }
    for (int o = 32; o; o >>= 1) { s += __shfl_down(s, o); ss += __shfl_down(ss, o); }
    __shared__ float ls[4], lss[4];
    int wid = threadIdx.x >> 6, lane = threadIdx.x & 63;
    if (lane == 0) { ls[wid] = s; lss[wid] = ss; }
    __syncthreads();
    if (threadIdx.x == 0) {
        float S = ls[0] + ls[1] + ls[2] + ls[3];
        float SS = lss[0] + lss[1] + lss[2] + lss[3];
        float mean = S / (float)CHW;
        float var = SS / (float)CHW - mean * mean;
        stats[b * 2] = mean;
        stats[b * 2 + 1] = rsqrtf(var + EPSV);
    }
}

// ---------------- 2. GN-apply + QKV conv1x1 (-> bf16) ----------------
__global__ void k_qkv(const float* __restrict__ x, const float* __restrict__ stats,
                      const float* __restrict__ qw, const float* __restrict__ qb,
                      const float* __restrict__ kw, const float* __restrict__ kb,
                      const float* __restrict__ vw, const float* __restrict__ vb,
                      const float* __restrict__ gnw, const float* __restrict__ gnb,
                      __hip_bfloat16* __restrict__ q, __hip_bfloat16* __restrict__ k,
                      __hip_bfloat16* __restrict__ v) {
    __shared__ float W[2322];
    for (int i = threadIdx.x; i < 729; i += 256) {
        W[i] = qw[i]; W[729 + i] = kw[i]; W[1458 + i] = vw[i];
    }
    if (threadIdx.x < 27) {
        int i = threadIdx.x;
        W[2187 + i] = qb[i]; W[2214 + i] = kb[i]; W[2241 + i] = vb[i];
        W[2268 + i] = gnw[i]; W[2295 + i] = gnb[i];
    }
    __syncthreads();
    int p = blockIdx.x * 256 + threadIdx.x;   // 0..802815
    int b = p / HW;
    int hw = p - b * HW;
    float mean = stats[b * 2], rstd = stats[b * 2 + 1];
    float xn[27];
    const float* xp = x + (size_t)b * CHW + hw;
#pragma unroll
    for (int c = 0; c < 27; c++)
        xn[c] = (xp[(size_t)c * HW] - mean) * rstd * W[2268 + c] + W[2295 + c];
    size_t ob = (size_t)b * CHW + hw;
#pragma unroll 1
    for (int o = 0; o < 27; o++) {
        float aq = W[2187 + o], ak = W[2214 + o], av = W[2241 + o];
#pragma unroll
        for (int c = 0; c < 27; c++) {
            float xv = xn[c];
            aq += W[o * 27 + c] * xv;
            ak += W[729 + o * 27 + c] * xv;
            av += W[1458 + o * 27 + c] * xv;
        }
        q[ob + (size_t)o * HW] = __float2bfloat16(aq);
        k[ob + (size_t)o * HW] = __float2bfloat16(ak);
        v[ob + (size_t)o * HW] = __float2bfloat16(av);
    }
}

// ---------------- 3. 8x8 avg pool -> transposed [b][g][27] ----------------
__global__ void k_pool(const __hip_bfloat16* __restrict__ src, float* __restrict__ dst) {
    int idx = blockIdx.x * 256 + threadIdx.x;  // < 4*27*3136 = 338688
    int g = idx % GG;
    int t = idx / GG;
    int c = t % 27;
    int b = t / 27;
    int gh = g / 56, gw = g - (g / 56) * 56;
    const ushort* sp = (const ushort*)src + (size_t)(b * 27 + c) * HW + (size_t)(gh * 8) * 448 + gw * 8;
    float s = 0.f;
#pragma unroll
    for (int r = 0; r < 8; r++) {
        const ushort4 a = *reinterpret_cast<const ushort4*>(sp + r * 448);
        const ushort4 d = *reinterpret_cast<const ushort4*>(sp + r * 448 + 4);
        s += bf2f(a.x) + bf2f(a.y) + bf2f(a.z) + bf2f(a.w)
           + bf2f(d.x) + bf2f(d.y) + bf2f(d.z) + bf2f(d.w);
    }
    dst[((size_t)b * GG + g) * 27 + c] = s * (1.f / 64.f);
}

// ---------------- 4a. patch attention S partials ----------------
__global__ void k_spart(const __hip_bfloat16* __restrict__ q, const __hip_bfloat16* __restrict__ k,
                        float* __restrict__ spart) {
    int blk = blockIdx.x;                 // BB*14*16 = 896
    int ds = blk & 15;
    int t = blk >> 4;
    int nt = t % 14;
    int b = t / 14;
    int n0 = nt * 14;
    int m = threadIdx.x < 196 ? threadIdx.x : 195;
    const ushort* qb_ = (const ushort*)q + (size_t)b * CHW;
    const ushort* kb_ = (const ushort*)k + (size_t)b * CHW;
    float acc[14];
#pragma unroll
    for (int j = 0; j < 14; j++) acc[j] = 0.f;
    int d0 = ds * DCHUNK;
    for (int d = d0; d < d0 + DCHUNK; ++d) {
        float kv = bf2f(kb_[(size_t)d * NP + m]);
        const uint32_t* qr = reinterpret_cast<const uint32_t*>(qb_ + (size_t)d * NP + n0);
#pragma unroll
        for (int tt = 0; tt < 7; tt++) {
            uint32_t u = qr[tt];
            float qlo = __uint_as_float(u << 16);
            float qhi = __uint_as_float(u & 0xffff0000u);
            acc[2 * tt] += qlo * kv;
            acc[2 * tt + 1] += qhi * kv;
        }
    }
    if (threadIdx.x < 196) {
        size_t base = ((size_t)(b * 16 + ds) * NP) * NP;
#pragma unroll
        for (int j = 0; j < 14; j++)
            spart[base + (size_t)(n0 + j) * NP + m] = acc[j];
    }
}

// ---------------- 4b. reduce + row softmax -> wT[b][m][n] ----------------
__global__ void k_softmax(const float* __restrict__ spart, float* __restrict__ wT) {
    int blk = blockIdx.x;        // BB*196
    int n = blk % NP;
    int b = blk / NP;
    int m = threadIdx.x;
    float val = -1e30f;
    if (m < 196) {
        float s = 0.f;
#pragma unroll
        for (int ds = 0; ds < 16; ds++)
            s += spart[((size_t)(b * 16 + ds) * NP + n) * NP + m];
        val = s * SCALE_P;
    }
    float mx = val;
    for (int o = 32; o; o >>= 1) mx = fmaxf(mx, __shfl_xor(mx, o));
    __shared__ float redm[4], reds[4];
    int wid = threadIdx.x >> 6, lane = threadIdx.x & 63;
    if (lane == 0) redm[wid] = mx;
    __syncthreads();
    mx = fmaxf(fmaxf(redm[0], redm[1]), fmaxf(redm[2], redm[3]));
    float p = (m < 196) ? __expf(val - mx) : 0.f;
    float sm = p;
    for (int o = 32; o; o >>= 1) sm += __shfl_xor(sm, o);
    if (lane == 0) reds[wid] = sm;
    __syncthreads();
    sm = reds[0] + reds[1] + reds[2] + reds[3];
    if (m < 196)
        wT[((size_t)b * NP + m) * NP + n] = p / sm;
}

// ---------------- 5a. global pooled attention: split-K partials ----------------
// scores are tiny (|s| < ~2): softmax without max-subtraction is exact in fp32,
// so partial (l, acc) over key subsets sum directly.
__global__ __launch_bounds__(256, 1)
void k_gattn_part(const float* __restrict__ qg, const float* __restrict__ kg,
                  const float* __restrict__ vg, float* __restrict__ pacc,
                  float* __restrict__ pl) {
    __shared__ __align__(16) float ksh[KPB * 28];
    __shared__ __align__(16) float vsh[KPB * 28];
    int blk = blockIdx.x;            // 4b * 4qblk * 32ks = 512
    int ks = blk & 31;
    int qblk = (blk >> 5) & 3;
    int b = blk >> 7;

    for (int idx = threadIdx.x; idx < KPB * 28; idx += 256) {
        int r = idx / 28, c = idx - (idx / 28) * 28;
        int g = ks * KPB + r;
        float kvv = 0.f, vvv = 0.f;
        if (c < 27) {
            kvv = kg[((size_t)b * GG + g) * 27 + c];
            vvv = vg[((size_t)b * GG + g) * 27 + c];
        }
        ksh[idx] = kvv; vsh[idx] = vvv;
    }
    __syncthreads();

    float q[4][28], acc[4][28];
    int qbase = qblk * 1024 + threadIdx.x;
#pragma unroll
    for (int qq = 0; qq < 4; qq++) {
#pragma unroll
        for (int c = 0; c < 28; c++) { q[qq][c] = 0.f; acc[qq][c] = 0.f; }
        int qi = qbase + qq * 256;
        if (qi < GG) {
            const float* qr = qg + ((size_t)b * GG + qi) * 27;
#pragma unroll
            for (int c = 0; c < 27; c++) q[qq][c] = qr[c];
        }
    }
    float l0 = 0.f, l1 = 0.f, l2 = 0.f, l3 = 0.f;

    for (int j = 0; j < KPB; j++) {
        const float4* kr = reinterpret_cast<const float4*>(ksh + j * 28);
        float s0 = 0.f, s1 = 0.f, s2 = 0.f, s3 = 0.f;
#pragma unroll
        for (int t = 0; t < 7; t++) {
            float4 kk = kr[t];
            s0 += q[0][4*t]*kk.x + q[0][4*t+1]*kk.y + q[0][4*t+2]*kk.z + q[0][4*t+3]*kk.w;
            s1 += q[1][4*t]*kk.x + q[1][4*t+1]*kk.y + q[1][4*t+2]*kk.z + q[1][4*t+3]*kk.w;
            s2 += q[2][4*t]*kk.x + q[2][4*t+1]*kk.y + q[2][4*t+2]*kk.z + q[2][4*t+3]*kk.w;
            s3 += q[3][4*t]*kk.x + q[3][4*t+1]*kk.y + q[3][4*t+2]*kk.z + q[3][4*t+3]*kk.w;
        }
        float p0 = __expf(s0 * SCALE_G);
        float p1 = __expf(s1 * SCALE_G);
        float p2 = __expf(s2 * SCALE_G);
        float p3 = __expf(s3 * SCALE_G);
        l0 += p0; l1 += p1; l2 += p2; l3 += p3;
        const float4* vr = reinterpret_cast<const float4*>(vsh + j * 28);
#pragma unroll
        for (int t = 0; t < 7; t++) {
            float4 vv = vr[t];
            acc[0][4*t] += p0*vv.x; acc[0][4*t+1] += p0*vv.y; acc[0][4*t+2] += p0*vv.z; acc[0][4*t+3] += p0*vv.w;
            acc[1][4*t] += p1*vv.x; acc[1][4*t+1] += p1*vv.y; acc[1][4*t+2] += p1*vv.z; acc[1][4*t+3] += p1*vv.w;
            acc[2][4*t] += p2*vv.x; acc[2][4*t+1] += p2*vv.y; acc[2][4*t+2] += p2*vv.z; acc[2][4*t+3] += p2*vv.w;
            acc[3][4*t] += p3*vv.x; acc[3][4*t+1] += p3*vv.y; acc[3][4*t+2] += p3*vv.z; acc[3][4*t+3] += p3*vv.w;
        }
    }

    float lv[4] = {l0, l1, l2, l3};
#pragma unroll
    for (int qq = 0; qq < 4; qq++) {
        int qi = qbase + qq * 256;
        if (qi < GG) {
            size_t base = ((size_t)(b * KSPLIT + ks) * GG + qi);
            pl[base] = lv[qq];
            float* pa = pacc + base * 27;
#pragma unroll
            for (int c = 0; c < 27; c++) pa[c] = acc[qq][c];
        }
    }
}

// ---------------- 5b. combine split-K partials ----------------
__global__ void k_gattn_reduce(const float* __restrict__ pacc, const float* __restrict__ pl,
                               float* __restrict__ hg) {
    int t = blockIdx.x * 256 + threadIdx.x;   // < BB*GG*27 = 338688
    if (t >= BB * GG * 27) return;
    int c = t % 27;
    int g = (t / 27) % GG;
    int b = t / (27 * GG);
    float l = 0.f, a = 0.f;
#pragma unroll
    for (int ks = 0; ks < KSPLIT; ks++) {
        size_t base = ((size_t)(b * KSPLIT + ks) * GG + g);
        l += pl[base];
        a += pacc[base * 27 + c];
    }
    hg[((size_t)b * GG + g) * 27 + c] = a / l;
}

// ---------------- 6. final: h_patch GEMV + blend + proj + residual ----------------
__global__ void k_final(const float* __restrict__ x, const __hip_bfloat16* __restrict__ v,
                        const float* __restrict__ wT, const float* __restrict__ hg,
                        const float* __restrict__ projw, float* __restrict__ out) {
    __shared__ __align__(16) float vs[27 * 196];
    __shared__ float pw[729];
    int blk = blockIdx.x;           // BB*1024
    int b = blk >> 10;
    int strip = blk & 1023;
    const ushort* vp = (const ushort*)v + (size_t)b * CHW + (size_t)strip * NP;
    for (int idx = threadIdx.x; idx < 27 * 196; idx += 256) {
        int c = idx / 196, j = idx - (idx / 196) * 196;
        vs[idx] = bf2f(vp[(size_t)c * HW + j]);
    }
    for (int idx = threadIdx.x; idx < 729; idx += 256) pw[idx] = projw[idx];
    __syncthreads();
    if (threadIdx.x < 196) {
        int i = threadIdx.x;
        int hw = strip * NP + i;
        int h = hw / 448;
        int w = hw - h * 448;
        int g = (h >> 3) * 56 + (w >> 3);
        const float* wrow = wT + (size_t)b * NP * NP;
        float acc[27];
#pragma unroll
        for (int c = 0; c < 27; c++) acc[c] = 0.f;
        for (int j4 = 0; j4 < 196; j4 += 4) {
            float w0 = wrow[(j4 + 0) * NP + i];
            float w1 = wrow[(j4 + 1) * NP + i];
            float w2 = wrow[(j4 + 2) * NP + i];
            float w3 = wrow[(j4 + 3) * NP + i];
#pragma unroll
            for (int c = 0; c < 27; c++) {
                const float4 vv = *reinterpret_cast<const float4*>(&vs[c * 196 + j4]);
                acc[c] += vv.x * w0 + vv.y * w1 + vv.z * w2 + vv.w * w3;
            }
        }
        const float* hgr = hg + ((size_t)b * GG + g) * 27;
        float hin[27];
#pragma unroll
        for (int c = 0; c < 27; c++) hin[c] = 0.75f * acc[c] + 0.25f * hgr[c];
        size_t ob = (size_t)b * CHW + hw;
#pragma unroll 1
        for (int o = 0; o < 27; o++) {
            float r = 0.f;
#pragma unroll
            for (int c = 0; c < 27; c++) r += pw[o * 27 + c] * hin[c];
            out[ob + (size_t)o * HW] = x[ob + (size_t)o * HW] + r;
        }
    }
}

// ---------------- launch ----------------
extern "C" void kernel_launch(void* const* d_in, const int* in_sizes, int n_in,
                              void* d_out, int out_size, void* d_ws, size_t ws_size,
                              hipStream_t stream) {
    const float* x    = (const float*)d_in[0];
    const float* gnw  = (const float*)d_in[1];
    const float* gnb  = (const float*)d_in[2];
    const float* qw   = (const float*)d_in[3];
    const float* qb   = (const float*)d_in[4];
    const float* kw   = (const float*)d_in[5];
    const float* kb   = (const float*)d_in[6];
    const float* vw   = (const float*)d_in[7];
    const float* vb   = (const float*)d_in[8];
    const float* pjw  = (const float*)d_in[9];
    float* out = (float*)d_out;

    char* ws = (char*)d_ws;
    size_t off = 0;
    auto alloc = [&](size_t bytes) { void* p = ws + off; off += (bytes + 255) & ~(size_t)255; return p; };
    __hip_bfloat16* qbf = (__hip_bfloat16*)alloc((size_t)BB * CHW * 2);
    __hip_bfloat16* kbf = (__hip_bfloat16*)alloc((size_t)BB * CHW * 2);
    __hip_bfloat16* vbf = (__hip_bfloat16*)alloc((size_t)BB * CHW * 2);
    float* spart = (float*)alloc((size_t)BB * 16 * NP * NP * 4);
    float* wT    = (float*)alloc((size_t)BB * NP * NP * 4);
    float* qg    = (float*)alloc((size_t)BB * GG * 27 * 4);
    float* kg    = (float*)alloc((size_t)BB * GG * 27 * 4);
    float* vg    = (float*)alloc((size_t)BB * GG * 27 * 4);
    float* hg    = (float*)alloc((size_t)BB * GG * 27 * 4);
    float* part  = (float*)alloc((size_t)BB * 1024 * 2 * 4);
    float* stats = (float*)alloc((size_t)BB * 2 * 4);
    float* pacc  = (float*)alloc((size_t)BB * KSPLIT * GG * 27 * 4);
    float* pl    = (float*)alloc((size_t)BB * KSPLIT * GG * 4);

    k_gn_partial<<<BB * 1024, 256, 0, stream>>>(x, part);
    k_gn_final<<<BB, 256, 0, stream>>>(part, stats);
    k_qkv<<<(BB * HW) / 256, 256, 0, stream>>>(x, stats, qw, qb, kw, kb, vw, vb, gnw, gnb,
                                               qbf, kbf, vbf);
    k_pool<<<(BB * 27 * GG) / 256, 256, 0, stream>>>(qbf, qg);
    k_pool<<<(BB * 27 * GG) / 256, 256, 0, stream>>>(kbf, kg);
    k_pool<<<(BB * 27 * GG) / 256, 256, 0, stream>>>(vbf, vg);
    k_spart<<<BB * 14 * 16, 256, 0, stream>>>(qbf, kbf, spart);
    k_softmax<<<BB * NP, 256, 0, stream>>>(spart, wT);
    k_gattn_part<<<BB * 4 * KSPLIT, 256, 0, stream>>>(qg, kg, vg, pacc, pl);
    k_gattn_reduce<<<(BB * GG * 27 + 255) / 256, 256, 0, stream>>>(pacc, pl, hg);
    k_final<<<BB * 1024, 256, 0, stream>>>(x, vbf, wT, hg, pjw, out);
}

// Round 4
// 668.669 us; speedup vs baseline: 1.4051x; 1.4051x over previous
//
#include <hip/hip_runtime.h>
#include <hip/hip_bf16.h>
#include <cstdint>

// ---------------- problem constants ----------------
namespace {
constexpr int BB = 4;
constexpr int CC = 27;
constexpr int HW = 448 * 448;                 // 200704
constexpr long long CHW = (long long)CC * HW; // 5419008
constexpr int NP = 196;                        // patch positions
constexpr int GG = 56 * 56;                    // 3136 pooled positions
constexpr int DTOT = CC * 1024;                // 27648
constexpr float SCALE_P = 0.0060140449f;       // 1/sqrt(27648)
constexpr float SCALE_G = 0.1924500897f;       // 1/sqrt(27)
constexpr float EPSV = 1e-5f;
constexpr int KSPLIT = 32;                     // key splits for global attn
constexpr int KPB = GG / KSPLIT;               // 98 keys per block
// MFMA spart config
constexpr int KCH = 512;                       // d-chunk per block
constexpr int NKS = DTOT / KCH;                // 54 partials
constexpr int MPAD = 224;                      // padded n/m (14 tiles of 16)
constexpr int ROWB = 128;                      // LDS bytes per row (32 d * 2B, pad to 128)
}

typedef __attribute__((ext_vector_type(8))) short short8;
typedef __attribute__((ext_vector_type(4))) float f32x4;

__device__ __forceinline__ float bf2f(unsigned short u) {
    return __uint_as_float(((uint32_t)u) << 16);
}

// ---------------- 1. GroupNorm stats ----------------
__global__ void k_gn_partial(const float* __restrict__ x, float* __restrict__ part) {
    int blk = blockIdx.x;          // BB*1024 blocks
    int b = blk >> 10;
    int chunk = blk & 1023;
    const int CLEN = (int)(CHW / 1024);   // 5292
    const float* p = x + (size_t)b * CHW + (size_t)chunk * CLEN;
    float s = 0.f, ss = 0.f;
    for (int i = threadIdx.x; i < CLEN; i += 256) {
        float v = p[i];
        s += v; ss += v * v;
    }
    for (int o = 32; o; o >>= 1) { s += __shfl_down(s, o); ss += __shfl_down(ss, o); }
    __shared__ float ls[4], lss[4];
    int wid = threadIdx.x >> 6, lane = threadIdx.x & 63;
    if (lane == 0) { ls[wid] = s; lss[wid] = ss; }
    __syncthreads();
    if (threadIdx.x == 0) {
        float S = ls[0] + ls[1] + ls[2] + ls[3];
        float SS = lss[0] + lss[1] + lss[2] + lss[3];
        part[blk * 2] = S; part[blk * 2 + 1] = SS;
    }
}

__global__ void k_gn_final(const float* __restrict__ part, float* __restrict__ stats) {
    int b = blockIdx.x;
    float s = 0.f, ss = 0.f;
    for (int i = threadIdx.x; i < 1024; i += 256) {
        s += part[(b * 1024 + i) * 2];
        ss += part[(b * 1024 + i) * 2 + 1];
    }
    for (int o = 32; o; o >>= 1) { s += __shfl_down(s, o); ss += __shfl_down(ss, o); }
    __shared__ float ls[4], lss[4];
    int wid = threadIdx.x >> 6, lane = threadIdx.x & 63;
    if (lane == 0) { ls[wid] = s; lss[wid] = ss; }
    __syncthreads();
    if (threadIdx.x == 0) {
        float S = ls[0] + ls[1] + ls[2] + ls[3];
        float SS = lss[0] + lss[1] + lss[2] + lss[3];
        float mean = S / (float)CHW;
        float var = SS / (float)CHW - mean * mean;
        stats[b * 2] = mean;
        stats[b * 2 + 1] = rsqrtf(var + EPSV);
    }
}

// ---------------- 2. GN-apply + QKV conv1x1 (-> bf16) ----------------
__global__ void k_qkv(const float* __restrict__ x, const float* __restrict__ stats,
                      const float* __restrict__ qw, const float* __restrict__ qb,
                      const float* __restrict__ kw, const float* __restrict__ kb,
                      const float* __restrict__ vw, const float* __restrict__ vb,
                      const float* __restrict__ gnw, const float* __restrict__ gnb,
                      __hip_bfloat16* __restrict__ q, __hip_bfloat16* __restrict__ k,
                      __hip_bfloat16* __restrict__ v) {
    __shared__ float W[2322];
    for (int i = threadIdx.x; i < 729; i += 256) {
        W[i] = qw[i]; W[729 + i] = kw[i]; W[1458 + i] = vw[i];
    }
    if (threadIdx.x < 27) {
        int i = threadIdx.x;
        W[2187 + i] = qb[i]; W[2214 + i] = kb[i]; W[2241 + i] = vb[i];
        W[2268 + i] = gnw[i]; W[2295 + i] = gnb[i];
    }
    __syncthreads();
    int p = blockIdx.x * 256 + threadIdx.x;   // 0..802815
    int b = p / HW;
    int hw = p - b * HW;
    float mean = stats[b * 2], rstd = stats[b * 2 + 1];
    float xn[27];
    const float* xp = x + (size_t)b * CHW + hw;
#pragma unroll
    for (int c = 0; c < 27; c++)
        xn[c] = (xp[(size_t)c * HW] - mean) * rstd * W[2268 + c] + W[2295 + c];
    size_t ob = (size_t)b * CHW + hw;
#pragma unroll 1
    for (int o = 0; o < 27; o++) {
        float aq = W[2187 + o], ak = W[2214 + o], av = W[2241 + o];
#pragma unroll
        for (int c = 0; c < 27; c++) {
            float xv = xn[c];
            aq += W[o * 27 + c] * xv;
            ak += W[729 + o * 27 + c] * xv;
            av += W[1458 + o * 27 + c] * xv;
        }
        q[ob + (size_t)o * HW] = __float2bfloat16(aq);
        k[ob + (size_t)o * HW] = __float2bfloat16(ak);
        v[ob + (size_t)o * HW] = __float2bfloat16(av);
    }
}

// ---------------- 3. 8x8 avg pool -> transposed [b][g][27] ----------------
__global__ void k_pool(const __hip_bfloat16* __restrict__ src, float* __restrict__ dst) {
    int idx = blockIdx.x * 256 + threadIdx.x;  // < 4*27*3136 = 338688
    int g = idx % GG;
    int t = idx / GG;
    int c = t % 27;
    int b = t / 27;
    int gh = g / 56, gw = g - (g / 56) * 56;
    const ushort* sp = (const ushort*)src + (size_t)(b * 27 + c) * HW + (size_t)(gh * 8) * 448 + gw * 8;
    float s = 0.f;
#pragma unroll
    for (int r = 0; r < 8; r++) {
        const ushort4 a = *reinterpret_cast<const ushort4*>(sp + r * 448);
        const ushort4 d = *reinterpret_cast<const ushort4*>(sp + r * 448 + 4);
        s += bf2f(a.x) + bf2f(a.y) + bf2f(a.z) + bf2f(a.w)
           + bf2f(d.x) + bf2f(d.y) + bf2f(d.z) + bf2f(d.w);
    }
    dst[((size_t)b * GG + g) * 27 + c] = s * (1.f / 64.f);
}

// ---------------- 4a. patch attention S partials via MFMA ----------------
// S[n][m] = sum_d Q[d][n] K[d][m].  A[n][d]=Q^T, B[d][m]=K.
// LDS slabs stored transposed: slab[col][dd] (dd in [0,32)), row = 128 B,
// byte = col*128 + (dd*2 ^ (16*(col&7)))  -> conflict-free b128 frag reads.
__global__ __launch_bounds__(448, 1)
void k_spart_mfma(const __hip_bfloat16* __restrict__ q, const __hip_bfloat16* __restrict__ k,
                  float* __restrict__ spart) {
    __shared__ ushort lq[MPAD * 64];   // 28672 B
    __shared__ ushort lk[MPAD * 64];
    int blk = blockIdx.x;              // 4b * 54ks = 216
    int ks = blk % NKS;
    int b = blk / NKS;
    const ushort* qb_ = (const ushort*)q + (size_t)b * CHW;
    const ushort* kb_ = (const ushort*)k + (size_t)b * CHW;
    int t = threadIdx.x;
    int w = t >> 6, l = t & 63;
    int lrow = l & 15, lg = l >> 4;    // fragment coords
    int sr = t & 15;                   // d-pair index 0..15 (d = 2sr, 2sr+1)
    int sn8 = t >> 4;                  // col-chunk 0..27 (cols sn8*8..+8)

    f32x4 acc[2][13];
#pragma unroll
    for (int i = 0; i < 2; i++)
#pragma unroll
        for (int ct = 0; ct < 13; ct++) acc[i][ct] = (f32x4){0.f, 0.f, 0.f, 0.f};

    int d0 = ks * KCH;
    for (int step = 0; step < KCH / 32; ++step) {
        int dbase = d0 + step * 32;
        // ---- stage Q slab ----
        {
            const ushort* s0 = qb_ + (size_t)(dbase + 2 * sr) * NP + sn8 * 8;
            const ushort* s1 = s0 + NP;
            ushort4 a0 = *reinterpret_cast<const ushort4*>(s0);
            ushort4 a1 = *reinterpret_cast<const ushort4*>(s0 + 4);
            ushort4 b0 = *reinterpret_cast<const ushort4*>(s1);
            ushort4 b1 = *reinterpret_cast<const ushort4*>(s1 + 4);
            ushort ra[8] = {a0.x, a0.y, a0.z, a0.w, a1.x, a1.y, a1.z, a1.w};
            ushort rb[8] = {b0.x, b0.y, b0.z, b0.w, b1.x, b1.y, b1.z, b1.w};
#pragma unroll
            for (int kk = 0; kk < 8; kk++) {
                int n = sn8 * 8 + kk;
                uint32_t val = (uint32_t)ra[kk] | ((uint32_t)rb[kk] << 16);
                *reinterpret_cast<uint32_t*>(reinterpret_cast<char*>(lq) + n * ROWB +
                                             ((4 * sr) ^ (16 * (n & 7)))) = val;
            }
        }
        // ---- stage K slab ----
        {
            const ushort* s0 = kb_ + (size_t)(dbase + 2 * sr) * NP + sn8 * 8;
            const ushort* s1 = s0 + NP;
            ushort4 a0 = *reinterpret_cast<const ushort4*>(s0);
            ushort4 a1 = *reinterpret_cast<const ushort4*>(s0 + 4);
            ushort4 b0 = *reinterpret_cast<const ushort4*>(s1);
            ushort4 b1 = *reinterpret_cast<const ushort4*>(s1 + 4);
            ushort ra[8] = {a0.x, a0.y, a0.z, a0.w, a1.x, a1.y, a1.z, a1.w};
            ushort rb[8] = {b0.x, b0.y, b0.z, b0.w, b1.x, b1.y, b1.z, b1.w};
#pragma unroll
            for (int kk = 0; kk < 8; kk++) {
                int m = sn8 * 8 + kk;
                uint32_t val = (uint32_t)ra[kk] | ((uint32_t)rb[kk] << 16);
                *reinterpret_cast<uint32_t*>(reinterpret_cast<char*>(lk) + m * ROWB +
                                             ((4 * sr) ^ (16 * (m & 7)))) = val;
            }
        }
        __syncthreads();
        // ---- fragments + MFMA ----
        int nA0 = (2 * w) * 16 + lrow;       // wave rows 2w, 2w+1
        int nA1 = nA0 + 16;
        const short8 afr0 = *reinterpret_cast<const short8*>(
            reinterpret_cast<const char*>(lq) + nA0 * ROWB + 16 * (lg ^ (nA0 & 7)));
        const short8 afr1 = *reinterpret_cast<const short8*>(
            reinterpret_cast<const char*>(lq) + nA1 * ROWB + 16 * (lg ^ (nA1 & 7)));
#pragma unroll
        for (int ct = 0; ct < 13; ct++) {
            int m = ct * 16 + lrow;
            const short8 bfr = *reinterpret_cast<const short8*>(
                reinterpret_cast<const char*>(lk) + m * ROWB + 16 * (lg ^ (m & 7)));
            acc[0][ct] = __builtin_amdgcn_mfma_f32_16x16x32_bf16(afr0, bfr, acc[0][ct], 0, 0, 0);
            acc[1][ct] = __builtin_amdgcn_mfma_f32_16x16x32_bf16(afr1, bfr, acc[1][ct], 0, 0, 0);
        }
        __syncthreads();
    }
    // ---- epilogue: D row = (lane>>4)*4 + reg, col = lane&15 ----
    float* sp = spart + (size_t)(b * NKS + ks) * NP * MPAD;
#pragma unroll
    for (int i = 0; i < 2; i++) {
        int rt = 2 * w + i;
#pragma unroll
        for (int r = 0; r < 4; r++) {
            int n = rt * 16 + lg * 4 + r;
            if (n < NP) {
#pragma unroll
                for (int ct = 0; ct < 13; ct++)
                    sp[(size_t)n * MPAD + ct * 16 + lrow] = acc[i][ct][r];
            }
        }
    }
}

// ---------------- 4b. reduce + row softmax -> wT[b][m][n] ----------------
__global__ void k_softmax(const float* __restrict__ spart, float* __restrict__ wT) {
    int blk = blockIdx.x;        // BB*196
    int n = blk % NP;            // query row
    int b = blk / NP;
    int m = threadIdx.x;         // key col
    float val = -1e30f;
    if (m < 196) {
        float s = 0.f;
        for (int ks = 0; ks < NKS; ks++)
            s += spart[((size_t)(b * NKS + ks) * NP + n) * MPAD + m];
        val = s * SCALE_P;
    }
    float mx = val;
    for (int o = 32; o; o >>= 1) mx = fmaxf(mx, __shfl_xor(mx, o));
    __shared__ float redm[4], reds[4];
    int wid = threadIdx.x >> 6, lane = threadIdx.x & 63;
    if (lane == 0) redm[wid] = mx;
    __syncthreads();
    mx = fmaxf(fmaxf(redm[0], redm[1]), fmaxf(redm[2], redm[3]));
    float p = (m < 196) ? __expf(val - mx) : 0.f;
    float sm = p;
    for (int o = 32; o; o >>= 1) sm += __shfl_xor(sm, o);
    if (lane == 0) reds[wid] = sm;
    __syncthreads();
    sm = reds[0] + reds[1] + reds[2] + reds[3];
    if (m < 196)
        wT[((size_t)b * NP + m) * NP + n] = p / sm;
}

// ---------------- 5a. global pooled attention: split-K partials ----------------
__global__ __launch_bounds__(256, 1)
void k_gattn_part(const float* __restrict__ qg, const float* __restrict__ kg,
                  const float* __restrict__ vg, float* __restrict__ pacc,
                  float* __restrict__ pl) {
    __shared__ __align__(16) float ksh[KPB * 28];
    __shared__ __align__(16) float vsh[KPB * 28];
    int blk = blockIdx.x;            // 4b * 4qblk * 32ks = 512
    int ks = blk & 31;
    int qblk = (blk >> 5) & 3;
    int b = blk >> 7;

    for (int idx = threadIdx.x; idx < KPB * 28; idx += 256) {
        int r = idx / 28, c = idx - (idx / 28) * 28;
        int g = ks * KPB + r;
        float kvv = 0.f, vvv = 0.f;
        if (c < 27) {
            kvv = kg[((size_t)b * GG + g) * 27 + c];
            vvv = vg[((size_t)b * GG + g) * 27 + c];
        }
        ksh[idx] = kvv; vsh[idx] = vvv;
    }
    __syncthreads();

    float q[4][28], acc[4][28];
    int qbase = qblk * 1024 + threadIdx.x;
#pragma unroll
    for (int qq = 0; qq < 4; qq++) {
#pragma unroll
        for (int c = 0; c < 28; c++) { q[qq][c] = 0.f; acc[qq][c] = 0.f; }
        int qi = qbase + qq * 256;
        if (qi < GG) {
            const float* qr = qg + ((size_t)b * GG + qi) * 27;
#pragma unroll
            for (int c = 0; c < 27; c++) q[qq][c] = qr[c];
        }
    }
    float l0 = 0.f, l1 = 0.f, l2 = 0.f, l3 = 0.f;

    for (int j = 0; j < KPB; j++) {
        const float4* kr = reinterpret_cast<const float4*>(ksh + j * 28);
        float s0 = 0.f, s1 = 0.f, s2 = 0.f, s3 = 0.f;
#pragma unroll
        for (int t = 0; t < 7; t++) {
            float4 kk = kr[t];
            s0 += q[0][4*t]*kk.x + q[0][4*t+1]*kk.y + q[0][4*t+2]*kk.z + q[0][4*t+3]*kk.w;
            s1 += q[1][4*t]*kk.x + q[1][4*t+1]*kk.y + q[1][4*t+2]*kk.z + q[1][4*t+3]*kk.w;
            s2 += q[2][4*t]*kk.x + q[2][4*t+1]*kk.y + q[2][4*t+2]*kk.z + q[2][4*t+3]*kk.w;
            s3 += q[3][4*t]*kk.x + q[3][4*t+1]*kk.y + q[3][4*t+2]*kk.z + q[3][4*t+3]*kk.w;
        }
        float p0 = __expf(s0 * SCALE_G);
        float p1 = __expf(s1 * SCALE_G);
        float p2 = __expf(s2 * SCALE_G);
        float p3 = __expf(s3 * SCALE_G);
        l0 += p0; l1 += p1; l2 += p2; l3 += p3;
        const float4* vr = reinterpret_cast<const float4*>(vsh + j * 28);
#pragma unroll
        for (int t = 0; t < 7; t++) {
            float4 vv = vr[t];
            acc[0][4*t] += p0*vv.x; acc[0][4*t+1] += p0*vv.y; acc[0][4*t+2] += p0*vv.z; acc[0][4*t+3] += p0*vv.w;
            acc[1][4*t] += p1*vv.x; acc[1][4*t+1] += p1*vv.y; acc[1][4*t+2] += p1*vv.z; acc[1][4*t+3] += p1*vv.w;
            acc[2][4*t] += p2*vv.x; acc[2][4*t+1] += p2*vv.y; acc[2][4*t+2] += p2*vv.z; acc[2][4*t+3] += p2*vv.w;
            acc[3][4*t] += p3*vv.x; acc[3][4*t+1] += p3*vv.y; acc[3][4*t+2] += p3*vv.z; acc[3][4*t+3] += p3*vv.w;
        }
    }

    float lv[4] = {l0, l1, l2, l3};
#pragma unroll
    for (int qq = 0; qq < 4; qq++) {
        int qi = qbase + qq * 256;
        if (qi < GG) {
            size_t base = ((size_t)(b * KSPLIT + ks) * GG + qi);
            pl[base] = lv[qq];
            float* pa = pacc + base * 27;
#pragma unroll
            for (int c = 0; c < 27; c++) pa[c] = acc[qq][c];
        }
    }
}

// ---------------- 5b. combine split-K partials ----------------
__global__ void k_gattn_reduce(const float* __restrict__ pacc, const float* __restrict__ pl,
                               float* __restrict__ hg) {
    int t = blockIdx.x * 256 + threadIdx.x;   // < BB*GG*27 = 338688
    if (t >= BB * GG * 27) return;
    int c = t % 27;
    int g = (t / 27) % GG;
    int b = t / (27 * GG);
    float l = 0.f, a = 0.f;
#pragma unroll
    for (int ks = 0; ks < KSPLIT; ks++) {
        size_t base = ((size_t)(b * KSPLIT + ks) * GG + g);
        l += pl[base];
        a += pacc[base * 27 + c];
    }
    hg[((size_t)b * GG + g) * 27 + c] = a / l;
}

// ---------------- 6. final: h_patch GEMV + blend + proj + residual ----------------
__global__ void k_final(const float* __restrict__ x, const __hip_bfloat16* __restrict__ v,
                        const float* __restrict__ wT, const float* __restrict__ hg,
                        const float* __restrict__ projw, float* __restrict__ out) {
    __shared__ __align__(16) float vs[27 * 196];
    __shared__ float pw[729];
    int blk = blockIdx.x;           // BB*1024
    int b = blk >> 10;
    int strip = blk & 1023;
    const ushort* vp = (const ushort*)v + (size_t)b * CHW + (size_t)strip * NP;
    for (int idx = threadIdx.x; idx < 27 * 196; idx += 256) {
        int c = idx / 196, j = idx - (idx / 196) * 196;
        vs[idx] = bf2f(vp[(size_t)c * HW + j]);
    }
    for (int idx = threadIdx.x; idx < 729; idx += 256) pw[idx] = projw[idx];
    __syncthreads();
    if (threadIdx.x < 196) {
        int i = threadIdx.x;
        int hw = strip * NP + i;
        int h = hw / 448;
        int w = hw - h * 448;
        int g = (h >> 3) * 56 + (w >> 3);
        const float* wrow = wT + (size_t)b * NP * NP;
        float acc[27];
#pragma unroll
        for (int c = 0; c < 27; c++) acc[c] = 0.f;
        for (int j4 = 0; j4 < 196; j4 += 4) {
            float w0 = wrow[(j4 + 0) * NP + i];
            float w1 = wrow[(j4 + 1) * NP + i];
            float w2 = wrow[(j4 + 2) * NP + i];
            float w3 = wrow[(j4 + 3) * NP + i];
#pragma unroll
            for (int c = 0; c < 27; c++) {
                const float4 vv = *reinterpret_cast<const float4*>(&vs[c * 196 + j4]);
                acc[c] += vv.x * w0 + vv.y * w1 + vv.z * w2 + vv.w * w3;
            }
        }
        const float* hgr = hg + ((size_t)b * GG + g) * 27;
        float hin[27];
#pragma unroll
        for (int c = 0; c < 27; c++) hin[c] = 0.75f * acc[c] + 0.25f * hgr[c];
        size_t ob = (size_t)b * CHW + hw;
#pragma unroll 1
        for (int o = 0; o < 27; o++) {
            float r = 0.f;
#pragma unroll
            for (int c = 0; c < 27; c++) r += pw[o * 27 + c] * hin[c];
            out[ob + (size_t)o * HW] = x[ob + (size_t)o * HW] + r;
        }
    }
}

// ---------------- launch ----------------
extern "C" void kernel_launch(void* const* d_in, const int* in_sizes, int n_in,
                              void* d_out, int out_size, void* d_ws, size_t ws_size,
                              hipStream_t stream) {
    const float* x    = (const float*)d_in[0];
    const float* gnw  = (const float*)d_in[1];
    const float* gnb  = (const float*)d_in[2];
    const float* qw   = (const float*)d_in[3];
    const float* qb   = (const float*)d_in[4];
    const float* kw   = (const float*)d_in[5];
    const float* kb   = (const float*)d_in[6];
    const float* vw   = (const float*)d_in[7];
    const float* vb   = (const float*)d_in[8];
    const float* pjw  = (const float*)d_in[9];
    float* out = (float*)d_out;

    char* ws = (char*)d_ws;
    size_t off = 0;
    auto alloc = [&](size_t bytes) { void* p = ws + off; off += (bytes + 255) & ~(size_t)255; return p; };
    __hip_bfloat16* qbf = (__hip_bfloat16*)alloc((size_t)BB * CHW * 2);
    __hip_bfloat16* kbf = (__hip_bfloat16*)alloc((size_t)BB * CHW * 2);
    __hip_bfloat16* vbf = (__hip_bfloat16*)alloc((size_t)BB * CHW * 2);
    // shared region: spart partials (4*54*196*224 f32 = 37.9MB) aliased with
    // gattn pacc (4*32*3136*27 f32 = 43.4MB) — disjoint lifetimes (ordered on stream)
    size_t shared_elems = (size_t)BB * KSPLIT * GG * 27;   // 10,838,016 (the larger)
    float* shbuf = (float*)alloc(shared_elems * 4);
    float* spart = shbuf;
    float* pacc  = shbuf;
    float* wT    = (float*)alloc((size_t)BB * NP * NP * 4);
    float* qg    = (float*)alloc((size_t)BB * GG * 27 * 4);
    float* kg    = (float*)alloc((size_t)BB * GG * 27 * 4);
    float* vg    = (float*)alloc((size_t)BB * GG * 27 * 4);
    float* hg    = (float*)alloc((size_t)BB * GG * 27 * 4);
    float* part  = (float*)alloc((size_t)BB * 1024 * 2 * 4);
    float* stats = (float*)alloc((size_t)BB * 2 * 4);
    float* pl    = (float*)alloc((size_t)BB * KSPLIT * GG * 4);

    k_gn_partial<<<BB * 1024, 256, 0, stream>>>(x, part);
    k_gn_final<<<BB, 256, 0, stream>>>(part, stats);
    k_qkv<<<(BB * HW) / 256, 256, 0, stream>>>(x, stats, qw, qb, kw, kb, vw, vb, gnw, gnb,
                                               qbf, kbf, vbf);
    k_pool<<<(BB * 27 * GG) / 256, 256, 0, stream>>>(qbf, qg);
    k_pool<<<(BB * 27 * GG) / 256, 256, 0, stream>>>(kbf, kg);
    k_pool<<<(BB * 27 * GG) / 256, 256, 0, stream>>>(vbf, vg);
    // spart uses shbuf; must complete (incl. softmax read) before gattn writes pacc
    k_spart_mfma<<<BB * NKS, 448, 0, stream>>>(qbf, kbf, spart);
    k_softmax<<<BB * NP, 256, 0, stream>>>(spart, wT);
    k_gattn_part<<<BB * 4 * KSPLIT, 256, 0, stream>>>(qg, kg, vg, pacc, pl);
    k_gattn_reduce<<<(BB * GG * 27 + 255) / 256, 256, 0, stream>>>(pacc, pl, hg);
    k_final<<<BB * 1024, 256, 0, stream>>>(x, vbf, wT, hg, pjw, out);
}

// Round 6
// 514.044 us; speedup vs baseline: 1.8278x; 1.3008x over previous
//
#include <hip/hip_runtime.h>
#include <hip/hip_bf16.h>
#include <cstdint>

// ---------------- problem constants ----------------
namespace {
constexpr int BB = 4;
constexpr int CC = 27;
constexpr int HW = 448 * 448;                 // 200704
constexpr long long CHW = (long long)CC * HW; // 5419008
constexpr int NP = 196;                        // patch positions
constexpr int GG = 56 * 56;                    // 3136 pooled positions
constexpr int DTOT = CC * 1024;                // 27648
constexpr float SCALE_P = 0.0060140449f;       // 1/sqrt(27648)
constexpr float SCALE_G = 0.1924500897f;       // 1/sqrt(27)
constexpr float EPSV = 1e-5f;
constexpr int KSPLIT = 32;                     // key splits for global attn
constexpr int KPB = GG / KSPLIT;               // 98 keys per block
// MFMA spart config
constexpr int KCH = 512;                       // d-chunk per block
constexpr int NKS = DTOT / KCH;                // 54 partials
constexpr int MPAD = 224;                      // padded n/m (14 tiles of 16)
constexpr int ROWB = 128;                      // LDS bytes per row
// wHat (softmax weights, bf16, [i][j]) padding
constexpr int WROWS = 208;                     // 13 tiles of 16
constexpr int WCOLS = 224;                     // 7 k-steps of 32
}

typedef __attribute__((ext_vector_type(8))) short short8;
typedef __attribute__((ext_vector_type(4))) float f32x4;

__device__ __forceinline__ float bf2f(unsigned short u) {
    return __uint_as_float(((uint32_t)u) << 16);
}

__device__ __forceinline__ ushort f2bf(float f) {
    union { __hip_bfloat16 h; ushort u; } cv;
    cv.h = __float2bfloat16(f);
    return cv.u;
}

// ---------------- 1. GroupNorm stats ----------------
__global__ void k_gn_partial(const float* __restrict__ x, float* __restrict__ part) {
    int blk = blockIdx.x;          // BB*1024 blocks
    int b = blk >> 10;
    int chunk = blk & 1023;
    const int CLEN = (int)(CHW / 1024);   // 5292
    const float* p = x + (size_t)b * CHW + (size_t)chunk * CLEN;
    float s = 0.f, ss = 0.f;
    for (int i = threadIdx.x; i < CLEN; i += 256) {
        float v = p[i];
        s += v; ss += v * v;
    }
    for (int o = 32; o; o >>= 1) { s += __shfl_down(s, o); ss += __shfl_down(ss, o); }
    __shared__ float ls[4], lss[4];
    int wid = threadIdx.x >> 6, lane = threadIdx.x & 63;
    if (lane == 0) { ls[wid] = s; lss[wid] = ss; }
    __syncthreads();
    if (threadIdx.x == 0) {
        float S = ls[0] + ls[1] + ls[2] + ls[3];
        float SS = lss[0] + lss[1] + lss[2] + lss[3];
        part[blk * 2] = S; part[blk * 2 + 1] = SS;
    }
}

__global__ void k_gn_final(const float* __restrict__ part, float* __restrict__ stats) {
    int b = blockIdx.x;
    float s = 0.f, ss = 0.f;
    for (int i = threadIdx.x; i < 1024; i += 256) {
        s += part[(b * 1024 + i) * 2];
        ss += part[(b * 1024 + i) * 2 + 1];
    }
    for (int o = 32; o; o >>= 1) { s += __shfl_down(s, o); ss += __shfl_down(ss, o); }
    __shared__ float ls[4], lss[4];
    int wid = threadIdx.x >> 6, lane = threadIdx.x & 63;
    if (lane == 0) { ls[wid] = s; lss[wid] = ss; }
    __syncthreads();
    if (threadIdx.x == 0) {
        float S = ls[0] + ls[1] + ls[2] + ls[3];
        float SS = lss[0] + lss[1] + lss[2] + lss[3];
        float mean = S / (float)CHW;
        float var = SS / (float)CHW - mean * mean;
        stats[b * 2] = mean;
        stats[b * 2 + 1] = rsqrtf(var + EPSV);
    }
}

// ---------------- 2. GN-apply + QKV conv1x1 (-> bf16) ----------------
__global__ void k_qkv(const float* __restrict__ x, const float* __restrict__ stats,
                      const float* __restrict__ qw, const float* __restrict__ qb,
                      const float* __restrict__ kw, const float* __restrict__ kb,
                      const float* __restrict__ vw, const float* __restrict__ vb,
                      const float* __restrict__ gnw, const float* __restrict__ gnb,
                      __hip_bfloat16* __restrict__ q, __hip_bfloat16* __restrict__ k,
                      __hip_bfloat16* __restrict__ v) {
    __shared__ float W[2322];
    for (int i = threadIdx.x; i < 729; i += 256) {
        W[i] = qw[i]; W[729 + i] = kw[i]; W[1458 + i] = vw[i];
    }
    if (threadIdx.x < 27) {
        int i = threadIdx.x;
        W[2187 + i] = qb[i]; W[2214 + i] = kb[i]; W[2241 + i] = vb[i];
        W[2268 + i] = gnw[i]; W[2295 + i] = gnb[i];
    }
    __syncthreads();
    int p = blockIdx.x * 256 + threadIdx.x;   // 0..802815
    int b = p / HW;
    int hw = p - b * HW;
    float mean = stats[b * 2], rstd = stats[b * 2 + 1];
    float xn[27];
    const float* xp = x + (size_t)b * CHW + hw;
#pragma unroll
    for (int c = 0; c < 27; c++)
        xn[c] = (xp[(size_t)c * HW] - mean) * rstd * W[2268 + c] + W[2295 + c];
    size_t ob = (size_t)b * CHW + hw;
#pragma unroll 1
    for (int o = 0; o < 27; o++) {
        float aq = W[2187 + o], ak = W[2214 + o], av = W[2241 + o];
#pragma unroll
        for (int c = 0; c < 27; c++) {
            float xv = xn[c];
            aq += W[o * 27 + c] * xv;
            ak += W[729 + o * 27 + c] * xv;
            av += W[1458 + o * 27 + c] * xv;
        }
        q[ob + (size_t)o * HW] = __float2bfloat16(aq);
        k[ob + (size_t)o * HW] = __float2bfloat16(ak);
        v[ob + (size_t)o * HW] = __float2bfloat16(av);
    }
}

// ---------------- 3. 8x8 avg pool -> transposed [b][g][27] ----------------
__global__ void k_pool(const __hip_bfloat16* __restrict__ src, float* __restrict__ dst) {
    int idx = blockIdx.x * 256 + threadIdx.x;  // < 4*27*3136 = 338688
    int g = idx % GG;
    int t = idx / GG;
    int c = t % 27;
    int b = t / 27;
    int gh = g / 56, gw = g - (g / 56) * 56;
    const ushort* sp = (const ushort*)src + (size_t)(b * 27 + c) * HW + (size_t)(gh * 8) * 448 + gw * 8;
    float s = 0.f;
#pragma unroll
    for (int r = 0; r < 8; r++) {
        const ushort4 a = *reinterpret_cast<const ushort4*>(sp + r * 448);
        const ushort4 d = *reinterpret_cast<const ushort4*>(sp + r * 448 + 4);
        s += bf2f(a.x) + bf2f(a.y) + bf2f(a.z) + bf2f(a.w)
           + bf2f(d.x) + bf2f(d.y) + bf2f(d.z) + bf2f(d.w);
    }
    dst[((size_t)b * GG + g) * 27 + c] = s * (1.f / 64.f);
}

// ---------------- 4a. patch attention S partials via MFMA ----------------
__global__ __launch_bounds__(448, 1)
void k_spart_mfma(const __hip_bfloat16* __restrict__ q, const __hip_bfloat16* __restrict__ k,
                  float* __restrict__ spart) {
    __shared__ ushort lq[MPAD * 64];   // 28672 B
    __shared__ ushort lk[MPAD * 64];
    int blk = blockIdx.x;              // 4b * 54ks = 216
    int ks = blk % NKS;
    int b = blk / NKS;
    const ushort* qb_ = (const ushort*)q + (size_t)b * CHW;
    const ushort* kb_ = (const ushort*)k + (size_t)b * CHW;
    int t = threadIdx.x;
    int w = t >> 6, l = t & 63;
    int lrow = l & 15, lg = l >> 4;    // fragment coords
    int sr = t & 15;                   // d-pair index 0..15 (d = 2sr, 2sr+1)
    int sn8 = t >> 4;                  // col-chunk 0..27 (cols sn8*8..+8)

    f32x4 acc[2][13];
#pragma unroll
    for (int i = 0; i < 2; i++)
#pragma unroll
        for (int ct = 0; ct < 13; ct++) acc[i][ct] = (f32x4){0.f, 0.f, 0.f, 0.f};

    int d0 = ks * KCH;
    for (int step = 0; step < KCH / 32; ++step) {
        int dbase = d0 + step * 32;
        {
            const ushort* s0 = qb_ + (size_t)(dbase + 2 * sr) * NP + sn8 * 8;
            const ushort* s1 = s0 + NP;
            ushort4 a0 = *reinterpret_cast<const ushort4*>(s0);
            ushort4 a1 = *reinterpret_cast<const ushort4*>(s0 + 4);
            ushort4 b0 = *reinterpret_cast<const ushort4*>(s1);
            ushort4 b1 = *reinterpret_cast<const ushort4*>(s1 + 4);
            ushort ra[8] = {a0.x, a0.y, a0.z, a0.w, a1.x, a1.y, a1.z, a1.w};
            ushort rb[8] = {b0.x, b0.y, b0.z, b0.w, b1.x, b1.y, b1.z, b1.w};
#pragma unroll
            for (int kk = 0; kk < 8; kk++) {
                int n = sn8 * 8 + kk;
                uint32_t val = (uint32_t)ra[kk] | ((uint32_t)rb[kk] << 16);
                *reinterpret_cast<uint32_t*>(reinterpret_cast<char*>(lq) + n * ROWB +
                                             ((4 * sr) ^ (16 * (n & 7)))) = val;
            }
        }
        {
            const ushort* s0 = kb_ + (size_t)(dbase + 2 * sr) * NP + sn8 * 8;
            const ushort* s1 = s0 + NP;
            ushort4 a0 = *reinterpret_cast<const ushort4*>(s0);
            ushort4 a1 = *reinterpret_cast<const ushort4*>(s0 + 4);
            ushort4 b0 = *reinterpret_cast<const ushort4*>(s1);
            ushort4 b1 = *reinterpret_cast<const ushort4*>(s1 + 4);
            ushort ra[8] = {a0.x, a0.y, a0.z, a0.w, a1.x, a1.y, a1.z, a1.w};
            ushort rb[8] = {b0.x, b0.y, b0.z, b0.w, b1.x, b1.y, b1.z, b1.w};
#pragma unroll
            for (int kk = 0; kk < 8; kk++) {
                int m = sn8 * 8 + kk;
                uint32_t val = (uint32_t)ra[kk] | ((uint32_t)rb[kk] << 16);
                *reinterpret_cast<uint32_t*>(reinterpret_cast<char*>(lk) + m * ROWB +
                                             ((4 * sr) ^ (16 * (m & 7)))) = val;
            }
        }
        __syncthreads();
        int nA0 = (2 * w) * 16 + lrow;
        int nA1 = nA0 + 16;
        const short8 afr0 = *reinterpret_cast<const short8*>(
            reinterpret_cast<const char*>(lq) + nA0 * ROWB + 16 * (lg ^ (nA0 & 7)));
        const short8 afr1 = *reinterpret_cast<const short8*>(
            reinterpret_cast<const char*>(lq) + nA1 * ROWB + 16 * (lg ^ (nA1 & 7)));
#pragma unroll
        for (int ct = 0; ct < 13; ct++) {
            int m = ct * 16 + lrow;
            const short8 bfr = *reinterpret_cast<const short8*>(
                reinterpret_cast<const char*>(lk) + m * ROWB + 16 * (lg ^ (m & 7)));
            acc[0][ct] = __builtin_amdgcn_mfma_f32_16x16x32_bf16(afr0, bfr, acc[0][ct], 0, 0, 0);
            acc[1][ct] = __builtin_amdgcn_mfma_f32_16x16x32_bf16(afr1, bfr, acc[1][ct], 0, 0, 0);
        }
        __syncthreads();
    }
    float* sp = spart + (size_t)(b * NKS + ks) * NP * MPAD;
#pragma unroll
    for (int i = 0; i < 2; i++) {
        int rt = 2 * w + i;
#pragma unroll
        for (int r = 0; r < 4; r++) {
            int n = rt * 16 + lg * 4 + r;
            if (n < NP) {
#pragma unroll
                for (int ct = 0; ct < 13; ct++)
                    sp[(size_t)n * MPAD + ct * 16 + lrow] = acc[i][ct][r];
            }
        }
    }
}

// ---------------- 4b. reduce + row softmax -> wHat[b][i][j] bf16 ----------------
// wHat[i=query][j=key], rows padded to 208 (unwritten), cols padded to 224 (zeroed)
__global__ void k_softmax(const float* __restrict__ spart, __hip_bfloat16* __restrict__ wh) {
    int blk = blockIdx.x;        // BB*196
    int n = blk % NP;            // query row
    int b = blk / NP;
    int m = threadIdx.x;         // key col
    float val = -1e30f;
    if (m < 196) {
        float s = 0.f;
        for (int ks = 0; ks < NKS; ks++)
            s += spart[((size_t)(b * NKS + ks) * NP + n) * MPAD + m];
        val = s * SCALE_P;
    }
    float mx = val;
    for (int o = 32; o; o >>= 1) mx = fmaxf(mx, __shfl_xor(mx, o));
    __shared__ float redm[4], reds[4];
    int wid = threadIdx.x >> 6, lane = threadIdx.x & 63;
    if (lane == 0) redm[wid] = mx;
    __syncthreads();
    mx = fmaxf(fmaxf(redm[0], redm[1]), fmaxf(redm[2], redm[3]));
    float p = (m < 196) ? __expf(val - mx) : 0.f;
    float sm = p;
    for (int o = 32; o; o >>= 1) sm += __shfl_xor(sm, o);
    if (lane == 0) reds[wid] = sm;
    __syncthreads();
    sm = reds[0] + reds[1] + reds[2] + reds[3];
    if (m < WCOLS)
        wh[((size_t)b * WROWS + n) * WCOLS + m] =
            __float2bfloat16((m < 196) ? p / sm : 0.f);
}

// ---------------- 5a. global pooled attention: split-K partials ----------------
__global__ __launch_bounds__(256, 1)
void k_gattn_part(const float* __restrict__ qg, const float* __restrict__ kg,
                  const float* __restrict__ vg, float* __restrict__ pacc,
                  float* __restrict__ pl) {
    __shared__ __align__(16) float ksh[KPB * 28];
    __shared__ __align__(16) float vsh[KPB * 28];
    int blk = blockIdx.x;            // 4b * 4qblk * 32ks = 512
    int ks = blk & 31;
    int qblk = (blk >> 5) & 3;
    int b = blk >> 7;

    for (int idx = threadIdx.x; idx < KPB * 28; idx += 256) {
        int r = idx / 28, c = idx - (idx / 28) * 28;
        int g = ks * KPB + r;
        float kvv = 0.f, vvv = 0.f;
        if (c < 27) {
            kvv = kg[((size_t)b * GG + g) * 27 + c];
            vvv = vg[((size_t)b * GG + g) * 27 + c];
        }
        ksh[idx] = kvv; vsh[idx] = vvv;
    }
    __syncthreads();

    float q[4][28], acc[4][28];
    int qbase = qblk * 1024 + threadIdx.x;
#pragma unroll
    for (int qq = 0; qq < 4; qq++) {
#pragma unroll
        for (int c = 0; c < 28; c++) { q[qq][c] = 0.f; acc[qq][c] = 0.f; }
        int qi = qbase + qq * 256;
        if (qi < GG) {
            const float* qr = qg + ((size_t)b * GG + qi) * 27;
#pragma unroll
            for (int c = 0; c < 27; c++) q[qq][c] = qr[c];
        }
    }
    float l0 = 0.f, l1 = 0.f, l2 = 0.f, l3 = 0.f;

    for (int j = 0; j < KPB; j++) {
        const float4* kr = reinterpret_cast<const float4*>(ksh + j * 28);
        float s0 = 0.f, s1 = 0.f, s2 = 0.f, s3 = 0.f;
#pragma unroll
        for (int t = 0; t < 7; t++) {
            float4 kk = kr[t];
            s0 += q[0][4*t]*kk.x + q[0][4*t+1]*kk.y + q[0][4*t+2]*kk.z + q[0][4*t+3]*kk.w;
            s1 += q[1][4*t]*kk.x + q[1][4*t+1]*kk.y + q[1][4*t+2]*kk.z + q[1][4*t+3]*kk.w;
            s2 += q[2][4*t]*kk.x + q[2][4*t+1]*kk.y + q[2][4*t+2]*kk.z + q[2][4*t+3]*kk.w;
            s3 += q[3][4*t]*kk.x + q[3][4*t+1]*kk.y + q[3][4*t+2]*kk.z + q[3][4*t+3]*kk.w;
        }
        float p0 = __expf(s0 * SCALE_G);
        float p1 = __expf(s1 * SCALE_G);
        float p2 = __expf(s2 * SCALE_G);
        float p3 = __expf(s3 * SCALE_G);
        l0 += p0; l1 += p1; l2 += p2; l3 += p3;
        const float4* vr = reinterpret_cast<const float4*>(vsh + j * 28);
#pragma unroll
        for (int t = 0; t < 7; t++) {
            float4 vv = vr[t];
            acc[0][4*t] += p0*vv.x; acc[0][4*t+1] += p0*vv.y; acc[0][4*t+2] += p0*vv.z; acc[0][4*t+3] += p0*vv.w;
            acc[1][4*t] += p1*vv.x; acc[1][4*t+1] += p1*vv.y; acc[1][4*t+2] += p1*vv.z; acc[1][4*t+3] += p1*vv.w;
            acc[2][4*t] += p2*vv.x; acc[2][4*t+1] += p2*vv.y; acc[2][4*t+2] += p2*vv.z; acc[2][4*t+3] += p2*vv.w;
            acc[3][4*t] += p3*vv.x; acc[3][4*t+1] += p3*vv.y; acc[3][4*t+2] += p3*vv.z; acc[3][4*t+3] += p3*vv.w;
        }
    }

    float lv[4] = {l0, l1, l2, l3};
#pragma unroll
    for (int qq = 0; qq < 4; qq++) {
        int qi = qbase + qq * 256;
        if (qi < GG) {
            size_t base = ((size_t)(b * KSPLIT + ks) * GG + qi);
            pl[base] = lv[qq];
            float* pa = pacc + base * 27;
#pragma unroll
            for (int c = 0; c < 27; c++) pa[c] = acc[qq][c];
        }
    }
}

// ---------------- 5b. combine split-K partials ----------------
__global__ void k_gattn_reduce(const float* __restrict__ pacc, const float* __restrict__ pl,
                               float* __restrict__ hg) {
    int t = blockIdx.x * 256 + threadIdx.x;   // < BB*GG*27 = 338688
    if (t >= BB * GG * 27) return;
    int c = t % 27;
    int g = (t / 27) % GG;
    int b = t / (27 * GG);
    float l = 0.f, a = 0.f;
#pragma unroll
    for (int ks = 0; ks < KSPLIT; ks++) {
        size_t base = ((size_t)(b * KSPLIT + ks) * GG + g);
        l += pl[base];
        a += pacc[base * 27 + c];
    }
    hg[((size_t)b * GG + g) * 27 + c] = a / l;
}

// ---------------- 6a. h_patch GEMM via MFMA: hp[d][i] = sum_j V[d][j] W[i][j] ----------------
// A = V (bf16 [27648][196] per batch, row 392B => 8B-aligned loads)
// B = wHat (bf16 [208][224] per batch, row 448B, 16B-aligned), j-pad zeroed.
// A overreads up to 56B past row end: j>=196 killed by B=0. vbf has 64B zero tail.
__global__ __launch_bounds__(256, 1)
void k_hp_gemm(const __hip_bfloat16* __restrict__ v, const __hip_bfloat16* __restrict__ wh,
               __hip_bfloat16* __restrict__ hp) {
    int blk = blockIdx.x;              // BB * 432
    int b = blk / 432;
    int grp = blk % 432;
    int w = threadIdx.x >> 6, l = threadIdx.x & 63;
    int ar = l & 15;                   // A row within tile / B col
    int kg = l >> 4;                   // k-group
    int D0 = (grp * 4 + w) * 16;       // d-tile base

    const ushort* vb = (const ushort*)v + (size_t)b * CHW;
    const ushort* wb = (const ushort*)wh + (size_t)b * WROWS * WCOLS;

    f32x4 acc[13];
#pragma unroll
    for (int ct = 0; ct < 13; ct++) acc[ct] = (f32x4){0.f, 0.f, 0.f, 0.f};

    const ushort* arow = vb + (size_t)(D0 + ar) * NP;
#pragma unroll 1
    for (int step = 0; step < 7; ++step) {
        int joff = step * 32 + kg * 8;
        ushort4 alo = *reinterpret_cast<const ushort4*>(arow + joff);
        ushort4 ahi = *reinterpret_cast<const ushort4*>(arow + joff + 4);
        short8 av;
        av[0] = alo.x; av[1] = alo.y; av[2] = alo.z; av[3] = alo.w;
        av[4] = ahi.x; av[5] = ahi.y; av[6] = ahi.z; av[7] = ahi.w;
#pragma unroll
        for (int ct = 0; ct < 13; ct++) {
            int bi = ct * 16 + ar;
            const short8 bv = *reinterpret_cast<const short8*>(wb + (size_t)bi * WCOLS + joff);
            acc[ct] = __builtin_amdgcn_mfma_f32_16x16x32_bf16(av, bv, acc[ct], 0, 0, 0);
        }
    }
    // C: row = kg*4 + r (d within tile), col = ar (i)
    ushort* hb = (ushort*)hp + (size_t)b * CHW;
#pragma unroll
    for (int ct = 0; ct < 13; ct++) {
        int i = ct * 16 + ar;
        if (i < NP) {
#pragma unroll
            for (int r = 0; r < 4; r++) {
                int d = D0 + kg * 4 + r;
                hb[(size_t)d * NP + i] = f2bf(acc[ct][r]);
            }
        }
    }
}

// ---------------- 6b. blend + proj + residual ----------------
__global__ void k_projres(const float* __restrict__ x, const __hip_bfloat16* __restrict__ hp,
                          const float* __restrict__ hg, const float* __restrict__ projw,
                          float* __restrict__ out) {
    __shared__ float pw[729];
    for (int idx = threadIdx.x; idx < 729; idx += 256) pw[idx] = projw[idx];
    __syncthreads();
    int p = blockIdx.x * 256 + threadIdx.x;   // 0..802815
    int b = p / HW;
    int hw = p - b * HW;
    int h = hw / 448;
    int w = hw - h * 448;
    int g = (h >> 3) * 56 + (w >> 3);
    const ushort* hpp = (const ushort*)hp + (size_t)b * CHW + hw;
    const float* hgr = hg + ((size_t)b * GG + g) * 27;
    float hin[27];
#pragma unroll
    for (int c = 0; c < 27; c++)
        hin[c] = 0.75f * bf2f(hpp[(size_t)c * HW]) + 0.25f * hgr[c];
    size_t ob = (size_t)b * CHW + hw;
#pragma unroll 1
    for (int o = 0; o < 27; o++) {
        float r = 0.f;
#pragma unroll
        for (int c = 0; c < 27; c++) r += pw[o * 27 + c] * hin[c];
        out[ob + (size_t)o * HW] = x[ob + (size_t)o * HW] + r;
    }
}

// ---------------- launch ----------------
extern "C" void kernel_launch(void* const* d_in, const int* in_sizes, int n_in,
                              void* d_out, int out_size, void* d_ws, size_t ws_size,
                              hipStream_t stream) {
    const float* x    = (const float*)d_in[0];
    const float* gnw  = (const float*)d_in[1];
    const float* gnb  = (const float*)d_in[2];
    const float* qw   = (const float*)d_in[3];
    const float* qb   = (const float*)d_in[4];
    const float* kw   = (const float*)d_in[5];
    const float* kb   = (const float*)d_in[6];
    const float* vw   = (const float*)d_in[7];
    const float* vb   = (const float*)d_in[8];
    const float* pjw  = (const float*)d_in[9];
    float* out = (float*)d_out;

    char* ws = (char*)d_ws;
    size_t off = 0;
    auto alloc = [&](size_t bytes) { void* p = ws + off; off += (bytes + 255) & ~(size_t)255; return p; };
    __hip_bfloat16* qbf = (__hip_bfloat16*)alloc((size_t)BB * CHW * 2);
    __hip_bfloat16* kbf = (__hip_bfloat16*)alloc((size_t)BB * CHW * 2);
    __hip_bfloat16* vbf = (__hip_bfloat16*)alloc((size_t)BB * CHW * 2 + 64); // 64B zero tail
    // shared region, disjoint lifetimes (stream-ordered):
    //   spart partials (4*54*196*224 f32 = 37.9MB)
    //   -> gattn pacc (4*32*3136*27 f32 = 43.35MB)
    //   -> h_patch bf16 (4*27*200704*2 = 43.35MB)
    size_t shared_elems = (size_t)BB * KSPLIT * GG * 27;
    float* shbuf = (float*)alloc(shared_elems * 4);
    float* spart = shbuf;
    float* pacc  = shbuf;
    __hip_bfloat16* hp = (__hip_bfloat16*)shbuf;
    __hip_bfloat16* wHat = (__hip_bfloat16*)alloc((size_t)BB * WROWS * WCOLS * 2);
    float* qg    = (float*)alloc((size_t)BB * GG * 27 * 4);
    float* kg    = (float*)alloc((size_t)BB * GG * 27 * 4);
    float* vg    = (float*)alloc((size_t)BB * GG * 27 * 4);
    float* hg    = (float*)alloc((size_t)BB * GG * 27 * 4);
    float* part  = (float*)alloc((size_t)BB * 1024 * 2 * 4);
    float* stats = (float*)alloc((size_t)BB * 2 * 4);
    float* pl    = (float*)alloc((size_t)BB * KSPLIT * GG * 4);

    (void)hipMemsetAsync((char*)vbf + (size_t)BB * CHW * 2, 0, 64, stream);
    k_gn_partial<<<BB * 1024, 256, 0, stream>>>(x, part);
    k_gn_final<<<BB, 256, 0, stream>>>(part, stats);
    k_qkv<<<(BB * HW) / 256, 256, 0, stream>>>(x, stats, qw, qb, kw, kb, vw, vb, gnw, gnb,
                                               qbf, kbf, vbf);
    k_pool<<<(BB * 27 * GG) / 256, 256, 0, stream>>>(qbf, qg);
    k_pool<<<(BB * 27 * GG) / 256, 256, 0, stream>>>(kbf, kg);
    k_pool<<<(BB * 27 * GG) / 256, 256, 0, stream>>>(vbf, vg);
    k_spart_mfma<<<BB * NKS, 448, 0, stream>>>(qbf, kbf, spart);
    k_softmax<<<BB * NP, 256, 0, stream>>>(spart, wHat);
    k_gattn_part<<<BB * 4 * KSPLIT, 256, 0, stream>>>(qg, kg, vg, pacc, pl);
    k_gattn_reduce<<<(BB * GG * 27 + 255) / 256, 256, 0, stream>>>(pacc, pl, hg);
    k_hp_gemm<<<BB * 432, 256, 0, stream>>>(vbf, wHat, hp);
    k_projres<<<(BB * HW) / 256, 256, 0, stream>>>(x, hp, hg, pjw, out);
}

// Round 7
// 470.661 us; speedup vs baseline: 1.9962x; 1.0922x over previous
//
#include <hip/hip_runtime.h>
#include <hip/hip_bf16.h>
#include <cstdint>

// ---------------- problem constants ----------------
namespace {
constexpr int BB = 4;
constexpr int CC = 27;
constexpr int HW = 448 * 448;                 // 200704
constexpr long long CHW = (long long)CC * HW; // 5419008
constexpr int NP = 196;                        // patch positions
constexpr int GG = 56 * 56;                    // 3136 pooled positions
constexpr int DTOT = CC * 1024;                // 27648
constexpr float SCALE_P = 0.0060140449f;       // 1/sqrt(27648)
constexpr float SCALE_G = 0.1924500897f;       // 1/sqrt(27)
constexpr float EPSV = 1e-5f;
constexpr int KSPLIT = 32;                     // key splits for global attn
constexpr int KPB = GG / KSPLIT;               // 98 keys per block
constexpr int NQBLK = 7;                       // query blocks (512 q each)
// MFMA spart config
constexpr int KCH = 512;                       // d-chunk per block
constexpr int NKS = DTOT / KCH;                // 54 partials
constexpr int MPAD = 224;                      // padded n/m (14 tiles of 16)
constexpr int ROWB = 128;                      // LDS bytes per row
// wHat (softmax weights, bf16, [i][j]) padding
constexpr int WROWS = 208;                     // 13 tiles of 16
constexpr int WCOLS = 224;                     // 7 k-steps of 32
}

typedef __attribute__((ext_vector_type(8))) short short8;
typedef __attribute__((ext_vector_type(4))) float f32x4;

__device__ __forceinline__ float bf2f(unsigned short u) {
    return __uint_as_float(((uint32_t)u) << 16);
}

__device__ __forceinline__ ushort f2bf(float f) {
    union { __hip_bfloat16 h; ushort u; } cv;
    cv.h = __float2bfloat16(f);
    return cv.u;
}

// ---------------- 1. GroupNorm stats ----------------
__global__ void k_gn_partial(const float* __restrict__ x, float* __restrict__ part) {
    int blk = blockIdx.x;          // BB*1024 blocks
    int b = blk >> 10;
    int chunk = blk & 1023;
    const int CLEN = (int)(CHW / 1024);   // 5292
    const float* p = x + (size_t)b * CHW + (size_t)chunk * CLEN;
    float s = 0.f, ss = 0.f;
    for (int i = threadIdx.x; i < CLEN; i += 256) {
        float v = p[i];
        s += v; ss += v * v;
    }
    for (int o = 32; o; o >>= 1) { s += __shfl_down(s, o); ss += __shfl_down(ss, o); }
    __shared__ float ls[4], lss[4];
    int wid = threadIdx.x >> 6, lane = threadIdx.x & 63;
    if (lane == 0) { ls[wid] = s; lss[wid] = ss; }
    __syncthreads();
    if (threadIdx.x == 0) {
        float S = ls[0] + ls[1] + ls[2] + ls[3];
        float SS = lss[0] + lss[1] + lss[2] + lss[3];
        part[blk * 2] = S; part[blk * 2 + 1] = SS;
    }
}

__global__ void k_gn_final(const float* __restrict__ part, float* __restrict__ stats) {
    int b = blockIdx.x;
    float s = 0.f, ss = 0.f;
    for (int i = threadIdx.x; i < 1024; i += 256) {
        s += part[(b * 1024 + i) * 2];
        ss += part[(b * 1024 + i) * 2 + 1];
    }
    for (int o = 32; o; o >>= 1) { s += __shfl_down(s, o); ss += __shfl_down(ss, o); }
    __shared__ float ls[4], lss[4];
    int wid = threadIdx.x >> 6, lane = threadIdx.x & 63;
    if (lane == 0) { ls[wid] = s; lss[wid] = ss; }
    __syncthreads();
    if (threadIdx.x == 0) {
        float S = ls[0] + ls[1] + ls[2] + ls[3];
        float SS = lss[0] + lss[1] + lss[2] + lss[3];
        float mean = S / (float)CHW;
        float var = SS / (float)CHW - mean * mean;
        stats[b * 2] = mean;
        stats[b * 2 + 1] = rsqrtf(var + EPSV);
    }
}

// ---------------- 2. GN-apply + QKV conv1x1 (-> bf16) ----------------
__global__ void k_qkv(const float* __restrict__ x, const float* __restrict__ stats,
                      const float* __restrict__ qw, const float* __restrict__ qb,
                      const float* __restrict__ kw, const float* __restrict__ kb,
                      const float* __restrict__ vw, const float* __restrict__ vb,
                      const float* __restrict__ gnw, const float* __restrict__ gnb,
                      __hip_bfloat16* __restrict__ q, __hip_bfloat16* __restrict__ k,
                      __hip_bfloat16* __restrict__ v) {
    __shared__ float W[2322];
    for (int i = threadIdx.x; i < 729; i += 256) {
        W[i] = qw[i]; W[729 + i] = kw[i]; W[1458 + i] = vw[i];
    }
    if (threadIdx.x < 27) {
        int i = threadIdx.x;
        W[2187 + i] = qb[i]; W[2214 + i] = kb[i]; W[2241 + i] = vb[i];
        W[2268 + i] = gnw[i]; W[2295 + i] = gnb[i];
    }
    __syncthreads();
    int p = blockIdx.x * 256 + threadIdx.x;   // 0..802815
    int b = p / HW;
    int hw = p - b * HW;
    float mean = stats[b * 2], rstd = stats[b * 2 + 1];
    float xn[27];
    const float* xp = x + (size_t)b * CHW + hw;
#pragma unroll
    for (int c = 0; c < 27; c++)
        xn[c] = (xp[(size_t)c * HW] - mean) * rstd * W[2268 + c] + W[2295 + c];
    size_t ob = (size_t)b * CHW + hw;
#pragma unroll 1
    for (int o = 0; o < 27; o++) {
        float aq = W[2187 + o], ak = W[2214 + o], av = W[2241 + o];
#pragma unroll
        for (int c = 0; c < 27; c++) {
            float xv = xn[c];
            aq += W[o * 27 + c] * xv;
            ak += W[729 + o * 27 + c] * xv;
            av += W[1458 + o * 27 + c] * xv;
        }
        q[ob + (size_t)o * HW] = __float2bfloat16(aq);
        k[ob + (size_t)o * HW] = __float2bfloat16(ak);
        v[ob + (size_t)o * HW] = __float2bfloat16(av);
    }
}

// ---------------- 3. 8x8 avg pool -> transposed [b][g][27] ----------------
__global__ void k_pool(const __hip_bfloat16* __restrict__ src, float* __restrict__ dst) {
    int idx = blockIdx.x * 256 + threadIdx.x;  // < 4*27*3136 = 338688
    int g = idx % GG;
    int t = idx / GG;
    int c = t % 27;
    int b = t / 27;
    int gh = g / 56, gw = g - (g / 56) * 56;
    const ushort* sp = (const ushort*)src + (size_t)(b * 27 + c) * HW + (size_t)(gh * 8) * 448 + gw * 8;
    float s = 0.f;
#pragma unroll
    for (int r = 0; r < 8; r++) {
        const ushort4 a = *reinterpret_cast<const ushort4*>(sp + r * 448);
        const ushort4 d = *reinterpret_cast<const ushort4*>(sp + r * 448 + 4);
        s += bf2f(a.x) + bf2f(a.y) + bf2f(a.z) + bf2f(a.w)
           + bf2f(d.x) + bf2f(d.y) + bf2f(d.z) + bf2f(d.w);
    }
    dst[((size_t)b * GG + g) * 27 + c] = s * (1.f / 64.f);
}

// ---------------- 4a. patch attention S partials via MFMA ----------------
__global__ __launch_bounds__(448, 1)
void k_spart_mfma(const __hip_bfloat16* __restrict__ q, const __hip_bfloat16* __restrict__ k,
                  float* __restrict__ spart) {
    __shared__ ushort lq[MPAD * 64];   // 28672 B
    __shared__ ushort lk[MPAD * 64];
    int blk = blockIdx.x;              // 4b * 54ks = 216
    int ks = blk % NKS;
    int b = blk / NKS;
    const ushort* qb_ = (const ushort*)q + (size_t)b * CHW;
    const ushort* kb_ = (const ushort*)k + (size_t)b * CHW;
    int t = threadIdx.x;
    int w = t >> 6, l = t & 63;
    int lrow = l & 15, lg = l >> 4;    // fragment coords
    int sr = t & 15;                   // d-pair index 0..15 (d = 2sr, 2sr+1)
    int sn8 = t >> 4;                  // col-chunk 0..27 (cols sn8*8..+8)

    f32x4 acc[2][13];
#pragma unroll
    for (int i = 0; i < 2; i++)
#pragma unroll
        for (int ct = 0; ct < 13; ct++) acc[i][ct] = (f32x4){0.f, 0.f, 0.f, 0.f};

    int d0 = ks * KCH;
    for (int step = 0; step < KCH / 32; ++step) {
        int dbase = d0 + step * 32;
        {
            const ushort* s0 = qb_ + (size_t)(dbase + 2 * sr) * NP + sn8 * 8;
            const ushort* s1 = s0 + NP;
            ushort4 a0 = *reinterpret_cast<const ushort4*>(s0);
            ushort4 a1 = *reinterpret_cast<const ushort4*>(s0 + 4);
            ushort4 b0 = *reinterpret_cast<const ushort4*>(s1);
            ushort4 b1 = *reinterpret_cast<const ushort4*>(s1 + 4);
            ushort ra[8] = {a0.x, a0.y, a0.z, a0.w, a1.x, a1.y, a1.z, a1.w};
            ushort rb[8] = {b0.x, b0.y, b0.z, b0.w, b1.x, b1.y, b1.z, b1.w};
#pragma unroll
            for (int kk = 0; kk < 8; kk++) {
                int n = sn8 * 8 + kk;
                uint32_t val = (uint32_t)ra[kk] | ((uint32_t)rb[kk] << 16);
                *reinterpret_cast<uint32_t*>(reinterpret_cast<char*>(lq) + n * ROWB +
                                             ((4 * sr) ^ (16 * (n & 7)))) = val;
            }
        }
        {
            const ushort* s0 = kb_ + (size_t)(dbase + 2 * sr) * NP + sn8 * 8;
            const ushort* s1 = s0 + NP;
            ushort4 a0 = *reinterpret_cast<const ushort4*>(s0);
            ushort4 a1 = *reinterpret_cast<const ushort4*>(s0 + 4);
            ushort4 b0 = *reinterpret_cast<const ushort4*>(s1);
            ushort4 b1 = *reinterpret_cast<const ushort4*>(s1 + 4);
            ushort ra[8] = {a0.x, a0.y, a0.z, a0.w, a1.x, a1.y, a1.z, a1.w};
            ushort rb[8] = {b0.x, b0.y, b0.z, b0.w, b1.x, b1.y, b1.z, b1.w};
#pragma unroll
            for (int kk = 0; kk < 8; kk++) {
                int m = sn8 * 8 + kk;
                uint32_t val = (uint32_t)ra[kk] | ((uint32_t)rb[kk] << 16);
                *reinterpret_cast<uint32_t*>(reinterpret_cast<char*>(lk) + m * ROWB +
                                             ((4 * sr) ^ (16 * (m & 7)))) = val;
            }
        }
        __syncthreads();
        int nA0 = (2 * w) * 16 + lrow;
        int nA1 = nA0 + 16;
        const short8 afr0 = *reinterpret_cast<const short8*>(
            reinterpret_cast<const char*>(lq) + nA0 * ROWB + 16 * (lg ^ (nA0 & 7)));
        const short8 afr1 = *reinterpret_cast<const short8*>(
            reinterpret_cast<const char*>(lq) + nA1 * ROWB + 16 * (lg ^ (nA1 & 7)));
#pragma unroll
        for (int ct = 0; ct < 13; ct++) {
            int m = ct * 16 + lrow;
            const short8 bfr = *reinterpret_cast<const short8*>(
                reinterpret_cast<const char*>(lk) + m * ROWB + 16 * (lg ^ (m & 7)));
            acc[0][ct] = __builtin_amdgcn_mfma_f32_16x16x32_bf16(afr0, bfr, acc[0][ct], 0, 0, 0);
            acc[1][ct] = __builtin_amdgcn_mfma_f32_16x16x32_bf16(afr1, bfr, acc[1][ct], 0, 0, 0);
        }
        __syncthreads();
    }
    float* sp = spart + (size_t)(b * NKS + ks) * NP * MPAD;
#pragma unroll
    for (int i = 0; i < 2; i++) {
        int rt = 2 * w + i;
#pragma unroll
        for (int r = 0; r < 4; r++) {
            int n = rt * 16 + lg * 4 + r;
            if (n < NP) {
#pragma unroll
                for (int ct = 0; ct < 13; ct++)
                    sp[(size_t)n * MPAD + ct * 16 + lrow] = acc[i][ct][r];
            }
        }
    }
}

// ---------------- 4b. reduce + row softmax -> wHat[b][i][j] bf16 ----------------
__global__ void k_softmax(const float* __restrict__ spart, __hip_bfloat16* __restrict__ wh) {
    int blk = blockIdx.x;        // BB*196
    int n = blk % NP;            // query row
    int b = blk / NP;
    int m = threadIdx.x;         // key col
    float val = -1e30f;
    if (m < 196) {
        float s = 0.f;
        for (int ks = 0; ks < NKS; ks++)
            s += spart[((size_t)(b * NKS + ks) * NP + n) * MPAD + m];
        val = s * SCALE_P;
    }
    float mx = val;
    for (int o = 32; o; o >>= 1) mx = fmaxf(mx, __shfl_xor(mx, o));
    __shared__ float redm[4], reds[4];
    int wid = threadIdx.x >> 6, lane = threadIdx.x & 63;
    if (lane == 0) redm[wid] = mx;
    __syncthreads();
    mx = fmaxf(fmaxf(redm[0], redm[1]), fmaxf(redm[2], redm[3]));
    float p = (m < 196) ? __expf(val - mx) : 0.f;
    float sm = p;
    for (int o = 32; o; o >>= 1) sm += __shfl_xor(sm, o);
    if (lane == 0) reds[wid] = sm;
    __syncthreads();
    sm = reds[0] + reds[1] + reds[2] + reds[3];
    if (m < WCOLS)
        wh[((size_t)b * WROWS + n) * WCOLS + m] =
            __float2bfloat16((m < 196) ? p / sm : 0.f);
}

// ---------------- 5a. global pooled attention: split-K partials ----------------
// 2 queries/thread (no VGPR spill), 512 queries/block, grid 4b*7qblk*32ks=896
__global__ __launch_bounds__(256, 3)
void k_gattn_part(const float* __restrict__ qg, const float* __restrict__ kg,
                  const float* __restrict__ vg, float* __restrict__ pacc,
                  float* __restrict__ pl) {
    __shared__ __align__(16) float ksh[KPB * 28];
    __shared__ __align__(16) float vsh[KPB * 28];
    int blk = blockIdx.x;            // 4b * 7qblk * 32ks = 896
    int ks = blk & 31;
    int t2 = blk >> 5;
    int qblk = t2 % NQBLK;
    int b = t2 / NQBLK;

    for (int idx = threadIdx.x; idx < KPB * 28; idx += 256) {
        int r = idx / 28, c = idx - (idx / 28) * 28;
        int g = ks * KPB + r;
        float kvv = 0.f, vvv = 0.f;
        if (c < 27) {
            kvv = kg[((size_t)b * GG + g) * 27 + c];
            vvv = vg[((size_t)b * GG + g) * 27 + c];
        }
        ksh[idx] = kvv; vsh[idx] = vvv;
    }
    __syncthreads();

    float q[2][28], acc[2][28];
    int qbase = qblk * 512 + threadIdx.x;
#pragma unroll
    for (int qq = 0; qq < 2; qq++) {
#pragma unroll
        for (int c = 0; c < 28; c++) { q[qq][c] = 0.f; acc[qq][c] = 0.f; }
        int qi = qbase + qq * 256;
        if (qi < GG) {
            const float* qr = qg + ((size_t)b * GG + qi) * 27;
#pragma unroll
            for (int c = 0; c < 27; c++) q[qq][c] = qr[c];
        }
    }
    float l0 = 0.f, l1 = 0.f;

    for (int j = 0; j < KPB; j++) {
        const float4* kr = reinterpret_cast<const float4*>(ksh + j * 28);
        float s0 = 0.f, s1 = 0.f;
#pragma unroll
        for (int t = 0; t < 7; t++) {
            float4 kk = kr[t];
            s0 += q[0][4*t]*kk.x + q[0][4*t+1]*kk.y + q[0][4*t+2]*kk.z + q[0][4*t+3]*kk.w;
            s1 += q[1][4*t]*kk.x + q[1][4*t+1]*kk.y + q[1][4*t+2]*kk.z + q[1][4*t+3]*kk.w;
        }
        float p0 = __expf(s0 * SCALE_G);
        float p1 = __expf(s1 * SCALE_G);
        l0 += p0; l1 += p1;
        const float4* vr = reinterpret_cast<const float4*>(vsh + j * 28);
#pragma unroll
        for (int t = 0; t < 7; t++) {
            float4 vv = vr[t];
            acc[0][4*t] += p0*vv.x; acc[0][4*t+1] += p0*vv.y; acc[0][4*t+2] += p0*vv.z; acc[0][4*t+3] += p0*vv.w;
            acc[1][4*t] += p1*vv.x; acc[1][4*t+1] += p1*vv.y; acc[1][4*t+2] += p1*vv.z; acc[1][4*t+3] += p1*vv.w;
        }
    }

    float lv[2] = {l0, l1};
#pragma unroll
    for (int qq = 0; qq < 2; qq++) {
        int qi = qbase + qq * 256;
        if (qi < GG) {
            size_t base = ((size_t)(b * KSPLIT + ks) * GG + qi);
            pl[base] = lv[qq];
            float* pa = pacc + base * 27;
#pragma unroll
            for (int c = 0; c < 27; c++) pa[c] = acc[qq][c];
        }
    }
}

// ---------------- 5b. combine split-K partials ----------------
__global__ void k_gattn_reduce(const float* __restrict__ pacc, const float* __restrict__ pl,
                               float* __restrict__ hg) {
    int t = blockIdx.x * 256 + threadIdx.x;   // < BB*GG*27 = 338688
    if (t >= BB * GG * 27) return;
    int c = t % 27;
    int g = (t / 27) % GG;
    int b = t / (27 * GG);
    float l = 0.f, a = 0.f;
#pragma unroll
    for (int ks = 0; ks < KSPLIT; ks++) {
        size_t base = ((size_t)(b * KSPLIT + ks) * GG + g);
        l += pl[base];
        a += pacc[base * 27 + c];
    }
    hg[((size_t)b * GG + g) * 27 + c] = a / l;
}

// ---------------- 6a. h_patch GEMM via MFMA ----------------
__global__ __launch_bounds__(256, 1)
void k_hp_gemm(const __hip_bfloat16* __restrict__ v, const __hip_bfloat16* __restrict__ wh,
               __hip_bfloat16* __restrict__ hp) {
    int blk = blockIdx.x;              // BB * 432
    int b = blk / 432;
    int grp = blk % 432;
    int w = threadIdx.x >> 6, l = threadIdx.x & 63;
    int ar = l & 15;                   // A row within tile / B col
    int kg = l >> 4;                   // k-group
    int D0 = (grp * 4 + w) * 16;       // d-tile base

    const ushort* vb = (const ushort*)v + (size_t)b * CHW;
    const ushort* wb = (const ushort*)wh + (size_t)b * WROWS * WCOLS;

    f32x4 acc[13];
#pragma unroll
    for (int ct = 0; ct < 13; ct++) acc[ct] = (f32x4){0.f, 0.f, 0.f, 0.f};

    const ushort* arow = vb + (size_t)(D0 + ar) * NP;
#pragma unroll 1
    for (int step = 0; step < 7; ++step) {
        int joff = step * 32 + kg * 8;
        ushort4 alo = *reinterpret_cast<const ushort4*>(arow + joff);
        ushort4 ahi = *reinterpret_cast<const ushort4*>(arow + joff + 4);
        short8 av;
        av[0] = alo.x; av[1] = alo.y; av[2] = alo.z; av[3] = alo.w;
        av[4] = ahi.x; av[5] = ahi.y; av[6] = ahi.z; av[7] = ahi.w;
#pragma unroll
        for (int ct = 0; ct < 13; ct++) {
            int bi = ct * 16 + ar;
            const short8 bv = *reinterpret_cast<const short8*>(wb + (size_t)bi * WCOLS + joff);
            acc[ct] = __builtin_amdgcn_mfma_f32_16x16x32_bf16(av, bv, acc[ct], 0, 0, 0);
        }
    }
    ushort* hb = (ushort*)hp + (size_t)b * CHW;
#pragma unroll
    for (int ct = 0; ct < 13; ct++) {
        int i = ct * 16 + ar;
        if (i < NP) {
#pragma unroll
            for (int r = 0; r < 4; r++) {
                int d = D0 + kg * 4 + r;
                hb[(size_t)d * NP + i] = f2bf(acc[ct][r]);
            }
        }
    }
}

// ---------------- 6b. blend + proj + residual ----------------
__global__ void k_projres(const float* __restrict__ x, const __hip_bfloat16* __restrict__ hp,
                          const float* __restrict__ hg, const float* __restrict__ projw,
                          float* __restrict__ out) {
    __shared__ float pw[729];
    for (int idx = threadIdx.x; idx < 729; idx += 256) pw[idx] = projw[idx];
    __syncthreads();
    int p = blockIdx.x * 256 + threadIdx.x;   // 0..802815
    int b = p / HW;
    int hw = p - b * HW;
    int h = hw / 448;
    int w = hw - h * 448;
    int g = (h >> 3) * 56 + (w >> 3);
    const ushort* hpp = (const ushort*)hp + (size_t)b * CHW + hw;
    const float* hgr = hg + ((size_t)b * GG + g) * 27;
    float hin[27];
#pragma unroll
    for (int c = 0; c < 27; c++)
        hin[c] = 0.75f * bf2f(hpp[(size_t)c * HW]) + 0.25f * hgr[c];
    size_t ob = (size_t)b * CHW + hw;
#pragma unroll 1
    for (int o = 0; o < 27; o++) {
        float r = 0.f;
#pragma unroll
        for (int c = 0; c < 27; c++) r += pw[o * 27 + c] * hin[c];
        out[ob + (size_t)o * HW] = x[ob + (size_t)o * HW] + r;
    }
}

// ---------------- launch ----------------
extern "C" void kernel_launch(void* const* d_in, const int* in_sizes, int n_in,
                              void* d_out, int out_size, void* d_ws, size_t ws_size,
                              hipStream_t stream) {
    const float* x    = (const float*)d_in[0];
    const float* gnw  = (const float*)d_in[1];
    const float* gnb  = (const float*)d_in[2];
    const float* qw   = (const float*)d_in[3];
    const float* qb   = (const float*)d_in[4];
    const float* kw   = (const float*)d_in[5];
    const float* kb   = (const float*)d_in[6];
    const float* vw   = (const float*)d_in[7];
    const float* vb   = (const float*)d_in[8];
    const float* pjw  = (const float*)d_in[9];
    float* out = (float*)d_out;

    char* ws = (char*)d_ws;
    size_t off = 0;
    auto alloc = [&](size_t bytes) { void* p = ws + off; off += (bytes + 255) & ~(size_t)255; return p; };
    __hip_bfloat16* qbf = (__hip_bfloat16*)alloc((size_t)BB * CHW * 2);
    __hip_bfloat16* kbf = (__hip_bfloat16*)alloc((size_t)BB * CHW * 2);
    __hip_bfloat16* vbf = (__hip_bfloat16*)alloc((size_t)BB * CHW * 2 + 64); // 64B zero tail
    // shared region, disjoint lifetimes (stream-ordered):
    //   spart partials -> gattn pacc -> h_patch bf16
    size_t shared_elems = (size_t)BB * KSPLIT * GG * 27;
    float* shbuf = (float*)alloc(shared_elems * 4);
    float* spart = shbuf;
    float* pacc  = shbuf;
    __hip_bfloat16* hp = (__hip_bfloat16*)shbuf;
    __hip_bfloat16* wHat = (__hip_bfloat16*)alloc((size_t)BB * WROWS * WCOLS * 2);
    float* qg    = (float*)alloc((size_t)BB * GG * 27 * 4);
    float* kg    = (float*)alloc((size_t)BB * GG * 27 * 4);
    float* vg    = (float*)alloc((size_t)BB * GG * 27 * 4);
    float* hg    = (float*)alloc((size_t)BB * GG * 27 * 4);
    float* part  = (float*)alloc((size_t)BB * 1024 * 2 * 4);
    float* stats = (float*)alloc((size_t)BB * 2 * 4);
    float* pl    = (float*)alloc((size_t)BB * KSPLIT * GG * 4);

    (void)hipMemsetAsync((char*)vbf + (size_t)BB * CHW * 2, 0, 64, stream);
    k_gn_partial<<<BB * 1024, 256, 0, stream>>>(x, part);
    k_gn_final<<<BB, 256, 0, stream>>>(part, stats);
    k_qkv<<<(BB * HW) / 256, 256, 0, stream>>>(x, stats, qw, qb, kw, kb, vw, vb, gnw, gnb,
                                               qbf, kbf, vbf);
    k_pool<<<(BB * 27 * GG) / 256, 256, 0, stream>>>(qbf, qg);
    k_pool<<<(BB * 27 * GG) / 256, 256, 0, stream>>>(kbf, kg);
    k_pool<<<(BB * 27 * GG) / 256, 256, 0, stream>>>(vbf, vg);
    k_spart_mfma<<<BB * NKS, 448, 0, stream>>>(qbf, kbf, spart);
    k_softmax<<<BB * NP, 256, 0, stream>>>(spart, wHat);
    k_gattn_part<<<BB * NQBLK * KSPLIT, 256, 0, stream>>>(qg, kg, vg, pacc, pl);
    k_gattn_reduce<<<(BB * GG * 27 + 255) / 256, 256, 0, stream>>>(pacc, pl, hg);
    k_hp_gemm<<<BB * 432, 256, 0, stream>>>(vbf, wHat, hp);
    k_projres<<<(BB * HW) / 256, 256, 0, stream>>>(x, hp, hg, pjw, out);
}

// Round 8
// 400.190 us; speedup vs baseline: 2.3478x; 1.1761x over previous
//
#include <hip/hip_runtime.h>
#include <hip/hip_bf16.h>
#include <cstdint>

// ---------------- problem constants ----------------
namespace {
constexpr int BB = 4;
constexpr int CC = 27;
constexpr int HW = 448 * 448;                 // 200704
constexpr long long CHW = (long long)CC * HW; // 5419008
constexpr int NP = 196;                        // patch positions
constexpr int GG = 56 * 56;                    // 3136 pooled positions
constexpr int DTOT = CC * 1024;                // 27648
constexpr float SCALE_P = 0.0060140449f;       // 1/sqrt(27648)
constexpr float SCALE_G = 0.1924500897f;       // 1/sqrt(27)
constexpr float EPSV = 1e-5f;
constexpr int KSPLIT = 32;                     // key splits for global attn
constexpr int KPB = GG / KSPLIT;               // 98 keys per block
constexpr int NQBLK = 7;                       // query blocks (512 q each)
// MFMA spart config
constexpr int KCH = 512;                       // d-chunk per block
constexpr int NKS = DTOT / KCH;                // 54 partials
constexpr int MPAD = 224;                      // padded n/m (14 tiles of 16)
constexpr int ROWB = 128;                      // LDS bytes per row
// wHat (softmax weights, bf16, [i][j]) padding
constexpr int WROWS = 208;                     // 13 tiles of 16
constexpr int WCOLS = 224;                     // 7 k-steps of 32
// qkv-MFMA config
constexpr int XST = 40;                        // LDS row stride (shorts): 80B, 16B-aligned rows
}

typedef __attribute__((ext_vector_type(8))) short short8;
typedef __attribute__((ext_vector_type(4))) float f32x4;

__device__ __forceinline__ float bf2f(unsigned short u) {
    return __uint_as_float(((uint32_t)u) << 16);
}

__device__ __forceinline__ ushort f2bf(float f) {
    union { __hip_bfloat16 h; ushort u; } cv;
    cv.h = __float2bfloat16(f);
    return cv.u;
}

// ---------------- 1. GroupNorm stats ----------------
__global__ void k_gn_partial(const float* __restrict__ x, float* __restrict__ part) {
    int blk = blockIdx.x;          // BB*1024 blocks
    int b = blk >> 10;
    int chunk = blk & 1023;
    const int CLEN = (int)(CHW / 1024);   // 5292
    const float* p = x + (size_t)b * CHW + (size_t)chunk * CLEN;
    float s = 0.f, ss = 0.f;
    for (int i = threadIdx.x; i < CLEN; i += 256) {
        float v = p[i];
        s += v; ss += v * v;
    }
    for (int o = 32; o; o >>= 1) { s += __shfl_down(s, o); ss += __shfl_down(ss, o); }
    __shared__ float ls[4], lss[4];
    int wid = threadIdx.x >> 6, lane = threadIdx.x & 63;
    if (lane == 0) { ls[wid] = s; lss[wid] = ss; }
    __syncthreads();
    if (threadIdx.x == 0) {
        float S = ls[0] + ls[1] + ls[2] + ls[3];
        float SS = lss[0] + lss[1] + lss[2] + lss[3];
        part[blk * 2] = S; part[blk * 2 + 1] = SS;
    }
}

__global__ void k_gn_final(const float* __restrict__ part, float* __restrict__ stats) {
    int b = blockIdx.x;
    float s = 0.f, ss = 0.f;
    for (int i = threadIdx.x; i < 1024; i += 256) {
        s += part[(b * 1024 + i) * 2];
        ss += part[(b * 1024 + i) * 2 + 1];
    }
    for (int o = 32; o; o >>= 1) { s += __shfl_down(s, o); ss += __shfl_down(ss, o); }
    __shared__ float ls[4], lss[4];
    int wid = threadIdx.x >> 6, lane = threadIdx.x & 63;
    if (lane == 0) { ls[wid] = s; lss[wid] = ss; }
    __syncthreads();
    if (threadIdx.x == 0) {
        float S = ls[0] + ls[1] + ls[2] + ls[3];
        float SS = lss[0] + lss[1] + lss[2] + lss[3];
        float mean = S / (float)CHW;
        float var = SS / (float)CHW - mean * mean;
        stats[b * 2] = mean;
        stats[b * 2 + 1] = rsqrtf(var + EPSV);
    }
}

// ---------------- 2. GN-apply + QKV conv1x1 via MFMA (-> bf16) ----------------
// out[o][p] = bias[o] + sum_c Wstk[o][c] * xn[c][p], o in [0,81) = {q,k,v}x27
// A = Wstk (bf16, LDS [96][XST], K padded to 32 with zeros)
// B = xn   (bf16, LDS [256][XST] pixel-major, channels 27..31 zeroed)
// qkv = contiguous [3][BB][27][HW] bf16.
__global__ __launch_bounds__(256, 2)
void k_qkv_mfma(const float* __restrict__ x, const float* __restrict__ stats,
                const float* __restrict__ qw, const float* __restrict__ qb,
                const float* __restrict__ kw, const float* __restrict__ kb,
                const float* __restrict__ vw, const float* __restrict__ vb,
                const float* __restrict__ gnw, const float* __restrict__ gnb,
                __hip_bfloat16* __restrict__ qkv) {
    __shared__ ushort xs[256 * XST];            // 20480 B
    __shared__ ushort wls[96 * XST];            // 7680 B
    __shared__ __align__(16) float bls[96];
    __shared__ float gwls[27], gbls[27];

    int tid = threadIdx.x;
    int P0 = blockIdx.x * 256;                  // global pixel base
    int b = P0 / HW;                            // HW % 256 == 0: no straddle
    int hw0 = P0 - b * HW;

    // stage stacked weights (96x32, zero-padded) + biases + gn params
    for (int i = tid; i < 96 * 32; i += 256) {
        int row = i >> 5, c = i & 31;
        float wv = 0.f;
        if (c < 27 && row < 81) {
            int t = (row >= 54) ? 2 : (row >= 27 ? 1 : 0);
            int oc = row - t * 27;
            const float* wp = (t == 0) ? qw : (t == 1) ? kw : vw;
            wv = wp[oc * 27 + c];
        }
        wls[row * XST + c] = f2bf(wv);
    }
    if (tid < 96) {
        float bv = 0.f;
        if (tid < 27) bv = qb[tid];
        else if (tid < 54) bv = kb[tid - 27];
        else if (tid < 81) bv = vb[tid - 54];
        bls[tid] = bv;
    }
    if (tid < 27) { gwls[tid] = gnw[tid]; gbls[tid] = gnb[tid]; }
    float mean = stats[b * 2], rstd = stats[b * 2 + 1];
    __syncthreads();

    // stage xn (bf16) for this block's 256 pixels
    {
        const float* xp = x + (size_t)b * CHW + hw0 + tid;
        ushort xv[28];
#pragma unroll
        for (int c = 0; c < 27; c++) {
            float v = (xp[(size_t)c * HW] - mean) * rstd * gwls[c] + gbls[c];
            xv[c] = f2bf(v);
        }
        xv[27] = 0;
        uint32_t* xrow = reinterpret_cast<uint32_t*>(&xs[tid * XST]);
#pragma unroll
        for (int i = 0; i < 14; i++)
            xrow[i] = (uint32_t)xv[2 * i] | ((uint32_t)xv[2 * i + 1] << 16);
        xrow[14] = 0; xrow[15] = 0;
    }
    __syncthreads();

    int w = tid >> 6, l = tid & 63;
    int lrow = l & 15, kg = l >> 4;

    short8 afr[6];
    f32x4 binit[6];
#pragma unroll
    for (int mt = 0; mt < 6; mt++) {
        afr[mt] = *reinterpret_cast<const short8*>(&wls[(mt * 16 + lrow) * XST + kg * 8]);
        binit[mt] = *reinterpret_cast<const f32x4*>(&bls[mt * 16 + kg * 4]);
    }

    f32x4 acc[4][6];
#pragma unroll
    for (int pt = 0; pt < 4; pt++) {
        const short8 bfr = *reinterpret_cast<const short8*>(
            &xs[(w * 64 + pt * 16 + lrow) * XST + kg * 8]);
#pragma unroll
        for (int mt = 0; mt < 6; mt++)
            acc[pt][mt] = __builtin_amdgcn_mfma_f32_16x16x32_bf16(afr[mt], bfr, binit[mt], 0, 0, 0);
    }

    // D: col(pixel) = lane&15, row(o within tile) = kg*4 + r
    ushort* ob = (ushort*)qkv;
#pragma unroll
    for (int pt = 0; pt < 4; pt++) {
        int hw = hw0 + w * 64 + pt * 16 + lrow;
#pragma unroll
        for (int mt = 0; mt < 6; mt++) {
#pragma unroll
            for (int r = 0; r < 4; r++) {
                int o = mt * 16 + kg * 4 + r;
                if (o < 81) {
                    int t = (o >= 54) ? 2 : (o >= 27 ? 1 : 0);
                    int oc = o - t * 27;
                    ob[((size_t)t * BB + b) * CHW + (size_t)oc * HW + hw] = f2bf(acc[pt][mt][r]);
                }
            }
        }
    }
}

// ---------------- 3. 8x8 avg pool -> transposed [b][g][27] ----------------
__global__ void k_pool(const __hip_bfloat16* __restrict__ src, float* __restrict__ dst) {
    int idx = blockIdx.x * 256 + threadIdx.x;  // < 4*27*3136 = 338688
    int g = idx % GG;
    int t = idx / GG;
    int c = t % 27;
    int b = t / 27;
    int gh = g / 56, gw = g - (g / 56) * 56;
    const ushort* sp = (const ushort*)src + (size_t)(b * 27 + c) * HW + (size_t)(gh * 8) * 448 + gw * 8;
    float s = 0.f;
#pragma unroll
    for (int r = 0; r < 8; r++) {
        const ushort4 a = *reinterpret_cast<const ushort4*>(sp + r * 448);
        const ushort4 d = *reinterpret_cast<const ushort4*>(sp + r * 448 + 4);
        s += bf2f(a.x) + bf2f(a.y) + bf2f(a.z) + bf2f(a.w)
           + bf2f(d.x) + bf2f(d.y) + bf2f(d.z) + bf2f(d.w);
    }
    dst[((size_t)b * GG + g) * 27 + c] = s * (1.f / 64.f);
}

// ---------------- 4a. patch attention S partials via MFMA ----------------
__global__ __launch_bounds__(448, 1)
void k_spart_mfma(const __hip_bfloat16* __restrict__ q, const __hip_bfloat16* __restrict__ k,
                  float* __restrict__ spart) {
    __shared__ ushort lq[MPAD * 64];   // 28672 B
    __shared__ ushort lk[MPAD * 64];
    int blk = blockIdx.x;              // 4b * 54ks = 216
    int ks = blk % NKS;
    int b = blk / NKS;
    const ushort* qb_ = (const ushort*)q + (size_t)b * CHW;
    const ushort* kb_ = (const ushort*)k + (size_t)b * CHW;
    int t = threadIdx.x;
    int w = t >> 6, l = t & 63;
    int lrow = l & 15, lg = l >> 4;    // fragment coords
    int sr = t & 15;                   // d-pair index 0..15 (d = 2sr, 2sr+1)
    int sn8 = t >> 4;                  // col-chunk 0..27 (cols sn8*8..+8)

    f32x4 acc[2][13];
#pragma unroll
    for (int i = 0; i < 2; i++)
#pragma unroll
        for (int ct = 0; ct < 13; ct++) acc[i][ct] = (f32x4){0.f, 0.f, 0.f, 0.f};

    int d0 = ks * KCH;
    for (int step = 0; step < KCH / 32; ++step) {
        int dbase = d0 + step * 32;
        {
            const ushort* s0 = qb_ + (size_t)(dbase + 2 * sr) * NP + sn8 * 8;
            const ushort* s1 = s0 + NP;
            ushort4 a0 = *reinterpret_cast<const ushort4*>(s0);
            ushort4 a1 = *reinterpret_cast<const ushort4*>(s0 + 4);
            ushort4 b0 = *reinterpret_cast<const ushort4*>(s1);
            ushort4 b1 = *reinterpret_cast<const ushort4*>(s1 + 4);
            ushort ra[8] = {a0.x, a0.y, a0.z, a0.w, a1.x, a1.y, a1.z, a1.w};
            ushort rb[8] = {b0.x, b0.y, b0.z, b0.w, b1.x, b1.y, b1.z, b1.w};
#pragma unroll
            for (int kk = 0; kk < 8; kk++) {
                int n = sn8 * 8 + kk;
                uint32_t val = (uint32_t)ra[kk] | ((uint32_t)rb[kk] << 16);
                *reinterpret_cast<uint32_t*>(reinterpret_cast<char*>(lq) + n * ROWB +
                                             ((4 * sr) ^ (16 * (n & 7)))) = val;
            }
        }
        {
            const ushort* s0 = kb_ + (size_t)(dbase + 2 * sr) * NP + sn8 * 8;
            const ushort* s1 = s0 + NP;
            ushort4 a0 = *reinterpret_cast<const ushort4*>(s0);
            ushort4 a1 = *reinterpret_cast<const ushort4*>(s0 + 4);
            ushort4 b0 = *reinterpret_cast<const ushort4*>(s1);
            ushort4 b1 = *reinterpret_cast<const ushort4*>(s1 + 4);
            ushort ra[8] = {a0.x, a0.y, a0.z, a0.w, a1.x, a1.y, a1.z, a1.w};
            ushort rb[8] = {b0.x, b0.y, b0.z, b0.w, b1.x, b1.y, b1.z, b1.w};
#pragma unroll
            for (int kk = 0; kk < 8; kk++) {
                int m = sn8 * 8 + kk;
                uint32_t val = (uint32_t)ra[kk] | ((uint32_t)rb[kk] << 16);
                *reinterpret_cast<uint32_t*>(reinterpret_cast<char*>(lk) + m * ROWB +
                                             ((4 * sr) ^ (16 * (m & 7)))) = val;
            }
        }
        __syncthreads();
        int nA0 = (2 * w) * 16 + lrow;
        int nA1 = nA0 + 16;
        const short8 afr0 = *reinterpret_cast<const short8*>(
            reinterpret_cast<const char*>(lq) + nA0 * ROWB + 16 * (lg ^ (nA0 & 7)));
        const short8 afr1 = *reinterpret_cast<const short8*>(
            reinterpret_cast<const char*>(lq) + nA1 * ROWB + 16 * (lg ^ (nA1 & 7)));
#pragma unroll
        for (int ct = 0; ct < 13; ct++) {
            int m = ct * 16 + lrow;
            const short8 bfr = *reinterpret_cast<const short8*>(
                reinterpret_cast<const char*>(lk) + m * ROWB + 16 * (lg ^ (m & 7)));
            acc[0][ct] = __builtin_amdgcn_mfma_f32_16x16x32_bf16(afr0, bfr, acc[0][ct], 0, 0, 0);
            acc[1][ct] = __builtin_amdgcn_mfma_f32_16x16x32_bf16(afr1, bfr, acc[1][ct], 0, 0, 0);
        }
        __syncthreads();
    }
    float* sp = spart + (size_t)(b * NKS + ks) * NP * MPAD;
#pragma unroll
    for (int i = 0; i < 2; i++) {
        int rt = 2 * w + i;
#pragma unroll
        for (int r = 0; r < 4; r++) {
            int n = rt * 16 + lg * 4 + r;
            if (n < NP) {
#pragma unroll
                for (int ct = 0; ct < 13; ct++)
                    sp[(size_t)n * MPAD + ct * 16 + lrow] = acc[i][ct][r];
            }
        }
    }
}

// ---------------- 4b. reduce + row softmax -> wHat[b][i][j] bf16 ----------------
__global__ void k_softmax(const float* __restrict__ spart, __hip_bfloat16* __restrict__ wh) {
    int blk = blockIdx.x;        // BB*196
    int n = blk % NP;            // query row
    int b = blk / NP;
    int m = threadIdx.x;         // key col
    float val = -1e30f;
    if (m < 196) {
        float s = 0.f;
        for (int ks = 0; ks < NKS; ks++)
            s += spart[((size_t)(b * NKS + ks) * NP + n) * MPAD + m];
        val = s * SCALE_P;
    }
    float mx = val;
    for (int o = 32; o; o >>= 1) mx = fmaxf(mx, __shfl_xor(mx, o));
    __shared__ float redm[4], reds[4];
    int wid = threadIdx.x >> 6, lane = threadIdx.x & 63;
    if (lane == 0) redm[wid] = mx;
    __syncthreads();
    mx = fmaxf(fmaxf(redm[0], redm[1]), fmaxf(redm[2], redm[3]));
    float p = (m < 196) ? __expf(val - mx) : 0.f;
    float sm = p;
    for (int o = 32; o; o >>= 1) sm += __shfl_xor(sm, o);
    if (lane == 0) reds[wid] = sm;
    __syncthreads();
    sm = reds[0] + reds[1] + reds[2] + reds[3];
    if (m < WCOLS)
        wh[((size_t)b * WROWS + n) * WCOLS + m] =
            __float2bfloat16((m < 196) ? p / sm : 0.f);
}

// ---------------- 5a. global pooled attention: split-K partials ----------------
__global__ __launch_bounds__(256, 3)
void k_gattn_part(const float* __restrict__ qg, const float* __restrict__ kg,
                  const float* __restrict__ vg, float* __restrict__ pacc,
                  float* __restrict__ pl) {
    __shared__ __align__(16) float ksh[KPB * 28];
    __shared__ __align__(16) float vsh[KPB * 28];
    int blk = blockIdx.x;            // 4b * 7qblk * 32ks = 896
    int ks = blk & 31;
    int t2 = blk >> 5;
    int qblk = t2 % NQBLK;
    int b = t2 / NQBLK;

    for (int idx = threadIdx.x; idx < KPB * 28; idx += 256) {
        int r = idx / 28, c = idx - (idx / 28) * 28;
        int g = ks * KPB + r;
        float kvv = 0.f, vvv = 0.f;
        if (c < 27) {
            kvv = kg[((size_t)b * GG + g) * 27 + c];
            vvv = vg[((size_t)b * GG + g) * 27 + c];
        }
        ksh[idx] = kvv; vsh[idx] = vvv;
    }
    __syncthreads();

    float q[2][28], acc[2][28];
    int qbase = qblk * 512 + threadIdx.x;
#pragma unroll
    for (int qq = 0; qq < 2; qq++) {
#pragma unroll
        for (int c = 0; c < 28; c++) { q[qq][c] = 0.f; acc[qq][c] = 0.f; }
        int qi = qbase + qq * 256;
        if (qi < GG) {
            const float* qr = qg + ((size_t)b * GG + qi) * 27;
#pragma unroll
            for (int c = 0; c < 27; c++) q[qq][c] = qr[c];
        }
    }
    float l0 = 0.f, l1 = 0.f;

    for (int j = 0; j < KPB; j++) {
        const float4* kr = reinterpret_cast<const float4*>(ksh + j * 28);
        float s0 = 0.f, s1 = 0.f;
#pragma unroll
        for (int t = 0; t < 7; t++) {
            float4 kk = kr[t];
            s0 += q[0][4*t]*kk.x + q[0][4*t+1]*kk.y + q[0][4*t+2]*kk.z + q[0][4*t+3]*kk.w;
            s1 += q[1][4*t]*kk.x + q[1][4*t+1]*kk.y + q[1][4*t+2]*kk.z + q[1][4*t+3]*kk.w;
        }
        float p0 = __expf(s0 * SCALE_G);
        float p1 = __expf(s1 * SCALE_G);
        l0 += p0; l1 += p1;
        const float4* vr = reinterpret_cast<const float4*>(vsh + j * 28);
#pragma unroll
        for (int t = 0; t < 7; t++) {
            float4 vv = vr[t];
            acc[0][4*t] += p0*vv.x; acc[0][4*t+1] += p0*vv.y; acc[0][4*t+2] += p0*vv.z; acc[0][4*t+3] += p0*vv.w;
            acc[1][4*t] += p1*vv.x; acc[1][4*t+1] += p1*vv.y; acc[1][4*t+2] += p1*vv.z; acc[1][4*t+3] += p1*vv.w;
        }
    }

    float lv[2] = {l0, l1};
#pragma unroll
    for (int qq = 0; qq < 2; qq++) {
        int qi = qbase + qq * 256;
        if (qi < GG) {
            size_t base = ((size_t)(b * KSPLIT + ks) * GG + qi);
            pl[base] = lv[qq];
            float* pa = pacc + base * 27;
#pragma unroll
            for (int c = 0; c < 27; c++) pa[c] = acc[qq][c];
        }
    }
}

// ---------------- 5b. combine split-K partials ----------------
__global__ void k_gattn_reduce(const float* __restrict__ pacc, const float* __restrict__ pl,
                               float* __restrict__ hg) {
    int t = blockIdx.x * 256 + threadIdx.x;   // < BB*GG*27 = 338688
    if (t >= BB * GG * 27) return;
    int c = t % 27;
    int g = (t / 27) % GG;
    int b = t / (27 * GG);
    float l = 0.f, a = 0.f;
#pragma unroll
    for (int ks = 0; ks < KSPLIT; ks++) {
        size_t base = ((size_t)(b * KSPLIT + ks) * GG + g);
        l += pl[base];
        a += pacc[base * 27 + c];
    }
    hg[((size_t)b * GG + g) * 27 + c] = a / l;
}

// ---------------- 6a. h_patch GEMM via MFMA ----------------
__global__ __launch_bounds__(256, 1)
void k_hp_gemm(const __hip_bfloat16* __restrict__ v, const __hip_bfloat16* __restrict__ wh,
               __hip_bfloat16* __restrict__ hp) {
    int blk = blockIdx.x;              // BB * 432
    int b = blk / 432;
    int grp = blk % 432;
    int w = threadIdx.x >> 6, l = threadIdx.x & 63;
    int ar = l & 15;                   // A row within tile / B col
    int kg = l >> 4;                   // k-group
    int D0 = (grp * 4 + w) * 16;       // d-tile base

    const ushort* vb = (const ushort*)v + (size_t)b * CHW;
    const ushort* wb = (const ushort*)wh + (size_t)b * WROWS * WCOLS;

    f32x4 acc[13];
#pragma unroll
    for (int ct = 0; ct < 13; ct++) acc[ct] = (f32x4){0.f, 0.f, 0.f, 0.f};

    const ushort* arow = vb + (size_t)(D0 + ar) * NP;
#pragma unroll 1
    for (int step = 0; step < 7; ++step) {
        int joff = step * 32 + kg * 8;
        ushort4 alo = *reinterpret_cast<const ushort4*>(arow + joff);
        ushort4 ahi = *reinterpret_cast<const ushort4*>(arow + joff + 4);
        short8 av;
        av[0] = alo.x; av[1] = alo.y; av[2] = alo.z; av[3] = alo.w;
        av[4] = ahi.x; av[5] = ahi.y; av[6] = ahi.z; av[7] = ahi.w;
#pragma unroll
        for (int ct = 0; ct < 13; ct++) {
            int bi = ct * 16 + ar;
            const short8 bv = *reinterpret_cast<const short8*>(wb + (size_t)bi * WCOLS + joff);
            acc[ct] = __builtin_amdgcn_mfma_f32_16x16x32_bf16(av, bv, acc[ct], 0, 0, 0);
        }
    }
    ushort* hb = (ushort*)hp + (size_t)b * CHW;
#pragma unroll
    for (int ct = 0; ct < 13; ct++) {
        int i = ct * 16 + ar;
        if (i < NP) {
#pragma unroll
            for (int r = 0; r < 4; r++) {
                int d = D0 + kg * 4 + r;
                hb[(size_t)d * NP + i] = f2bf(acc[ct][r]);
            }
        }
    }
}

// ---------------- 6b. blend + proj + residual ----------------
__global__ void k_projres(const float* __restrict__ x, const __hip_bfloat16* __restrict__ hp,
                          const float* __restrict__ hg, const float* __restrict__ projw,
                          float* __restrict__ out) {
    __shared__ float pw[729];
    for (int idx = threadIdx.x; idx < 729; idx += 256) pw[idx] = projw[idx];
    __syncthreads();
    int p = blockIdx.x * 256 + threadIdx.x;   // 0..802815
    int b = p / HW;
    int hw = p - b * HW;
    int h = hw / 448;
    int w = hw - h * 448;
    int g = (h >> 3) * 56 + (w >> 3);
    const ushort* hpp = (const ushort*)hp + (size_t)b * CHW + hw;
    const float* hgr = hg + ((size_t)b * GG + g) * 27;
    float hin[27];
#pragma unroll
    for (int c = 0; c < 27; c++)
        hin[c] = 0.75f * bf2f(hpp[(size_t)c * HW]) + 0.25f * hgr[c];
    size_t ob = (size_t)b * CHW + hw;
#pragma unroll 1
    for (int o = 0; o < 27; o++) {
        float r = 0.f;
#pragma unroll
        for (int c = 0; c < 27; c++) r += pw[o * 27 + c] * hin[c];
        out[ob + (size_t)o * HW] = x[ob + (size_t)o * HW] + r;
    }
}

// ---------------- launch ----------------
extern "C" void kernel_launch(void* const* d_in, const int* in_sizes, int n_in,
                              void* d_out, int out_size, void* d_ws, size_t ws_size,
                              hipStream_t stream) {
    const float* x    = (const float*)d_in[0];
    const float* gnw  = (const float*)d_in[1];
    const float* gnb  = (const float*)d_in[2];
    const float* qw   = (const float*)d_in[3];
    const float* qb   = (const float*)d_in[4];
    const float* kw   = (const float*)d_in[5];
    const float* kb   = (const float*)d_in[6];
    const float* vw   = (const float*)d_in[7];
    const float* vb   = (const float*)d_in[8];
    const float* pjw  = (const float*)d_in[9];
    float* out = (float*)d_out;

    char* ws = (char*)d_ws;
    size_t off = 0;
    auto alloc = [&](size_t bytes) { void* p = ws + off; off += (bytes + 255) & ~(size_t)255; return p; };
    // qkv: contiguous [3][BB][27][HW] bf16 + 64B zero tail (k_hp_gemm overread)
    __hip_bfloat16* qkvbuf = (__hip_bfloat16*)alloc((size_t)3 * BB * CHW * 2 + 64);
    __hip_bfloat16* qbf = qkvbuf;
    __hip_bfloat16* kbf = qkvbuf + (size_t)BB * CHW;
    __hip_bfloat16* vbf = qkvbuf + (size_t)2 * BB * CHW;
    // shared region, disjoint lifetimes (stream-ordered):
    //   spart partials -> gattn pacc -> h_patch bf16
    size_t shared_elems = (size_t)BB * KSPLIT * GG * 27;
    float* shbuf = (float*)alloc(shared_elems * 4);
    float* spart = shbuf;
    float* pacc  = shbuf;
    __hip_bfloat16* hp = (__hip_bfloat16*)shbuf;
    __hip_bfloat16* wHat = (__hip_bfloat16*)alloc((size_t)BB * WROWS * WCOLS * 2);
    float* qg    = (float*)alloc((size_t)BB * GG * 27 * 4);
    float* kg    = (float*)alloc((size_t)BB * GG * 27 * 4);
    float* vg    = (float*)alloc((size_t)BB * GG * 27 * 4);
    float* hg    = (float*)alloc((size_t)BB * GG * 27 * 4);
    float* part  = (float*)alloc((size_t)BB * 1024 * 2 * 4);
    float* stats = (float*)alloc((size_t)BB * 2 * 4);
    float* pl    = (float*)alloc((size_t)BB * KSPLIT * GG * 4);

    (void)hipMemsetAsync((char*)qkvbuf + (size_t)3 * BB * CHW * 2, 0, 64, stream);
    k_gn_partial<<<BB * 1024, 256, 0, stream>>>(x, part);
    k_gn_final<<<BB, 256, 0, stream>>>(part, stats);
    k_qkv_mfma<<<(BB * HW) / 256, 256, 0, stream>>>(x, stats, qw, qb, kw, kb, vw, vb,
                                                    gnw, gnb, qkvbuf);
    k_pool<<<(BB * 27 * GG) / 256, 256, 0, stream>>>(qbf, qg);
    k_pool<<<(BB * 27 * GG) / 256, 256, 0, stream>>>(kbf, kg);
    k_pool<<<(BB * 27 * GG) / 256, 256, 0, stream>>>(vbf, vg);
    k_spart_mfma<<<BB * NKS, 448, 0, stream>>>(qbf, kbf, spart);
    k_softmax<<<BB * NP, 256, 0, stream>>>(spart, wHat);
    k_gattn_part<<<BB * NQBLK * KSPLIT, 256, 0, stream>>>(qg, kg, vg, pacc, pl);
    k_gattn_reduce<<<(BB * GG * 27 + 255) / 256, 256, 0, stream>>>(pacc, pl, hg);
    k_hp_gemm<<<BB * 432, 256, 0, stream>>>(vbf, wHat, hp);
    k_projres<<<(BB * HW) / 256, 256, 0, stream>>>(x, hp, hg, pjw, out);
}

// Round 9
// 395.873 us; speedup vs baseline: 2.3734x; 1.0109x over previous
//
#include <hip/hip_runtime.h>
#include <hip/hip_bf16.h>
#include <cstdint>

// ---------------- problem constants ----------------
namespace {
constexpr int BB = 4;
constexpr int CC = 27;
constexpr int HW = 448 * 448;                 // 200704
constexpr long long CHW = (long long)CC * HW; // 5419008
constexpr int NP = 196;                        // patch positions
constexpr int GG = 56 * 56;                    // 3136 pooled positions
constexpr int DTOT = CC * 1024;                // 27648
constexpr float SCALE_P = 0.0060140449f;       // 1/sqrt(27648)
constexpr float SCALE_G = 0.1924500897f;       // 1/sqrt(27)
constexpr float EPSV = 1e-5f;
constexpr int KSPLIT = 32;                     // key splits for global attn
constexpr int KPB = GG / KSPLIT;               // 98 keys per block
constexpr int NQBLK = 7;                       // query blocks (512 q each)
// MFMA spart config
constexpr int KCH = 512;                       // d-chunk per block
constexpr int NKS = DTOT / KCH;                // 54 partials
constexpr int MPAD = 224;                      // padded n/m (14 tiles of 16)
constexpr int ROWB = 128;                      // LDS bytes per row
// wHat (softmax weights, bf16, [i][j]) padding
constexpr int WROWS = 208;                     // 13 tiles of 16
constexpr int WCOLS = 224;                     // 7 k-steps of 32
// qkv-MFMA config
constexpr int XST = 40;                        // LDS row stride (shorts)
}

typedef __attribute__((ext_vector_type(8))) short short8;
typedef __attribute__((ext_vector_type(4))) float f32x4;

__device__ __forceinline__ float bf2f(unsigned short u) {
    return __uint_as_float(((uint32_t)u) << 16);
}

__device__ __forceinline__ ushort f2bf(float f) {
    union { __hip_bfloat16 h; ushort u; } cv;
    cv.h = __float2bfloat16(f);
    return cv.u;
}

// ---------------- 0. fold proj into V weights: pvw = proj*vw, pvb = proj*vb ----------------
__global__ void k_fold(const float* __restrict__ pjw, const float* __restrict__ vw,
                       const float* __restrict__ vb, float* __restrict__ pvw,
                       float* __restrict__ pvb) {
    __shared__ float pj[729], vv[729], vbs[27];
    int t = threadIdx.x;
    for (int i = t; i < 729; i += 256) { pj[i] = pjw[i]; vv[i] = vw[i]; }
    if (t < 27) vbs[t] = vb[t];
    __syncthreads();
    for (int i = t; i < 729; i += 256) {
        int o = i / 27, c2 = i - (i / 27) * 27;
        float s = 0.f;
#pragma unroll
        for (int c = 0; c < 27; c++) s += pj[o * 27 + c] * vv[c * 27 + c2];
        pvw[i] = s;
    }
    if (t < 27) {
        float s = 0.f;
#pragma unroll
        for (int c = 0; c < 27; c++) s += pj[t * 27 + c] * vbs[c];
        pvb[t] = s;
    }
}

// ---------------- 1. GroupNorm stats ----------------
__global__ void k_gn_partial(const float* __restrict__ x, float* __restrict__ part) {
    int blk = blockIdx.x;          // BB*1024 blocks
    int b = blk >> 10;
    int chunk = blk & 1023;
    const int CLEN = (int)(CHW / 1024);   // 5292
    const float* p = x + (size_t)b * CHW + (size_t)chunk * CLEN;
    float s = 0.f, ss = 0.f;
    for (int i = threadIdx.x; i < CLEN; i += 256) {
        float v = p[i];
        s += v; ss += v * v;
    }
    for (int o = 32; o; o >>= 1) { s += __shfl_down(s, o); ss += __shfl_down(ss, o); }
    __shared__ float ls[4], lss[4];
    int wid = threadIdx.x >> 6, lane = threadIdx.x & 63;
    if (lane == 0) { ls[wid] = s; lss[wid] = ss; }
    __syncthreads();
    if (threadIdx.x == 0) {
        float S = ls[0] + ls[1] + ls[2] + ls[3];
        float SS = lss[0] + lss[1] + lss[2] + lss[3];
        part[blk * 2] = S; part[blk * 2 + 1] = SS;
    }
}

__global__ void k_gn_final(const float* __restrict__ part, float* __restrict__ stats) {
    int b = blockIdx.x;
    float s = 0.f, ss = 0.f;
    for (int i = threadIdx.x; i < 1024; i += 256) {
        s += part[(b * 1024 + i) * 2];
        ss += part[(b * 1024 + i) * 2 + 1];
    }
    for (int o = 32; o; o >>= 1) { s += __shfl_down(s, o); ss += __shfl_down(ss, o); }
    __shared__ float ls[4], lss[4];
    int wid = threadIdx.x >> 6, lane = threadIdx.x & 63;
    if (lane == 0) { ls[wid] = s; lss[wid] = ss; }
    __syncthreads();
    if (threadIdx.x == 0) {
        float S = ls[0] + ls[1] + ls[2] + ls[3];
        float SS = lss[0] + lss[1] + lss[2] + lss[3];
        float mean = S / (float)CHW;
        float var = SS / (float)CHW - mean * mean;
        stats[b * 2] = mean;
        stats[b * 2 + 1] = rsqrtf(var + EPSV);
    }
}

// ---------------- 2. GN-apply + QKV conv1x1 via MFMA (-> bf16) ----------------
// v-slot weights are pre-folded with proj (pvw/pvb): vbf holds proj-ed V.
__global__ __launch_bounds__(256, 2)
void k_qkv_mfma(const float* __restrict__ x, const float* __restrict__ stats,
                const float* __restrict__ qw, const float* __restrict__ qb,
                const float* __restrict__ kw, const float* __restrict__ kb,
                const float* __restrict__ vw, const float* __restrict__ vb,
                const float* __restrict__ gnw, const float* __restrict__ gnb,
                __hip_bfloat16* __restrict__ qkv) {
    __shared__ ushort xs[256 * XST];            // 20480 B
    __shared__ ushort wls[96 * XST];            // 7680 B
    __shared__ __align__(16) float bls[96];
    __shared__ float gwls[27], gbls[27];

    int tid = threadIdx.x;
    int P0 = blockIdx.x * 256;                  // global pixel base
    int b = P0 / HW;                            // HW % 256 == 0: no straddle
    int hw0 = P0 - b * HW;

    for (int i = tid; i < 96 * 32; i += 256) {
        int row = i >> 5, c = i & 31;
        float wv = 0.f;
        if (c < 27 && row < 81) {
            int t = (row >= 54) ? 2 : (row >= 27 ? 1 : 0);
            int oc = row - t * 27;
            const float* wp = (t == 0) ? qw : (t == 1) ? kw : vw;
            wv = wp[oc * 27 + c];
        }
        wls[row * XST + c] = f2bf(wv);
    }
    if (tid < 96) {
        float bv = 0.f;
        if (tid < 27) bv = qb[tid];
        else if (tid < 54) bv = kb[tid - 27];
        else if (tid < 81) bv = vb[tid - 54];
        bls[tid] = bv;
    }
    if (tid < 27) { gwls[tid] = gnw[tid]; gbls[tid] = gnb[tid]; }
    float mean = stats[b * 2], rstd = stats[b * 2 + 1];
    __syncthreads();

    {
        const float* xp = x + (size_t)b * CHW + hw0 + tid;
        ushort xv[28];
#pragma unroll
        for (int c = 0; c < 27; c++) {
            float v = (xp[(size_t)c * HW] - mean) * rstd * gwls[c] + gbls[c];
            xv[c] = f2bf(v);
        }
        xv[27] = 0;
        uint32_t* xrow = reinterpret_cast<uint32_t*>(&xs[tid * XST]);
#pragma unroll
        for (int i = 0; i < 14; i++)
            xrow[i] = (uint32_t)xv[2 * i] | ((uint32_t)xv[2 * i + 1] << 16);
        xrow[14] = 0; xrow[15] = 0;
    }
    __syncthreads();

    int w = tid >> 6, l = tid & 63;
    int lrow = l & 15, kg = l >> 4;

    short8 afr[6];
    f32x4 binit[6];
#pragma unroll
    for (int mt = 0; mt < 6; mt++) {
        afr[mt] = *reinterpret_cast<const short8*>(&wls[(mt * 16 + lrow) * XST + kg * 8]);
        binit[mt] = *reinterpret_cast<const f32x4*>(&bls[mt * 16 + kg * 4]);
    }

    f32x4 acc[4][6];
#pragma unroll
    for (int pt = 0; pt < 4; pt++) {
        const short8 bfr = *reinterpret_cast<const short8*>(
            &xs[(w * 64 + pt * 16 + lrow) * XST + kg * 8]);
#pragma unroll
        for (int mt = 0; mt < 6; mt++)
            acc[pt][mt] = __builtin_amdgcn_mfma_f32_16x16x32_bf16(afr[mt], bfr, binit[mt], 0, 0, 0);
    }

    ushort* ob = (ushort*)qkv;
#pragma unroll
    for (int pt = 0; pt < 4; pt++) {
        int hw = hw0 + w * 64 + pt * 16 + lrow;
#pragma unroll
        for (int mt = 0; mt < 6; mt++) {
#pragma unroll
            for (int r = 0; r < 4; r++) {
                int o = mt * 16 + kg * 4 + r;
                if (o < 81) {
                    int t = (o >= 54) ? 2 : (o >= 27 ? 1 : 0);
                    int oc = o - t * 27;
                    ob[((size_t)t * BB + b) * CHW + (size_t)oc * HW + hw] = f2bf(acc[pt][mt][r]);
                }
            }
        }
    }
}

// ---------------- 3. 8x8 avg pool -> transposed [b][g][27] ----------------
__global__ void k_pool(const __hip_bfloat16* __restrict__ src, float* __restrict__ dst) {
    int idx = blockIdx.x * 256 + threadIdx.x;  // < 4*27*3136 = 338688
    int g = idx % GG;
    int t = idx / GG;
    int c = t % 27;
    int b = t / 27;
    int gh = g / 56, gw = g - (g / 56) * 56;
    const ushort* sp = (const ushort*)src + (size_t)(b * 27 + c) * HW + (size_t)(gh * 8) * 448 + gw * 8;
    float s = 0.f;
#pragma unroll
    for (int r = 0; r < 8; r++) {
        const ushort4 a = *reinterpret_cast<const ushort4*>(sp + r * 448);
        const ushort4 d = *reinterpret_cast<const ushort4*>(sp + r * 448 + 4);
        s += bf2f(a.x) + bf2f(a.y) + bf2f(a.z) + bf2f(a.w)
           + bf2f(d.x) + bf2f(d.y) + bf2f(d.z) + bf2f(d.w);
    }
    dst[((size_t)b * GG + g) * 27 + c] = s * (1.f / 64.f);
}

// ---------------- 4a. patch attention S partials via MFMA ----------------
__global__ __launch_bounds__(448, 1)
void k_spart_mfma(const __hip_bfloat16* __restrict__ q, const __hip_bfloat16* __restrict__ k,
                  float* __restrict__ spart) {
    __shared__ ushort lq[MPAD * 64];   // 28672 B
    __shared__ ushort lk[MPAD * 64];
    int blk = blockIdx.x;              // 4b * 54ks = 216
    int ks = blk % NKS;
    int b = blk / NKS;
    const ushort* qb_ = (const ushort*)q + (size_t)b * CHW;
    const ushort* kb_ = (const ushort*)k + (size_t)b * CHW;
    int t = threadIdx.x;
    int w = t >> 6, l = t & 63;
    int lrow = l & 15, lg = l >> 4;    // fragment coords
    int sr = t & 15;                   // d-pair index 0..15 (d = 2sr, 2sr+1)
    int sn8 = t >> 4;                  // col-chunk 0..27 (cols sn8*8..+8)

    f32x4 acc[2][13];
#pragma unroll
    for (int i = 0; i < 2; i++)
#pragma unroll
        for (int ct = 0; ct < 13; ct++) acc[i][ct] = (f32x4){0.f, 0.f, 0.f, 0.f};

    int d0 = ks * KCH;
    for (int step = 0; step < KCH / 32; ++step) {
        int dbase = d0 + step * 32;
        {
            const ushort* s0 = qb_ + (size_t)(dbase + 2 * sr) * NP + sn8 * 8;
            const ushort* s1 = s0 + NP;
            ushort4 a0 = *reinterpret_cast<const ushort4*>(s0);
            ushort4 a1 = *reinterpret_cast<const ushort4*>(s0 + 4);
            ushort4 b0 = *reinterpret_cast<const ushort4*>(s1);
            ushort4 b1 = *reinterpret_cast<const ushort4*>(s1 + 4);
            ushort ra[8] = {a0.x, a0.y, a0.z, a0.w, a1.x, a1.y, a1.z, a1.w};
            ushort rb[8] = {b0.x, b0.y, b0.z, b0.w, b1.x, b1.y, b1.z, b1.w};
#pragma unroll
            for (int kk = 0; kk < 8; kk++) {
                int n = sn8 * 8 + kk;
                uint32_t val = (uint32_t)ra[kk] | ((uint32_t)rb[kk] << 16);
                *reinterpret_cast<uint32_t*>(reinterpret_cast<char*>(lq) + n * ROWB +
                                             ((4 * sr) ^ (16 * (n & 7)))) = val;
            }
        }
        {
            const ushort* s0 = kb_ + (size_t)(dbase + 2 * sr) * NP + sn8 * 8;
            const ushort* s1 = s0 + NP;
            ushort4 a0 = *reinterpret_cast<const ushort4*>(s0);
            ushort4 a1 = *reinterpret_cast<const ushort4*>(s0 + 4);
            ushort4 b0 = *reinterpret_cast<const ushort4*>(s1);
            ushort4 b1 = *reinterpret_cast<const ushort4*>(s1 + 4);
            ushort ra[8] = {a0.x, a0.y, a0.z, a0.w, a1.x, a1.y, a1.z, a1.w};
            ushort rb[8] = {b0.x, b0.y, b0.z, b0.w, b1.x, b1.y, b1.z, b1.w};
#pragma unroll
            for (int kk = 0; kk < 8; kk++) {
                int m = sn8 * 8 + kk;
                uint32_t val = (uint32_t)ra[kk] | ((uint32_t)rb[kk] << 16);
                *reinterpret_cast<uint32_t*>(reinterpret_cast<char*>(lk) + m * ROWB +
                                             ((4 * sr) ^ (16 * (m & 7)))) = val;
            }
        }
        __syncthreads();
        int nA0 = (2 * w) * 16 + lrow;
        int nA1 = nA0 + 16;
        const short8 afr0 = *reinterpret_cast<const short8*>(
            reinterpret_cast<const char*>(lq) + nA0 * ROWB + 16 * (lg ^ (nA0 & 7)));
        const short8 afr1 = *reinterpret_cast<const short8*>(
            reinterpret_cast<const char*>(lq) + nA1 * ROWB + 16 * (lg ^ (nA1 & 7)));
#pragma unroll
        for (int ct = 0; ct < 13; ct++) {
            int m = ct * 16 + lrow;
            const short8 bfr = *reinterpret_cast<const short8*>(
                reinterpret_cast<const char*>(lk) + m * ROWB + 16 * (lg ^ (m & 7)));
            acc[0][ct] = __builtin_amdgcn_mfma_f32_16x16x32_bf16(afr0, bfr, acc[0][ct], 0, 0, 0);
            acc[1][ct] = __builtin_amdgcn_mfma_f32_16x16x32_bf16(afr1, bfr, acc[1][ct], 0, 0, 0);
        }
        __syncthreads();
    }
    float* sp = spart + (size_t)(b * NKS + ks) * NP * MPAD;
#pragma unroll
    for (int i = 0; i < 2; i++) {
        int rt = 2 * w + i;
#pragma unroll
        for (int r = 0; r < 4; r++) {
            int n = rt * 16 + lg * 4 + r;
            if (n < NP) {
#pragma unroll
                for (int ct = 0; ct < 13; ct++)
                    sp[(size_t)n * MPAD + ct * 16 + lrow] = acc[i][ct][r];
            }
        }
    }
}

// ---------------- 4b. reduce + row softmax -> wHat[b][i][j] bf16 ----------------
__global__ void k_softmax(const float* __restrict__ spart, __hip_bfloat16* __restrict__ wh) {
    int blk = blockIdx.x;        // BB*196
    int n = blk % NP;            // query row
    int b = blk / NP;
    int m = threadIdx.x;         // key col
    float val = -1e30f;
    if (m < 196) {
        float s = 0.f;
        for (int ks = 0; ks < NKS; ks++)
            s += spart[((size_t)(b * NKS + ks) * NP + n) * MPAD + m];
        val = s * SCALE_P;
    }
    float mx = val;
    for (int o = 32; o; o >>= 1) mx = fmaxf(mx, __shfl_xor(mx, o));
    __shared__ float redm[4], reds[4];
    int wid = threadIdx.x >> 6, lane = threadIdx.x & 63;
    if (lane == 0) redm[wid] = mx;
    __syncthreads();
    mx = fmaxf(fmaxf(redm[0], redm[1]), fmaxf(redm[2], redm[3]));
    float p = (m < 196) ? __expf(val - mx) : 0.f;
    float sm = p;
    for (int o = 32; o; o >>= 1) sm += __shfl_xor(sm, o);
    if (lane == 0) reds[wid] = sm;
    __syncthreads();
    sm = reds[0] + reds[1] + reds[2] + reds[3];
    if (m < WCOLS)
        wh[((size_t)b * WROWS + n) * WCOLS + m] =
            __float2bfloat16((m < 196) ? p / sm : 0.f);
}

// ---------------- 5a. global pooled attention: split-K partials ----------------
// 2 queries/thread; launch_bounds(256,2): ~150 VGPR live, must NOT spill.
__global__ __launch_bounds__(256, 2)
void k_gattn_part(const float* __restrict__ qg, const float* __restrict__ kg,
                  const float* __restrict__ vg, float* __restrict__ pacc,
                  float* __restrict__ pl) {
    __shared__ __align__(16) float ksh[KPB * 28];
    __shared__ __align__(16) float vsh[KPB * 28];
    int blk = blockIdx.x;            // 4b * 7qblk * 32ks = 896
    int ks = blk & 31;
    int t2 = blk >> 5;
    int qblk = t2 % NQBLK;
    int b = t2 / NQBLK;

    for (int idx = threadIdx.x; idx < KPB * 28; idx += 256) {
        int r = idx / 28, c = idx - (idx / 28) * 28;
        int g = ks * KPB + r;
        float kvv = 0.f, vvv = 0.f;
        if (c < 27) {
            kvv = kg[((size_t)b * GG + g) * 27 + c];
            vvv = vg[((size_t)b * GG + g) * 27 + c];
        }
        ksh[idx] = kvv; vsh[idx] = vvv;
    }
    __syncthreads();

    float q[2][28], acc[2][28];
    int qbase = qblk * 512 + threadIdx.x;
#pragma unroll
    for (int qq = 0; qq < 2; qq++) {
#pragma unroll
        for (int c = 0; c < 28; c++) { q[qq][c] = 0.f; acc[qq][c] = 0.f; }
        int qi = qbase + qq * 256;
        if (qi < GG) {
            const float* qr = qg + ((size_t)b * GG + qi) * 27;
#pragma unroll
            for (int c = 0; c < 27; c++) q[qq][c] = qr[c];
        }
    }
    float l0 = 0.f, l1 = 0.f;

    for (int j = 0; j < KPB; j++) {
        const float4* kr = reinterpret_cast<const float4*>(ksh + j * 28);
        float s0 = 0.f, s1 = 0.f;
#pragma unroll
        for (int t = 0; t < 7; t++) {
            float4 kk = kr[t];
            s0 += q[0][4*t]*kk.x + q[0][4*t+1]*kk.y + q[0][4*t+2]*kk.z + q[0][4*t+3]*kk.w;
            s1 += q[1][4*t]*kk.x + q[1][4*t+1]*kk.y + q[1][4*t+2]*kk.z + q[1][4*t+3]*kk.w;
        }
        float p0 = __expf(s0 * SCALE_G);
        float p1 = __expf(s1 * SCALE_G);
        l0 += p0; l1 += p1;
        const float4* vr = reinterpret_cast<const float4*>(vsh + j * 28);
#pragma unroll
        for (int t = 0; t < 7; t++) {
            float4 vv = vr[t];
            acc[0][4*t] += p0*vv.x; acc[0][4*t+1] += p0*vv.y; acc[0][4*t+2] += p0*vv.z; acc[0][4*t+3] += p0*vv.w;
            acc[1][4*t] += p1*vv.x; acc[1][4*t+1] += p1*vv.y; acc[1][4*t+2] += p1*vv.z; acc[1][4*t+3] += p1*vv.w;
        }
    }

    float lv[2] = {l0, l1};
#pragma unroll
    for (int qq = 0; qq < 2; qq++) {
        int qi = qbase + qq * 256;
        if (qi < GG) {
            size_t base = ((size_t)(b * KSPLIT + ks) * GG + qi);
            pl[base] = lv[qq];
            float* pa = pacc + base * 27;
#pragma unroll
            for (int c = 0; c < 27; c++) pa[c] = acc[qq][c];
        }
    }
}

// ---------------- 5b. combine split-K partials ----------------
__global__ void k_gattn_reduce(const float* __restrict__ pacc, const float* __restrict__ pl,
                               float* __restrict__ hg) {
    int t = blockIdx.x * 256 + threadIdx.x;   // < BB*GG*27 = 338688
    if (t >= BB * GG * 27) return;
    int c = t % 27;
    int g = (t / 27) % GG;
    int b = t / (27 * GG);
    float l = 0.f, a = 0.f;
#pragma unroll
    for (int ks = 0; ks < KSPLIT; ks++) {
        size_t base = ((size_t)(b * KSPLIT + ks) * GG + g);
        l += pl[base];
        a += pacc[base * 27 + c];
    }
    hg[((size_t)b * GG + g) * 27 + c] = a / l;
}

// ---------------- 6. h_patch GEMM via MFMA, fused blend + residual -> out ----------------
// hp'[d][i] = sum_j V'[d][j] W[i][j] (V' pre-projected)
// out[c][hw] = x[c][hw] + 0.75*hp'[c][hw] + 0.25*hg'[g(hw)][c]
__global__ __launch_bounds__(256, 1)
void k_hp_fused(const __hip_bfloat16* __restrict__ v, const __hip_bfloat16* __restrict__ wh,
                const float* __restrict__ x, const float* __restrict__ hg,
                float* __restrict__ out) {
    int blk = blockIdx.x;              // BB * 432
    int b = blk / 432;
    int grp = blk % 432;
    int w = threadIdx.x >> 6, l = threadIdx.x & 63;
    int ar = l & 15;                   // A row within tile / B col
    int kg = l >> 4;                   // k-group
    int D0 = (grp * 4 + w) * 16;       // d-tile base

    const ushort* vb = (const ushort*)v + (size_t)b * CHW;
    const ushort* wb = (const ushort*)wh + (size_t)b * WROWS * WCOLS;

    f32x4 acc[13];
#pragma unroll
    for (int ct = 0; ct < 13; ct++) acc[ct] = (f32x4){0.f, 0.f, 0.f, 0.f};

    const ushort* arow = vb + (size_t)(D0 + ar) * NP;
#pragma unroll 1
    for (int step = 0; step < 7; ++step) {
        int joff = step * 32 + kg * 8;
        ushort4 alo = *reinterpret_cast<const ushort4*>(arow + joff);
        ushort4 ahi = *reinterpret_cast<const ushort4*>(arow + joff + 4);
        short8 av;
        av[0] = alo.x; av[1] = alo.y; av[2] = alo.z; av[3] = alo.w;
        av[4] = ahi.x; av[5] = ahi.y; av[6] = ahi.z; av[7] = ahi.w;
#pragma unroll
        for (int ct = 0; ct < 13; ct++) {
            int bi = ct * 16 + ar;
            const short8 bv = *reinterpret_cast<const short8*>(wb + (size_t)bi * WCOLS + joff);
            acc[ct] = __builtin_amdgcn_mfma_f32_16x16x32_bf16(av, bv, acc[ct], 0, 0, 0);
        }
    }
    // C: row = kg*4 + r (d within tile), col = ar (i). d = c*1024 + strip.
    const float* xb = x + (size_t)b * CHW;
    float* ob = out + (size_t)b * CHW;
    const float* hgb = hg + (size_t)b * GG * 27;
    int c = D0 >> 10;                  // constant per wave (16 | 1024)
    int strip0 = D0 & 1023;
#pragma unroll
    for (int ct = 0; ct < 13; ct++) {
        int i = ct * 16 + ar;
        if (i < NP) {
#pragma unroll
            for (int r = 0; r < 4; r++) {
                int strip = strip0 + kg * 4 + r;
                int hw = strip * NP + i;
                int h = hw / 448;
                int w2 = hw - h * 448;
                int g = (h >> 3) * 56 + (w2 >> 3);
                size_t addr = (size_t)c * HW + hw;
                ob[addr] = xb[addr] + 0.75f * acc[ct][r] + 0.25f * hgb[g * 27 + c];
            }
        }
    }
}

// ---------------- launch ----------------
extern "C" void kernel_launch(void* const* d_in, const int* in_sizes, int n_in,
                              void* d_out, int out_size, void* d_ws, size_t ws_size,
                              hipStream_t stream) {
    const float* x    = (const float*)d_in[0];
    const float* gnw  = (const float*)d_in[1];
    const float* gnb  = (const float*)d_in[2];
    const float* qw   = (const float*)d_in[3];
    const float* qb   = (const float*)d_in[4];
    const float* kw   = (const float*)d_in[5];
    const float* kb   = (const float*)d_in[6];
    const float* vw   = (const float*)d_in[7];
    const float* vb   = (const float*)d_in[8];
    const float* pjw  = (const float*)d_in[9];
    float* out = (float*)d_out;

    char* ws = (char*)d_ws;
    size_t off = 0;
    auto alloc = [&](size_t bytes) { void* p = ws + off; off += (bytes + 255) & ~(size_t)255; return p; };
    // qkv: contiguous [3][BB][27][HW] bf16 + 64B zero tail (k_hp_fused overread)
    __hip_bfloat16* qkvbuf = (__hip_bfloat16*)alloc((size_t)3 * BB * CHW * 2 + 64);
    __hip_bfloat16* qbf = qkvbuf;
    __hip_bfloat16* kbf = qkvbuf + (size_t)BB * CHW;
    __hip_bfloat16* vbf = qkvbuf + (size_t)2 * BB * CHW;
    // shared region, disjoint lifetimes (stream-ordered): spart partials -> gattn pacc
    size_t shared_elems = (size_t)BB * KSPLIT * GG * 27;
    float* shbuf = (float*)alloc(shared_elems * 4);
    float* spart = shbuf;
    float* pacc  = shbuf;
    __hip_bfloat16* wHat = (__hip_bfloat16*)alloc((size_t)BB * WROWS * WCOLS * 2);
    float* qg    = (float*)alloc((size_t)BB * GG * 27 * 4);
    float* kg    = (float*)alloc((size_t)BB * GG * 27 * 4);
    float* vg    = (float*)alloc((size_t)BB * GG * 27 * 4);
    float* hg    = (float*)alloc((size_t)BB * GG * 27 * 4);
    float* part  = (float*)alloc((size_t)BB * 1024 * 2 * 4);
    float* stats = (float*)alloc((size_t)BB * 2 * 4);
    float* pl    = (float*)alloc((size_t)BB * KSPLIT * GG * 4);
    float* pvw   = (float*)alloc(729 * 4);
    float* pvb   = (float*)alloc(27 * 4);

    (void)hipMemsetAsync((char*)qkvbuf + (size_t)3 * BB * CHW * 2, 0, 64, stream);
    k_fold<<<1, 256, 0, stream>>>(pjw, vw, vb, pvw, pvb);
    k_gn_partial<<<BB * 1024, 256, 0, stream>>>(x, part);
    k_gn_final<<<BB, 256, 0, stream>>>(part, stats);
    k_qkv_mfma<<<(BB * HW) / 256, 256, 0, stream>>>(x, stats, qw, qb, kw, kb, pvw, pvb,
                                                    gnw, gnb, qkvbuf);
    k_pool<<<(BB * 27 * GG) / 256, 256, 0, stream>>>(qbf, qg);
    k_pool<<<(BB * 27 * GG) / 256, 256, 0, stream>>>(kbf, kg);
    k_pool<<<(BB * 27 * GG) / 256, 256, 0, stream>>>(vbf, vg);
    k_spart_mfma<<<BB * NKS, 448, 0, stream>>>(qbf, kbf, spart);
    k_softmax<<<BB * NP, 256, 0, stream>>>(spart, wHat);
    k_gattn_part<<<BB * NQBLK * KSPLIT, 256, 0, stream>>>(qg, kg, vg, pacc, pl);
    k_gattn_reduce<<<(BB * GG * 27 + 255) / 256, 256, 0, stream>>>(pacc, pl, hg);
    k_hp_fused<<<BB * 432, 256, 0, stream>>>(vbf, wHat, x, hg, out);
}

// Round 10
// 333.406 us; speedup vs baseline: 2.8180x; 1.1874x over previous
//
#include <hip/hip_runtime.h>
#include <hip/hip_bf16.h>
#include <cstdint>

// ---------------- problem constants ----------------
namespace {
constexpr int BB = 4;
constexpr int CC = 27;
constexpr int HW = 448 * 448;                 // 200704
constexpr long long CHW = (long long)CC * HW; // 5419008
constexpr int NP = 196;                        // patch positions
constexpr int GG = 56 * 56;                    // 3136 pooled positions
constexpr int DTOT = CC * 1024;                // 27648
constexpr float SCALE_P = 0.0060140449f;       // 1/sqrt(27648)
constexpr float SCALE_G = 0.1924500897f;       // 1/sqrt(27)
constexpr float EPSV = 1e-5f;
// MFMA spart config
constexpr int KCH = 512;                       // d-chunk per block
constexpr int NKS = DTOT / KCH;                // 54 partials
constexpr int MPAD = 224;                      // padded n/m (14 tiles of 16)
constexpr int ROWB = 128;                      // LDS bytes per row
// wHat (softmax weights, bf16, [i][j]) padding
constexpr int WROWS = 208;                     // 13 tiles of 16
constexpr int WCOLS = 224;                     // 7 k-steps of 32
// qkv-MFMA config
constexpr int XST = 40;                        // LDS row stride (shorts)
// flash gattn config
constexpr int GKC = 224;                       // keys per chunk (14 chunks)
constexpr int KST = 40;                        // ks row stride (shorts)
constexpr int VST = 232;                       // vs/ps row stride (shorts)
}

typedef __attribute__((ext_vector_type(8))) short short8;
typedef __attribute__((ext_vector_type(4))) float f32x4;

__device__ __forceinline__ float bf2f(unsigned short u) {
    return __uint_as_float(((uint32_t)u) << 16);
}

__device__ __forceinline__ ushort f2bf(float f) {
    union { __hip_bfloat16 h; ushort u; } cv;
    cv.h = __float2bfloat16(f);
    return cv.u;
}

// ---------------- 0. fold proj into V weights: pvw = proj*vw, pvb = proj*vb ----------------
__global__ void k_fold(const float* __restrict__ pjw, const float* __restrict__ vw,
                       const float* __restrict__ vb, float* __restrict__ pvw,
                       float* __restrict__ pvb) {
    __shared__ float pj[729], vv[729], vbs[27];
    int t = threadIdx.x;
    for (int i = t; i < 729; i += 256) { pj[i] = pjw[i]; vv[i] = vw[i]; }
    if (t < 27) vbs[t] = vb[t];
    __syncthreads();
    for (int i = t; i < 729; i += 256) {
        int o = i / 27, c2 = i - (i / 27) * 27;
        float s = 0.f;
#pragma unroll
        for (int c = 0; c < 27; c++) s += pj[o * 27 + c] * vv[c * 27 + c2];
        pvw[i] = s;
    }
    if (t < 27) {
        float s = 0.f;
#pragma unroll
        for (int c = 0; c < 27; c++) s += pj[t * 27 + c] * vbs[c];
        pvb[t] = s;
    }
}

// ---------------- 1. GroupNorm stats ----------------
__global__ void k_gn_partial(const float* __restrict__ x, float* __restrict__ part) {
    int blk = blockIdx.x;          // BB*1024 blocks
    int b = blk >> 10;
    int chunk = blk & 1023;
    const int CLEN = (int)(CHW / 1024);   // 5292
    const float* p = x + (size_t)b * CHW + (size_t)chunk * CLEN;
    float s = 0.f, ss = 0.f;
    for (int i = threadIdx.x; i < CLEN; i += 256) {
        float v = p[i];
        s += v; ss += v * v;
    }
    for (int o = 32; o; o >>= 1) { s += __shfl_down(s, o); ss += __shfl_down(ss, o); }
    __shared__ float ls[4], lss[4];
    int wid = threadIdx.x >> 6, lane = threadIdx.x & 63;
    if (lane == 0) { ls[wid] = s; lss[wid] = ss; }
    __syncthreads();
    if (threadIdx.x == 0) {
        float S = ls[0] + ls[1] + ls[2] + ls[3];
        float SS = lss[0] + lss[1] + lss[2] + lss[3];
        part[blk * 2] = S; part[blk * 2 + 1] = SS;
    }
}

__global__ void k_gn_final(const float* __restrict__ part, float* __restrict__ stats) {
    int b = blockIdx.x;
    float s = 0.f, ss = 0.f;
    for (int i = threadIdx.x; i < 1024; i += 256) {
        s += part[(b * 1024 + i) * 2];
        ss += part[(b * 1024 + i) * 2 + 1];
    }
    for (int o = 32; o; o >>= 1) { s += __shfl_down(s, o); ss += __shfl_down(ss, o); }
    __shared__ float ls[4], lss[4];
    int wid = threadIdx.x >> 6, lane = threadIdx.x & 63;
    if (lane == 0) { ls[wid] = s; lss[wid] = ss; }
    __syncthreads();
    if (threadIdx.x == 0) {
        float S = ls[0] + ls[1] + ls[2] + ls[3];
        float SS = lss[0] + lss[1] + lss[2] + lss[3];
        float mean = S / (float)CHW;
        float var = SS / (float)CHW - mean * mean;
        stats[b * 2] = mean;
        stats[b * 2 + 1] = rsqrtf(var + EPSV);
    }
}

// ---------------- 2. GN-apply + QKV conv1x1 via MFMA (-> bf16) ----------------
__global__ __launch_bounds__(256, 2)
void k_qkv_mfma(const float* __restrict__ x, const float* __restrict__ stats,
                const float* __restrict__ qw, const float* __restrict__ qb,
                const float* __restrict__ kw, const float* __restrict__ kb,
                const float* __restrict__ vw, const float* __restrict__ vb,
                const float* __restrict__ gnw, const float* __restrict__ gnb,
                __hip_bfloat16* __restrict__ qkv) {
    __shared__ ushort xs[256 * XST];            // 20480 B
    __shared__ ushort wls[96 * XST];            // 7680 B
    __shared__ __align__(16) float bls[96];
    __shared__ float gwls[27], gbls[27];

    int tid = threadIdx.x;
    int P0 = blockIdx.x * 256;                  // global pixel base
    int b = P0 / HW;                            // HW % 256 == 0: no straddle
    int hw0 = P0 - b * HW;

    for (int i = tid; i < 96 * 32; i += 256) {
        int row = i >> 5, c = i & 31;
        float wv = 0.f;
        if (c < 27 && row < 81) {
            int t = (row >= 54) ? 2 : (row >= 27 ? 1 : 0);
            int oc = row - t * 27;
            const float* wp = (t == 0) ? qw : (t == 1) ? kw : vw;
            wv = wp[oc * 27 + c];
        }
        wls[row * XST + c] = f2bf(wv);
    }
    if (tid < 96) {
        float bv = 0.f;
        if (tid < 27) bv = qb[tid];
        else if (tid < 54) bv = kb[tid - 27];
        else if (tid < 81) bv = vb[tid - 54];
        bls[tid] = bv;
    }
    if (tid < 27) { gwls[tid] = gnw[tid]; gbls[tid] = gnb[tid]; }
    float mean = stats[b * 2], rstd = stats[b * 2 + 1];
    __syncthreads();

    {
        const float* xp = x + (size_t)b * CHW + hw0 + tid;
        ushort xv[28];
#pragma unroll
        for (int c = 0; c < 27; c++) {
            float v = (xp[(size_t)c * HW] - mean) * rstd * gwls[c] + gbls[c];
            xv[c] = f2bf(v);
        }
        xv[27] = 0;
        uint32_t* xrow = reinterpret_cast<uint32_t*>(&xs[tid * XST]);
#pragma unroll
        for (int i = 0; i < 14; i++)
            xrow[i] = (uint32_t)xv[2 * i] | ((uint32_t)xv[2 * i + 1] << 16);
        xrow[14] = 0; xrow[15] = 0;
    }
    __syncthreads();

    int w = tid >> 6, l = tid & 63;
    int lrow = l & 15, kg = l >> 4;

    short8 afr[6];
    f32x4 binit[6];
#pragma unroll
    for (int mt = 0; mt < 6; mt++) {
        afr[mt] = *reinterpret_cast<const short8*>(&wls[(mt * 16 + lrow) * XST + kg * 8]);
        binit[mt] = *reinterpret_cast<const f32x4*>(&bls[mt * 16 + kg * 4]);
    }

    f32x4 acc[4][6];
#pragma unroll
    for (int pt = 0; pt < 4; pt++) {
        const short8 bfr = *reinterpret_cast<const short8*>(
            &xs[(w * 64 + pt * 16 + lrow) * XST + kg * 8]);
#pragma unroll
        for (int mt = 0; mt < 6; mt++)
            acc[pt][mt] = __builtin_amdgcn_mfma_f32_16x16x32_bf16(afr[mt], bfr, binit[mt], 0, 0, 0);
    }

    ushort* ob = (ushort*)qkv;
#pragma unroll
    for (int pt = 0; pt < 4; pt++) {
        int hw = hw0 + w * 64 + pt * 16 + lrow;
#pragma unroll
        for (int mt = 0; mt < 6; mt++) {
#pragma unroll
            for (int r = 0; r < 4; r++) {
                int o = mt * 16 + kg * 4 + r;
                if (o < 81) {
                    int t = (o >= 54) ? 2 : (o >= 27 ? 1 : 0);
                    int oc = o - t * 27;
                    ob[((size_t)t * BB + b) * CHW + (size_t)oc * HW + hw] = f2bf(acc[pt][mt][r]);
                }
            }
        }
    }
}

// ---------------- 3. 8x8 avg pool -> transposed [b][g][27] ----------------
__global__ void k_pool(const __hip_bfloat16* __restrict__ src, float* __restrict__ dst) {
    int idx = blockIdx.x * 256 + threadIdx.x;  // < 4*27*3136 = 338688
    int g = idx % GG;
    int t = idx / GG;
    int c = t % 27;
    int b = t / 27;
    int gh = g / 56, gw = g - (g / 56) * 56;
    const ushort* sp = (const ushort*)src + (size_t)(b * 27 + c) * HW + (size_t)(gh * 8) * 448 + gw * 8;
    float s = 0.f;
#pragma unroll
    for (int r = 0; r < 8; r++) {
        const ushort4 a = *reinterpret_cast<const ushort4*>(sp + r * 448);
        const ushort4 d = *reinterpret_cast<const ushort4*>(sp + r * 448 + 4);
        s += bf2f(a.x) + bf2f(a.y) + bf2f(a.z) + bf2f(a.w)
           + bf2f(d.x) + bf2f(d.y) + bf2f(d.z) + bf2f(d.w);
    }
    dst[((size_t)b * GG + g) * 27 + c] = s * (1.f / 64.f);
}

// ---------------- 4a. patch attention S partials via MFMA ----------------
__global__ __launch_bounds__(448, 1)
void k_spart_mfma(const __hip_bfloat16* __restrict__ q, const __hip_bfloat16* __restrict__ k,
                  float* __restrict__ spart) {
    __shared__ ushort lq[MPAD * 64];   // 28672 B
    __shared__ ushort lk[MPAD * 64];
    int blk = blockIdx.x;              // 4b * 54ks = 216
    int ks = blk % NKS;
    int b = blk / NKS;
    const ushort* qb_ = (const ushort*)q + (size_t)b * CHW;
    const ushort* kb_ = (const ushort*)k + (size_t)b * CHW;
    int t = threadIdx.x;
    int w = t >> 6, l = t & 63;
    int lrow = l & 15, lg = l >> 4;    // fragment coords
    int sr = t & 15;                   // d-pair index 0..15 (d = 2sr, 2sr+1)
    int sn8 = t >> 4;                  // col-chunk 0..27 (cols sn8*8..+8)

    f32x4 acc[2][13];
#pragma unroll
    for (int i = 0; i < 2; i++)
#pragma unroll
        for (int ct = 0; ct < 13; ct++) acc[i][ct] = (f32x4){0.f, 0.f, 0.f, 0.f};

    int d0 = ks * KCH;
    for (int step = 0; step < KCH / 32; ++step) {
        int dbase = d0 + step * 32;
        {
            const ushort* s0 = qb_ + (size_t)(dbase + 2 * sr) * NP + sn8 * 8;
            const ushort* s1 = s0 + NP;
            ushort4 a0 = *reinterpret_cast<const ushort4*>(s0);
            ushort4 a1 = *reinterpret_cast<const ushort4*>(s0 + 4);
            ushort4 b0 = *reinterpret_cast<const ushort4*>(s1);
            ushort4 b1 = *reinterpret_cast<const ushort4*>(s1 + 4);
            ushort ra[8] = {a0.x, a0.y, a0.z, a0.w, a1.x, a1.y, a1.z, a1.w};
            ushort rb[8] = {b0.x, b0.y, b0.z, b0.w, b1.x, b1.y, b1.z, b1.w};
#pragma unroll
            for (int kk = 0; kk < 8; kk++) {
                int n = sn8 * 8 + kk;
                uint32_t val = (uint32_t)ra[kk] | ((uint32_t)rb[kk] << 16);
                *reinterpret_cast<uint32_t*>(reinterpret_cast<char*>(lq) + n * ROWB +
                                             ((4 * sr) ^ (16 * (n & 7)))) = val;
            }
        }
        {
            const ushort* s0 = kb_ + (size_t)(dbase + 2 * sr) * NP + sn8 * 8;
            const ushort* s1 = s0 + NP;
            ushort4 a0 = *reinterpret_cast<const ushort4*>(s0);
            ushort4 a1 = *reinterpret_cast<const ushort4*>(s0 + 4);
            ushort4 b0 = *reinterpret_cast<const ushort4*>(s1);
            ushort4 b1 = *reinterpret_cast<const ushort4*>(s1 + 4);
            ushort ra[8] = {a0.x, a0.y, a0.z, a0.w, a1.x, a1.y, a1.z, a1.w};
            ushort rb[8] = {b0.x, b0.y, b0.z, b0.w, b1.x, b1.y, b1.z, b1.w};
#pragma unroll
            for (int kk = 0; kk < 8; kk++) {
                int m = sn8 * 8 + kk;
                uint32_t val = (uint32_t)ra[kk] | ((uint32_t)rb[kk] << 16);
                *reinterpret_cast<uint32_t*>(reinterpret_cast<char*>(lk) + m * ROWB +
                                             ((4 * sr) ^ (16 * (m & 7)))) = val;
            }
        }
        __syncthreads();
        int nA0 = (2 * w) * 16 + lrow;
        int nA1 = nA0 + 16;
        const short8 afr0 = *reinterpret_cast<const short8*>(
            reinterpret_cast<const char*>(lq) + nA0 * ROWB + 16 * (lg ^ (nA0 & 7)));
        const short8 afr1 = *reinterpret_cast<const short8*>(
            reinterpret_cast<const char*>(lq) + nA1 * ROWB + 16 * (lg ^ (nA1 & 7)));
#pragma unroll
        for (int ct = 0; ct < 13; ct++) {
            int m = ct * 16 + lrow;
            const short8 bfr = *reinterpret_cast<const short8*>(
                reinterpret_cast<const char*>(lk) + m * ROWB + 16 * (lg ^ (m & 7)));
            acc[0][ct] = __builtin_amdgcn_mfma_f32_16x16x32_bf16(afr0, bfr, acc[0][ct], 0, 0, 0);
            acc[1][ct] = __builtin_amdgcn_mfma_f32_16x16x32_bf16(afr1, bfr, acc[1][ct], 0, 0, 0);
        }
        __syncthreads();
    }
    float* sp = spart + (size_t)(b * NKS + ks) * NP * MPAD;
#pragma unroll
    for (int i = 0; i < 2; i++) {
        int rt = 2 * w + i;
#pragma unroll
        for (int r = 0; r < 4; r++) {
            int n = rt * 16 + lg * 4 + r;
            if (n < NP) {
#pragma unroll
                for (int ct = 0; ct < 13; ct++)
                    sp[(size_t)n * MPAD + ct * 16 + lrow] = acc[i][ct][r];
            }
        }
    }
}

// ---------------- 4b. reduce + row softmax -> wHat[b][i][j] bf16 ----------------
__global__ void k_softmax(const float* __restrict__ spart, __hip_bfloat16* __restrict__ wh) {
    int blk = blockIdx.x;        // BB*196
    int n = blk % NP;            // query row
    int b = blk / NP;
    int m = threadIdx.x;         // key col
    float val = -1e30f;
    if (m < 196) {
        float s = 0.f;
        for (int ks = 0; ks < NKS; ks++)
            s += spart[((size_t)(b * NKS + ks) * NP + n) * MPAD + m];
        val = s * SCALE_P;
    }
    float mx = val;
    for (int o = 32; o; o >>= 1) mx = fmaxf(mx, __shfl_xor(mx, o));
    __shared__ float redm[4], reds[4];
    int wid = threadIdx.x >> 6, lane = threadIdx.x & 63;
    if (lane == 0) redm[wid] = mx;
    __syncthreads();
    mx = fmaxf(fmaxf(redm[0], redm[1]), fmaxf(redm[2], redm[3]));
    float p = (m < 196) ? __expf(val - mx) : 0.f;
    float sm = p;
    for (int o = 32; o; o >>= 1) sm += __shfl_xor(sm, o);
    if (lane == 0) reds[wid] = sm;
    __syncthreads();
    sm = reds[0] + reds[1] + reds[2] + reds[3];
    if (m < WCOLS)
        wh[((size_t)b * WROWS + n) * WCOLS + m] =
            __float2bfloat16((m < 196) ? p / sm : 0.f);
}

// ---------------- 5. global pooled attention: flash MFMA ----------------
// Block = 4 waves = 64 queries. 14 chunks x 224 keys over 3136.
// S = mfma(Qfrag, Kfrag) (K-dim 32, d27 zero-pad); P = exp(S*scale) bf16 -> LDS;
// H = mfma(P, V^T) accumulated. V^T row d=27 is ones => H col 27 = sum(P) = l.
__global__ __launch_bounds__(256)
void k_gattn_flash(const float* __restrict__ qg, const float* __restrict__ kg,
                   const float* __restrict__ vg, float* __restrict__ hg) {
    __shared__ __align__(16) ushort ksh[GKC * KST];    // [k][d] 17920 B
    __shared__ __align__(16) ushort vsh[32 * VST];     // [d][k] 14848 B
    __shared__ __align__(16) ushort psh[4][16 * VST];  // per-wave P [q][k] 29696 B

    int blk = blockIdx.x;              // BB * 49
    int b = blk / 49;
    int q0 = (blk % 49) * 64;
    int tid = threadIdx.x;
    int w = tid >> 6, l = tid & 63;
    int lr = l & 15, lg = l >> 4;

    // one-time pads: ks cols 27..31 zero; vs rows: 27 = ones, 28..31 = zero
    for (int i = tid; i < GKC; i += 256) {
        ushort* kr = &ksh[i * KST];
        kr[27] = 0; kr[28] = 0; kr[29] = 0; kr[30] = 0; kr[31] = 0;
        vsh[27 * VST + i] = 0x3f80;    // bf16 1.0
        vsh[28 * VST + i] = 0; vsh[29 * VST + i] = 0;
        vsh[30 * VST + i] = 0; vsh[31 * VST + i] = 0;
    }

    // Q fragment from global (held all kernel): rows q = q0 + w*16 + lr
    short8 aq;
    {
        const float* qr = qg + ((size_t)b * GG + q0 + w * 16 + lr) * 27;
#pragma unroll
        for (int j = 0; j < 8; j++) {
            int c = 8 * lg + j;
            aq[j] = (c < 27) ? (short)f2bf(qr[c]) : (short)0;
        }
    }

    f32x4 acc_h0 = {0.f, 0.f, 0.f, 0.f};
    f32x4 acc_h1 = {0.f, 0.f, 0.f, 0.f};
    ushort* myps = &psh[w][0];
    const float* kgb = kg + (size_t)b * GG * 27;
    const float* vgb = vg + (size_t)b * GG * 27;

    for (int ch = 0; ch < 14; ch++) {
        __syncthreads();               // prev chunk's PV reads done
        // stage K [k][d] and V^T [d][k] (bf16), coalesced global reads
        int base = ch * GKC * 27;
        for (int idx = tid; idx < GKC * 27; idx += 256) {
            int kk = idx / 27, c = idx - (idx / 27) * 27;
            ksh[kk * KST + c] = f2bf(kgb[base + idx]);
            vsh[c * VST + kk] = f2bf(vgb[base + idx]);
        }
        __syncthreads();

        // S = Q K^T : 14 n-tiles of 16 keys
        f32x4 s[14];
#pragma unroll
        for (int ct = 0; ct < 14; ct++) {
            const short8 bk = *reinterpret_cast<const short8*>(
                &ksh[(ct * 16 + lr) * KST + 8 * lg]);
            s[ct] = __builtin_amdgcn_mfma_f32_16x16x32_bf16(
                aq, bk, (f32x4){0.f, 0.f, 0.f, 0.f}, 0, 0, 0);
        }
        // P = exp(S*scale) -> per-wave LDS [16 q][224 k] bf16
#pragma unroll
        for (int ct = 0; ct < 14; ct++) {
#pragma unroll
            for (int r = 0; r < 4; r++) {
                float p = __expf(s[ct][r] * SCALE_G);
                myps[(4 * lg + r) * VST + ct * 16 + lr] = f2bf(p);
            }
        }
        // H += P V : K = 224 in 7 steps of 32; 2 d-tiles
#pragma unroll
        for (int kstep = 0; kstep < 7; kstep++) {
            const short8 ap = *reinterpret_cast<const short8*>(
                &myps[lr * VST + kstep * 32 + 8 * lg]);
            const short8 bv0 = *reinterpret_cast<const short8*>(
                &vsh[lr * VST + kstep * 32 + 8 * lg]);
            const short8 bv1 = *reinterpret_cast<const short8*>(
                &vsh[(16 + lr) * VST + kstep * 32 + 8 * lg]);
            acc_h0 = __builtin_amdgcn_mfma_f32_16x16x32_bf16(ap, bv0, acc_h0, 0, 0, 0);
            acc_h1 = __builtin_amdgcn_mfma_f32_16x16x32_bf16(ap, bv1, acc_h1, 0, 0, 0);
        }
    }

    // epilogue: rows q = 4*lg + r (local), l = H col 27 = dtile1 col 11
#pragma unroll
    for (int r = 0; r < 4; r++) {
        float lsum = __shfl(acc_h1[r], (l & 48) | 11, 64);
        float inv = 1.f / lsum;
        int q = q0 + w * 16 + 4 * lg + r;
        float* hr = hg + ((size_t)b * GG + q) * 27;
        hr[lr] = acc_h0[r] * inv;
        if (lr < 11) hr[16 + lr] = acc_h1[r] * inv;
    }
}

// ---------------- 6. h_patch GEMM via MFMA, fused blend + residual -> out ----------------
__global__ __launch_bounds__(256, 1)
void k_hp_fused(const __hip_bfloat16* __restrict__ v, const __hip_bfloat16* __restrict__ wh,
                const float* __restrict__ x, const float* __restrict__ hg,
                float* __restrict__ out) {
    int blk = blockIdx.x;              // BB * 432
    int b = blk / 432;
    int grp = blk % 432;
    int w = threadIdx.x >> 6, l = threadIdx.x & 63;
    int ar = l & 15;                   // A row within tile / B col
    int kg = l >> 4;                   // k-group
    int D0 = (grp * 4 + w) * 16;       // d-tile base

    const ushort* vb = (const ushort*)v + (size_t)b * CHW;
    const ushort* wb = (const ushort*)wh + (size_t)b * WROWS * WCOLS;

    f32x4 acc[13];
#pragma unroll
    for (int ct = 0; ct < 13; ct++) acc[ct] = (f32x4){0.f, 0.f, 0.f, 0.f};

    const ushort* arow = vb + (size_t)(D0 + ar) * NP;
#pragma unroll 1
    for (int step = 0; step < 7; ++step) {
        int joff = step * 32 + kg * 8;
        ushort4 alo = *reinterpret_cast<const ushort4*>(arow + joff);
        ushort4 ahi = *reinterpret_cast<const ushort4*>(arow + joff + 4);
        short8 av;
        av[0] = alo.x; av[1] = alo.y; av[2] = alo.z; av[3] = alo.w;
        av[4] = ahi.x; av[5] = ahi.y; av[6] = ahi.z; av[7] = ahi.w;
#pragma unroll
        for (int ct = 0; ct < 13; ct++) {
            int bi = ct * 16 + ar;
            const short8 bv = *reinterpret_cast<const short8*>(wb + (size_t)bi * WCOLS + joff);
            acc[ct] = __builtin_amdgcn_mfma_f32_16x16x32_bf16(av, bv, acc[ct], 0, 0, 0);
        }
    }
    const float* xb = x + (size_t)b * CHW;
    float* ob = out + (size_t)b * CHW;
    const float* hgb = hg + (size_t)b * GG * 27;
    int c = D0 >> 10;
    int strip0 = D0 & 1023;
#pragma unroll
    for (int ct = 0; ct < 13; ct++) {
        int i = ct * 16 + ar;
        if (i < NP) {
#pragma unroll
            for (int r = 0; r < 4; r++) {
                int strip = strip0 + kg * 4 + r;
                int hw = strip * NP + i;
                int h = hw / 448;
                int w2 = hw - h * 448;
                int g = (h >> 3) * 56 + (w2 >> 3);
                size_t addr = (size_t)c * HW + hw;
                ob[addr] = xb[addr] + 0.75f * acc[ct][r] + 0.25f * hgb[g * 27 + c];
            }
        }
    }
}

// ---------------- launch ----------------
extern "C" void kernel_launch(void* const* d_in, const int* in_sizes, int n_in,
                              void* d_out, int out_size, void* d_ws, size_t ws_size,
                              hipStream_t stream) {
    const float* x    = (const float*)d_in[0];
    const float* gnw  = (const float*)d_in[1];
    const float* gnb  = (const float*)d_in[2];
    const float* qw   = (const float*)d_in[3];
    const float* qb   = (const float*)d_in[4];
    const float* kw   = (const float*)d_in[5];
    const float* kb   = (const float*)d_in[6];
    const float* vw   = (const float*)d_in[7];
    const float* vb   = (const float*)d_in[8];
    const float* pjw  = (const float*)d_in[9];
    float* out = (float*)d_out;

    char* ws = (char*)d_ws;
    size_t off = 0;
    auto alloc = [&](size_t bytes) { void* p = ws + off; off += (bytes + 255) & ~(size_t)255; return p; };
    // qkv: contiguous [3][BB][27][HW] bf16 + 64B zero tail (k_hp_fused overread)
    __hip_bfloat16* qkvbuf = (__hip_bfloat16*)alloc((size_t)3 * BB * CHW * 2 + 64);
    __hip_bfloat16* qbf = qkvbuf;
    __hip_bfloat16* kbf = qkvbuf + (size_t)BB * CHW;
    __hip_bfloat16* vbf = qkvbuf + (size_t)2 * BB * CHW;
    float* spart = (float*)alloc((size_t)BB * NKS * NP * MPAD * 4);
    __hip_bfloat16* wHat = (__hip_bfloat16*)alloc((size_t)BB * WROWS * WCOLS * 2);
    float* qg    = (float*)alloc((size_t)BB * GG * 27 * 4);
    float* kg    = (float*)alloc((size_t)BB * GG * 27 * 4);
    float* vg    = (float*)alloc((size_t)BB * GG * 27 * 4);
    float* hg    = (float*)alloc((size_t)BB * GG * 27 * 4);
    float* part  = (float*)alloc((size_t)BB * 1024 * 2 * 4);
    float* stats = (float*)alloc((size_t)BB * 2 * 4);
    float* pvw   = (float*)alloc(729 * 4);
    float* pvb   = (float*)alloc(27 * 4);

    (void)hipMemsetAsync((char*)qkvbuf + (size_t)3 * BB * CHW * 2, 0, 64, stream);
    k_fold<<<1, 256, 0, stream>>>(pjw, vw, vb, pvw, pvb);
    k_gn_partial<<<BB * 1024, 256, 0, stream>>>(x, part);
    k_gn_final<<<BB, 256, 0, stream>>>(part, stats);
    k_qkv_mfma<<<(BB * HW) / 256, 256, 0, stream>>>(x, stats, qw, qb, kw, kb, pvw, pvb,
                                                    gnw, gnb, qkvbuf);
    k_pool<<<(BB * 27 * GG) / 256, 256, 0, stream>>>(qbf, qg);
    k_pool<<<(BB * 27 * GG) / 256, 256, 0, stream>>>(kbf, kg);
    k_pool<<<(BB * 27 * GG) / 256, 256, 0, stream>>>(vbf, vg);
    k_spart_mfma<<<BB * NKS, 448, 0, stream>>>(qbf, kbf, spart);
    k_softmax<<<BB * NP, 256, 0, stream>>>(spart, wHat);
    k_gattn_flash<<<BB * 49, 256, 0, stream>>>(qg, kg, vg, hg);
    k_hp_fused<<<BB * 432, 256, 0, stream>>>(vbf, wHat, x, hg, out);
}

// Round 11
// 313.132 us; speedup vs baseline: 3.0005x; 1.0647x over previous
//
#include <hip/hip_runtime.h>
#include <hip/hip_bf16.h>
#include <cstdint>

// ---------------- problem constants ----------------
namespace {
constexpr int BB = 4;
constexpr int CC = 27;
constexpr int HW = 448 * 448;                 // 200704
constexpr long long CHW = (long long)CC * HW; // 5419008
constexpr int NP = 196;                        // patch positions
constexpr int GG = 56 * 56;                    // 3136 pooled positions
constexpr int DTOT = CC * 1024;                // 27648
constexpr float SCALE_P = 0.0060140449f;       // 1/sqrt(27648)
constexpr float SCALE_G = 0.1924500897f;       // 1/sqrt(27)
constexpr float EPSV = 1e-5f;
// MFMA spart config
constexpr int KCH = 512;                       // d-chunk per block
constexpr int NKS = DTOT / KCH;                // 54 partials
constexpr int MPAD = 224;                      // padded n/m (14 tiles of 16)
constexpr int ROWB = 128;                      // LDS bytes per row
// wHat fragment-major: [13 ct][7 step][64 lane][8 elem] bf16 per batch = 46592 elems
constexpr int WFRAG = 13 * 7 * 64 * 8;
// qkv-MFMA config
constexpr int XST = 40;                        // LDS row stride (shorts)
// flash gattn config
constexpr int GKC = 224;                       // keys per chunk (14 chunks)
constexpr int KST = 40;                        // ks row stride (shorts)
constexpr int VST = 232;                       // vs/ps row stride (shorts)
}

typedef __attribute__((ext_vector_type(8))) short short8;
typedef __attribute__((ext_vector_type(4))) float f32x4;

__device__ __forceinline__ float bf2f(unsigned short u) {
    return __uint_as_float(((uint32_t)u) << 16);
}

__device__ __forceinline__ ushort f2bf(float f) {
    union { __hip_bfloat16 h; ushort u; } cv;
    cv.h = __float2bfloat16(f);
    return cv.u;
}

// ---------------- 0. fold proj into V weights: pvw = proj*vw, pvb = proj*vb ----------------
__global__ void k_fold(const float* __restrict__ pjw, const float* __restrict__ vw,
                       const float* __restrict__ vb, float* __restrict__ pvw,
                       float* __restrict__ pvb) {
    __shared__ float pj[729], vv[729], vbs[27];
    int t = threadIdx.x;
    for (int i = t; i < 729; i += 256) { pj[i] = pjw[i]; vv[i] = vw[i]; }
    if (t < 27) vbs[t] = vb[t];
    __syncthreads();
    for (int i = t; i < 729; i += 256) {
        int o = i / 27, c2 = i - (i / 27) * 27;
        float s = 0.f;
#pragma unroll
        for (int c = 0; c < 27; c++) s += pj[o * 27 + c] * vv[c * 27 + c2];
        pvw[i] = s;
    }
    if (t < 27) {
        float s = 0.f;
#pragma unroll
        for (int c = 0; c < 27; c++) s += pj[t * 27 + c] * vbs[c];
        pvb[t] = s;
    }
}

// ---------------- 1. GroupNorm stats ----------------
__global__ void k_gn_partial(const float* __restrict__ x, float* __restrict__ part) {
    int blk = blockIdx.x;          // BB*1024 blocks
    int b = blk >> 10;
    int chunk = blk & 1023;
    const int CLEN = (int)(CHW / 1024);   // 5292
    const float* p = x + (size_t)b * CHW + (size_t)chunk * CLEN;
    float s = 0.f, ss = 0.f;
    for (int i = threadIdx.x; i < CLEN; i += 256) {
        float v = p[i];
        s += v; ss += v * v;
    }
    for (int o = 32; o; o >>= 1) { s += __shfl_down(s, o); ss += __shfl_down(ss, o); }
    __shared__ float ls[4], lss[4];
    int wid = threadIdx.x >> 6, lane = threadIdx.x & 63;
    if (lane == 0) { ls[wid] = s; lss[wid] = ss; }
    __syncthreads();
    if (threadIdx.x == 0) {
        float S = ls[0] + ls[1] + ls[2] + ls[3];
        float SS = lss[0] + lss[1] + lss[2] + lss[3];
        part[blk * 2] = S; part[blk * 2 + 1] = SS;
    }
}

__global__ void k_gn_final(const float* __restrict__ part, float* __restrict__ stats) {
    int b = blockIdx.x;
    float s = 0.f, ss = 0.f;
    for (int i = threadIdx.x; i < 1024; i += 256) {
        s += part[(b * 1024 + i) * 2];
        ss += part[(b * 1024 + i) * 2 + 1];
    }
    for (int o = 32; o; o >>= 1) { s += __shfl_down(s, o); ss += __shfl_down(ss, o); }
    __shared__ float ls[4], lss[4];
    int wid = threadIdx.x >> 6, lane = threadIdx.x & 63;
    if (lane == 0) { ls[wid] = s; lss[wid] = ss; }
    __syncthreads();
    if (threadIdx.x == 0) {
        float S = ls[0] + ls[1] + ls[2] + ls[3];
        float SS = lss[0] + lss[1] + lss[2] + lss[3];
        float mean = S / (float)CHW;
        float var = SS / (float)CHW - mean * mean;
        stats[b * 2] = mean;
        stats[b * 2 + 1] = rsqrtf(var + EPSV);
    }
}

// ---------------- 2. GN-apply + QKV conv1x1 via MFMA (-> bf16) ----------------
__global__ __launch_bounds__(256, 2)
void k_qkv_mfma(const float* __restrict__ x, const float* __restrict__ stats,
                const float* __restrict__ qw, const float* __restrict__ qb,
                const float* __restrict__ kw, const float* __restrict__ kb,
                const float* __restrict__ vw, const float* __restrict__ vb,
                const float* __restrict__ gnw, const float* __restrict__ gnb,
                __hip_bfloat16* __restrict__ qkv) {
    __shared__ ushort xs[256 * XST];            // 20480 B
    __shared__ ushort wls[96 * XST];            // 7680 B
    __shared__ __align__(16) float bls[96];
    __shared__ float gwls[27], gbls[27];

    int tid = threadIdx.x;
    int P0 = blockIdx.x * 256;                  // global pixel base
    int b = P0 / HW;                            // HW % 256 == 0: no straddle
    int hw0 = P0 - b * HW;

    for (int i = tid; i < 96 * 32; i += 256) {
        int row = i >> 5, c = i & 31;
        float wv = 0.f;
        if (c < 27 && row < 81) {
            int t = (row >= 54) ? 2 : (row >= 27 ? 1 : 0);
            int oc = row - t * 27;
            const float* wp = (t == 0) ? qw : (t == 1) ? kw : vw;
            wv = wp[oc * 27 + c];
        }
        wls[row * XST + c] = f2bf(wv);
    }
    if (tid < 96) {
        float bv = 0.f;
        if (tid < 27) bv = qb[tid];
        else if (tid < 54) bv = kb[tid - 27];
        else if (tid < 81) bv = vb[tid - 54];
        bls[tid] = bv;
    }
    if (tid < 27) { gwls[tid] = gnw[tid]; gbls[tid] = gnb[tid]; }
    float mean = stats[b * 2], rstd = stats[b * 2 + 1];
    __syncthreads();

    {
        const float* xp = x + (size_t)b * CHW + hw0 + tid;
        ushort xv[28];
#pragma unroll
        for (int c = 0; c < 27; c++) {
            float v = (xp[(size_t)c * HW] - mean) * rstd * gwls[c] + gbls[c];
            xv[c] = f2bf(v);
        }
        xv[27] = 0;
        uint32_t* xrow = reinterpret_cast<uint32_t*>(&xs[tid * XST]);
#pragma unroll
        for (int i = 0; i < 14; i++)
            xrow[i] = (uint32_t)xv[2 * i] | ((uint32_t)xv[2 * i + 1] << 16);
        xrow[14] = 0; xrow[15] = 0;
    }
    __syncthreads();

    int w = tid >> 6, l = tid & 63;
    int lrow = l & 15, kg = l >> 4;

    short8 afr[6];
    f32x4 binit[6];
#pragma unroll
    for (int mt = 0; mt < 6; mt++) {
        afr[mt] = *reinterpret_cast<const short8*>(&wls[(mt * 16 + lrow) * XST + kg * 8]);
        binit[mt] = *reinterpret_cast<const f32x4*>(&bls[mt * 16 + kg * 4]);
    }

    f32x4 acc[4][6];
#pragma unroll
    for (int pt = 0; pt < 4; pt++) {
        const short8 bfr = *reinterpret_cast<const short8*>(
            &xs[(w * 64 + pt * 16 + lrow) * XST + kg * 8]);
#pragma unroll
        for (int mt = 0; mt < 6; mt++)
            acc[pt][mt] = __builtin_amdgcn_mfma_f32_16x16x32_bf16(afr[mt], bfr, binit[mt], 0, 0, 0);
    }

    ushort* ob = (ushort*)qkv;
#pragma unroll
    for (int pt = 0; pt < 4; pt++) {
        int hw = hw0 + w * 64 + pt * 16 + lrow;
#pragma unroll
        for (int mt = 0; mt < 6; mt++) {
#pragma unroll
            for (int r = 0; r < 4; r++) {
                int o = mt * 16 + kg * 4 + r;
                if (o < 81) {
                    int t = (o >= 54) ? 2 : (o >= 27 ? 1 : 0);
                    int oc = o - t * 27;
                    ob[((size_t)t * BB + b) * CHW + (size_t)oc * HW + hw] = f2bf(acc[pt][mt][r]);
                }
            }
        }
    }
}

// ---------------- 3. 8x8 avg pool -> transposed [b][g][27] ----------------
__global__ void k_pool(const __hip_bfloat16* __restrict__ src, float* __restrict__ dst) {
    int idx = blockIdx.x * 256 + threadIdx.x;  // < 4*27*3136 = 338688
    int g = idx % GG;
    int t = idx / GG;
    int c = t % 27;
    int b = t / 27;
    int gh = g / 56, gw = g - (g / 56) * 56;
    const ushort* sp = (const ushort*)src + (size_t)(b * 27 + c) * HW + (size_t)(gh * 8) * 448 + gw * 8;
    float s = 0.f;
#pragma unroll
    for (int r = 0; r < 8; r++) {
        const ushort4 a = *reinterpret_cast<const ushort4*>(sp + r * 448);
        const ushort4 d = *reinterpret_cast<const ushort4*>(sp + r * 448 + 4);
        s += bf2f(a.x) + bf2f(a.y) + bf2f(a.z) + bf2f(a.w)
           + bf2f(d.x) + bf2f(d.y) + bf2f(d.z) + bf2f(d.w);
    }
    dst[((size_t)b * GG + g) * 27 + c] = s * (1.f / 64.f);
}

// ---------------- 4a. patch attention S partials via MFMA ----------------
__global__ __launch_bounds__(448, 1)
void k_spart_mfma(const __hip_bfloat16* __restrict__ q, const __hip_bfloat16* __restrict__ k,
                  float* __restrict__ spart) {
    __shared__ ushort lq[MPAD * 64];   // 28672 B
    __shared__ ushort lk[MPAD * 64];
    int blk = blockIdx.x;              // 4b * 54ks = 216
    int ks = blk % NKS;
    int b = blk / NKS;
    const ushort* qb_ = (const ushort*)q + (size_t)b * CHW;
    const ushort* kb_ = (const ushort*)k + (size_t)b * CHW;
    int t = threadIdx.x;
    int w = t >> 6, l = t & 63;
    int lrow = l & 15, lg = l >> 4;    // fragment coords
    int sr = t & 15;                   // d-pair index 0..15 (d = 2sr, 2sr+1)
    int sn8 = t >> 4;                  // col-chunk 0..27 (cols sn8*8..+8)

    f32x4 acc[2][13];
#pragma unroll
    for (int i = 0; i < 2; i++)
#pragma unroll
        for (int ct = 0; ct < 13; ct++) acc[i][ct] = (f32x4){0.f, 0.f, 0.f, 0.f};

    int d0 = ks * KCH;
    for (int step = 0; step < KCH / 32; ++step) {
        int dbase = d0 + step * 32;
        {
            const ushort* s0 = qb_ + (size_t)(dbase + 2 * sr) * NP + sn8 * 8;
            const ushort* s1 = s0 + NP;
            ushort4 a0 = *reinterpret_cast<const ushort4*>(s0);
            ushort4 a1 = *reinterpret_cast<const ushort4*>(s0 + 4);
            ushort4 b0 = *reinterpret_cast<const ushort4*>(s1);
            ushort4 b1 = *reinterpret_cast<const ushort4*>(s1 + 4);
            ushort ra[8] = {a0.x, a0.y, a0.z, a0.w, a1.x, a1.y, a1.z, a1.w};
            ushort rb[8] = {b0.x, b0.y, b0.z, b0.w, b1.x, b1.y, b1.z, b1.w};
#pragma unroll
            for (int kk = 0; kk < 8; kk++) {
                int n = sn8 * 8 + kk;
                uint32_t val = (uint32_t)ra[kk] | ((uint32_t)rb[kk] << 16);
                *reinterpret_cast<uint32_t*>(reinterpret_cast<char*>(lq) + n * ROWB +
                                             ((4 * sr) ^ (16 * (n & 7)))) = val;
            }
        }
        {
            const ushort* s0 = kb_ + (size_t)(dbase + 2 * sr) * NP + sn8 * 8;
            const ushort* s1 = s0 + NP;
            ushort4 a0 = *reinterpret_cast<const ushort4*>(s0);
            ushort4 a1 = *reinterpret_cast<const ushort4*>(s0 + 4);
            ushort4 b0 = *reinterpret_cast<const ushort4*>(s1);
            ushort4 b1 = *reinterpret_cast<const ushort4*>(s1 + 4);
            ushort ra[8] = {a0.x, a0.y, a0.z, a0.w, a1.x, a1.y, a1.z, a1.w};
            ushort rb[8] = {b0.x, b0.y, b0.z, b0.w, b1.x, b1.y, b1.z, b1.w};
#pragma unroll
            for (int kk = 0; kk < 8; kk++) {
                int m = sn8 * 8 + kk;
                uint32_t val = (uint32_t)ra[kk] | ((uint32_t)rb[kk] << 16);
                *reinterpret_cast<uint32_t*>(reinterpret_cast<char*>(lk) + m * ROWB +
                                             ((4 * sr) ^ (16 * (m & 7)))) = val;
            }
        }
        __syncthreads();
        int nA0 = (2 * w) * 16 + lrow;
        int nA1 = nA0 + 16;
        const short8 afr0 = *reinterpret_cast<const short8*>(
            reinterpret_cast<const char*>(lq) + nA0 * ROWB + 16 * (lg ^ (nA0 & 7)));
        const short8 afr1 = *reinterpret_cast<const short8*>(
            reinterpret_cast<const char*>(lq) + nA1 * ROWB + 16 * (lg ^ (nA1 & 7)));
#pragma unroll
        for (int ct = 0; ct < 13; ct++) {
            int m = ct * 16 + lrow;
            const short8 bfr = *reinterpret_cast<const short8*>(
                reinterpret_cast<const char*>(lk) + m * ROWB + 16 * (lg ^ (m & 7)));
            acc[0][ct] = __builtin_amdgcn_mfma_f32_16x16x32_bf16(afr0, bfr, acc[0][ct], 0, 0, 0);
            acc[1][ct] = __builtin_amdgcn_mfma_f32_16x16x32_bf16(afr1, bfr, acc[1][ct], 0, 0, 0);
        }
        __syncthreads();
    }
    float* sp = spart + (size_t)(b * NKS + ks) * NP * MPAD;
#pragma unroll
    for (int i = 0; i < 2; i++) {
        int rt = 2 * w + i;
#pragma unroll
        for (int r = 0; r < 4; r++) {
            int n = rt * 16 + lg * 4 + r;
            if (n < NP) {
#pragma unroll
                for (int ct = 0; ct < 13; ct++)
                    sp[(size_t)n * MPAD + ct * 16 + lrow] = acc[i][ct][r];
            }
        }
    }
}

// ---------------- 4b. reduce + row softmax -> whf fragment-major bf16 ----------------
// whf[b][((ct*7+step)*64 + kg*16 + lr)*8 + e]: B-fragment layout for k_hp_fused.
// value (query i=n, key j=m): ct=n>>4, lr=n&15, step=m>>5, kg=(m>>3)&3, e=m&7.
// cols m in [196,224) written 0; rows n in [196,208) left unwritten (never read into
// stored outputs: MFMA D-columns are independent).
__global__ void k_softmax(const float* __restrict__ spart, __hip_bfloat16* __restrict__ whf) {
    int blk = blockIdx.x;        // BB*196
    int n = blk % NP;            // query row
    int b = blk / NP;
    int m = threadIdx.x;         // key col
    float val = -1e30f;
    if (m < 196) {
        float s = 0.f;
        for (int ks = 0; ks < NKS; ks++)
            s += spart[((size_t)(b * NKS + ks) * NP + n) * MPAD + m];
        val = s * SCALE_P;
    }
    float mx = val;
    for (int o = 32; o; o >>= 1) mx = fmaxf(mx, __shfl_xor(mx, o));
    __shared__ float redm[4], reds[4];
    int wid = threadIdx.x >> 6, lane = threadIdx.x & 63;
    if (lane == 0) redm[wid] = mx;
    __syncthreads();
    mx = fmaxf(fmaxf(redm[0], redm[1]), fmaxf(redm[2], redm[3]));
    float p = (m < 196) ? __expf(val - mx) : 0.f;
    float sm = p;
    for (int o = 32; o; o >>= 1) sm += __shfl_xor(sm, o);
    if (lane == 0) reds[wid] = sm;
    __syncthreads();
    sm = reds[0] + reds[1] + reds[2] + reds[3];
    if (m < 224) {
        int ct = n >> 4, lr = n & 15;
        int step = m >> 5, kg = (m >> 3) & 3, e = m & 7;
        size_t addr = (size_t)b * WFRAG +
                      (((size_t)(ct * 7 + step) * 64 + kg * 16 + lr) << 3) + e;
        whf[addr] = __float2bfloat16((m < 196) ? p / sm : 0.f);
    }
}

// ---------------- 5. global pooled attention: flash MFMA ----------------
__global__ __launch_bounds__(256)
void k_gattn_flash(const float* __restrict__ qg, const float* __restrict__ kg,
                   const float* __restrict__ vg, float* __restrict__ hg) {
    __shared__ __align__(16) ushort ksh[GKC * KST];    // [k][d] 17920 B
    __shared__ __align__(16) ushort vsh[32 * VST];     // [d][k] 14848 B
    __shared__ __align__(16) ushort psh[4][16 * VST];  // per-wave P [q][k] 29696 B

    int blk = blockIdx.x;              // BB * 49
    int b = blk / 49;
    int q0 = (blk % 49) * 64;
    int tid = threadIdx.x;
    int w = tid >> 6, l = tid & 63;
    int lr = l & 15, lg = l >> 4;

    for (int i = tid; i < GKC; i += 256) {
        ushort* kr = &ksh[i * KST];
        kr[27] = 0; kr[28] = 0; kr[29] = 0; kr[30] = 0; kr[31] = 0;
        vsh[27 * VST + i] = 0x3f80;    // bf16 1.0
        vsh[28 * VST + i] = 0; vsh[29 * VST + i] = 0;
        vsh[30 * VST + i] = 0; vsh[31 * VST + i] = 0;
    }

    short8 aq;
    {
        const float* qr = qg + ((size_t)b * GG + q0 + w * 16 + lr) * 27;
#pragma unroll
        for (int j = 0; j < 8; j++) {
            int c = 8 * lg + j;
            aq[j] = (c < 27) ? (short)f2bf(qr[c]) : (short)0;
        }
    }

    f32x4 acc_h0 = {0.f, 0.f, 0.f, 0.f};
    f32x4 acc_h1 = {0.f, 0.f, 0.f, 0.f};
    ushort* myps = &psh[w][0];
    const float* kgb = kg + (size_t)b * GG * 27;
    const float* vgb = vg + (size_t)b * GG * 27;

    for (int ch = 0; ch < 14; ch++) {
        __syncthreads();
        int base = ch * GKC * 27;
        for (int idx = tid; idx < GKC * 27; idx += 256) {
            int kk = idx / 27, c = idx - (idx / 27) * 27;
            ksh[kk * KST + c] = f2bf(kgb[base + idx]);
            vsh[c * VST + kk] = f2bf(vgb[base + idx]);
        }
        __syncthreads();

        f32x4 s[14];
#pragma unroll
        for (int ct = 0; ct < 14; ct++) {
            const short8 bk = *reinterpret_cast<const short8*>(
                &ksh[(ct * 16 + lr) * KST + 8 * lg]);
            s[ct] = __builtin_amdgcn_mfma_f32_16x16x32_bf16(
                aq, bk, (f32x4){0.f, 0.f, 0.f, 0.f}, 0, 0, 0);
        }
#pragma unroll
        for (int ct = 0; ct < 14; ct++) {
#pragma unroll
            for (int r = 0; r < 4; r++) {
                float p = __expf(s[ct][r] * SCALE_G);
                myps[(4 * lg + r) * VST + ct * 16 + lr] = f2bf(p);
            }
        }
#pragma unroll
        for (int kstep = 0; kstep < 7; kstep++) {
            const short8 ap = *reinterpret_cast<const short8*>(
                &myps[lr * VST + kstep * 32 + 8 * lg]);
            const short8 bv0 = *reinterpret_cast<const short8*>(
                &vsh[lr * VST + kstep * 32 + 8 * lg]);
            const short8 bv1 = *reinterpret_cast<const short8*>(
                &vsh[(16 + lr) * VST + kstep * 32 + 8 * lg]);
            acc_h0 = __builtin_amdgcn_mfma_f32_16x16x32_bf16(ap, bv0, acc_h0, 0, 0, 0);
            acc_h1 = __builtin_amdgcn_mfma_f32_16x16x32_bf16(ap, bv1, acc_h1, 0, 0, 0);
        }
    }

#pragma unroll
    for (int r = 0; r < 4; r++) {
        float lsum = __shfl(acc_h1[r], (l & 48) | 11, 64);
        float inv = 1.f / lsum;
        int q = q0 + w * 16 + 4 * lg + r;
        float* hr = hg + ((size_t)b * GG + q) * 27;
        hr[lr] = acc_h0[r] * inv;
        if (lr < 11) hr[16 + lr] = acc_h1[r] * inv;
    }
}

// ---------------- 6. h_patch GEMM via MFMA, fused blend + residual -> out ----------------
// B operand (whf) is fragment-major: each load = 64 lanes x 16B contiguous (1KB).
// A (V rows) fully prefetched: one vmcnt drain instead of 7 serial HBM waits.
__global__ __launch_bounds__(256)
void k_hp_fused(const __hip_bfloat16* __restrict__ v, const __hip_bfloat16* __restrict__ whf,
                const float* __restrict__ x, const float* __restrict__ hg,
                float* __restrict__ out) {
    int blk = blockIdx.x;              // BB * 432
    int b = blk / 432;
    int grp = blk % 432;
    int w = threadIdx.x >> 6, l = threadIdx.x & 63;
    int ar = l & 15;                   // A row within tile / B col
    int kg = l >> 4;                   // k-group
    int D0 = (grp * 4 + w) * 16;       // d-tile base

    const ushort* vb = (const ushort*)v + (size_t)b * CHW;
    const ushort* wf = (const ushort*)whf + (size_t)b * WFRAG;

    // prefetch all 7 A fragments (V row D0+ar, 56B overread covered by zero tail)
    const ushort* arow = vb + (size_t)(D0 + ar) * NP;
    short8 av[7];
#pragma unroll
    for (int step = 0; step < 7; ++step) {
        int joff = step * 32 + kg * 8;
        ushort4 alo = *reinterpret_cast<const ushort4*>(arow + joff);
        ushort4 ahi = *reinterpret_cast<const ushort4*>(arow + joff + 4);
        av[step][0] = alo.x; av[step][1] = alo.y; av[step][2] = alo.z; av[step][3] = alo.w;
        av[step][4] = ahi.x; av[step][5] = ahi.y; av[step][6] = ahi.z; av[step][7] = ahi.w;
    }

    f32x4 acc[13];
#pragma unroll
    for (int ct = 0; ct < 13; ct++) {
        f32x4 a = {0.f, 0.f, 0.f, 0.f};
#pragma unroll
        for (int step = 0; step < 7; ++step) {
            const short8 bv = *reinterpret_cast<const short8*>(
                wf + (((size_t)(ct * 7 + step) * 64 + l) << 3));
            a = __builtin_amdgcn_mfma_f32_16x16x32_bf16(av[step], bv, a, 0, 0, 0);
        }
        acc[ct] = a;
    }

    const float* xb = x + (size_t)b * CHW;
    float* ob = out + (size_t)b * CHW;
    const float* hgb = hg + (size_t)b * GG * 27;
    int c = D0 >> 10;
    int strip0 = D0 & 1023;
#pragma unroll
    for (int ct = 0; ct < 13; ct++) {
        int i = ct * 16 + ar;
        if (i < NP) {
#pragma unroll
            for (int r = 0; r < 4; r++) {
                int strip = strip0 + kg * 4 + r;
                int hw = strip * NP + i;
                int h = hw / 448;
                int w2 = hw - h * 448;
                int g = (h >> 3) * 56 + (w2 >> 3);
                size_t addr = (size_t)c * HW + hw;
                ob[addr] = xb[addr] + 0.75f * acc[ct][r] + 0.25f * hgb[g * 27 + c];
            }
        }
    }
}

// ---------------- launch ----------------
extern "C" void kernel_launch(void* const* d_in, const int* in_sizes, int n_in,
                              void* d_out, int out_size, void* d_ws, size_t ws_size,
                              hipStream_t stream) {
    const float* x    = (const float*)d_in[0];
    const float* gnw  = (const float*)d_in[1];
    const float* gnb  = (const float*)d_in[2];
    const float* qw   = (const float*)d_in[3];
    const float* qb   = (const float*)d_in[4];
    const float* kw   = (const float*)d_in[5];
    const float* kb   = (const float*)d_in[6];
    const float* vw   = (const float*)d_in[7];
    const float* vb   = (const float*)d_in[8];
    const float* pjw  = (const float*)d_in[9];
    float* out = (float*)d_out;

    char* ws = (char*)d_ws;
    size_t off = 0;
    auto alloc = [&](size_t bytes) { void* p = ws + off; off += (bytes + 255) & ~(size_t)255; return p; };
    // qkv: contiguous [3][BB][27][HW] bf16 + 64B zero tail (k_hp_fused overread)
    __hip_bfloat16* qkvbuf = (__hip_bfloat16*)alloc((size_t)3 * BB * CHW * 2 + 64);
    __hip_bfloat16* qbf = qkvbuf;
    __hip_bfloat16* kbf = qkvbuf + (size_t)BB * CHW;
    __hip_bfloat16* vbf = qkvbuf + (size_t)2 * BB * CHW;
    float* spart = (float*)alloc((size_t)BB * NKS * NP * MPAD * 4);
    __hip_bfloat16* wHat = (__hip_bfloat16*)alloc((size_t)BB * WFRAG * 2);
    float* qg    = (float*)alloc((size_t)BB * GG * 27 * 4);
    float* kg    = (float*)alloc((size_t)BB * GG * 27 * 4);
    float* vg    = (float*)alloc((size_t)BB * GG * 27 * 4);
    float* hg    = (float*)alloc((size_t)BB * GG * 27 * 4);
    float* part  = (float*)alloc((size_t)BB * 1024 * 2 * 4);
    float* stats = (float*)alloc((size_t)BB * 2 * 4);
    float* pvw   = (float*)alloc(729 * 4);
    float* pvb   = (float*)alloc(27 * 4);

    (void)hipMemsetAsync((char*)qkvbuf + (size_t)3 * BB * CHW * 2, 0, 64, stream);
    k_fold<<<1, 256, 0, stream>>>(pjw, vw, vb, pvw, pvb);
    k_gn_partial<<<BB * 1024, 256, 0, stream>>>(x, part);
    k_gn_final<<<BB, 256, 0, stream>>>(part, stats);
    k_qkv_mfma<<<(BB * HW) / 256, 256, 0, stream>>>(x, stats, qw, qb, kw, kb, pvw, pvb,
                                                    gnw, gnb, qkvbuf);
    k_pool<<<(BB * 27 * GG) / 256, 256, 0, stream>>>(qbf, qg);
    k_pool<<<(BB * 27 * GG) / 256, 256, 0, stream>>>(kbf, kg);
    k_pool<<<(BB * 27 * GG) / 256, 256, 0, stream>>>(vbf, vg);
    k_spart_mfma<<<BB * NKS, 448, 0, stream>>>(qbf, kbf, spart);
    k_softmax<<<BB * NP, 256, 0, stream>>>(spart, wHat);
    k_gattn_flash<<<BB * 49, 256, 0, stream>>>(qg, kg, vg, hg);
    k_hp_fused<<<BB * 432, 256, 0, stream>>>(vbf, wHat, x, hg, out);
}